// Round 1
// baseline (3532.339 us; speedup 1.0000x reference)
//
#include <hip/hip_runtime.h>
#include <hip/hip_bf16.h>

#define B 8
#define N1 8192
#define N4 2048
#define CH 128
#define KNN 32
#define ROWS_PER_B (N4 * KNN)          // 65536 rows per batch in the [B,N,K] flattening
#define ROWS_TOTAL (B * ROWS_PER_B)    // 524288
#define FLOWLR_OFF (B * 3 * N1)        // flow_lr starts after flow in d_out

typedef unsigned int uint;

__device__ __forceinline__ float bf2f(unsigned short u) {
    union { uint i; float f; } v; v.i = ((uint)u) << 16; return v.f;
}

// ---------------- setup: transpose xyz_s4 [B,3,N4] -> xyz4 [B,N4,3] ----------------
__global__ void k_xyz_t(const float* __restrict__ xyz_s4, float* __restrict__ xyz4) {
    int g = blockIdx.x * 256 + threadIdx.x;
    if (g >= B * N4) return;
    int b = g >> 11, n = g & (N4 - 1);
    float x = xyz_s4[(b * 3 + 0) * N4 + n];
    float y = xyz_s4[(b * 3 + 1) * N4 + n];
    float z = xyz_s4[(b * 3 + 2) * N4 + n];
    xyz4[g * 3 + 0] = x; xyz4[g * 3 + 1] = y; xyz4[g * 3 + 2] = z;
}

// ---------------- transpose feats [B,C,N4] -> featA [B,N4,C] ----------------
__global__ void k_feat_t(const float* __restrict__ feats, float* __restrict__ featA) {
    __shared__ float tile[32][33];
    int b = blockIdx.x, nb = blockIdx.y, cb = blockIdx.z;
    int tx = threadIdx.x, ty = threadIdx.y; // 32 x 8
    int n0 = nb * 32, c0 = cb * 32;
#pragma unroll
    for (int i = 0; i < 4; ++i) {
        int c = c0 + ty + 8 * i;
        tile[ty + 8 * i][tx] = feats[((size_t)b * CH + c) * N4 + n0 + tx];
    }
    __syncthreads();
#pragma unroll
    for (int i = 0; i < 4; ++i) {
        int n = n0 + ty + 8 * i;
        featA[((size_t)b * N4 + n) * CH + c0 + tx] = tile[tx][ty + 8 * i];
    }
}

// ---------------- KNN: 32 nearest (incl self) among the 2048 points of each batch ----------------
// One wave per query point. Candidates distributed 32 per lane; 32 x extract-min
// with (value, index) tie-break on lower index (matches lax.top_k stability).
__global__ __launch_bounds__(256) void k_knn(const float* __restrict__ xyz4, int* __restrict__ idxout) {
    __shared__ float pts[N4 * 3];
    int b = blockIdx.x >> 9;            // 512 blocks per batch
    int qbase = (blockIdx.x & 511) * 4;
    for (int i = threadIdx.x; i < N4 * 3; i += 256) pts[i] = xyz4[(size_t)b * N4 * 3 + i];
    __syncthreads();
    int wave = threadIdx.x >> 6, lane = threadIdx.x & 63;
    int qn = qbase + wave;
    float qx = pts[qn * 3 + 0], qy = pts[qn * 3 + 1], qz = pts[qn * 3 + 2];
    float d[32];
#pragma unroll
    for (int t = 0; t < 32; ++t) {
        int c = t * 64 + lane;
        float dx = pts[c * 3 + 0] - qx;
        float dy = pts[c * 3 + 1] - qy;
        float dz = pts[c * 3 + 2] - qz;
        d[t] = dx * dx + dy * dy + dz * dz;
    }
    int outbase = (b * N4 + qn) * KNN;
    for (int e = 0; e < KNN; ++e) {
        float lv = 3.4e38f; int li = 0x7fffffff;
#pragma unroll
        for (int t = 0; t < 32; ++t) {
            int ci = t * 64 + lane;
            if (d[t] < lv) { lv = d[t]; li = ci; }
        }
#pragma unroll
        for (int m = 1; m < 64; m <<= 1) {
            float ov = __shfl_xor(lv, m, 64);
            int   oi = __shfl_xor(li, m, 64);
            if (ov < lv || (ov == lv && oi < li)) { lv = ov; li = oi; }
        }
        if (lane == 0) idxout[outbase + e] = li;
        if ((li & 63) == lane) {
            int tt = li >> 6;
#pragma unroll
            for (int t = 0; t < 32; ++t) if (t == tt) d[t] = 3.4e38f;
        }
    }
}

// ---------------- SA pass A: gather + GEMM1 (K=131) -> ybuf (bf16) ----------------
// K-dim permuted to [feats(128) | gxyz(3) | 0pad]; W permuted identically.
__global__ __launch_bounds__(256, 1) void k_gemmA(
    const float* __restrict__ F, const float* __restrict__ xyz4,
    const int* __restrict__ idx,
    const float* __restrict__ W1, const float* __restrict__ b1,
    __hip_bfloat16* __restrict__ ybuf)
{
    __shared__ float hs[64][132];
    __shared__ float ws[128][132];
    int t = threadIdx.x;
    for (int i = t; i < 128 * 132; i += 256) {
        int dd = i / 132, c = i - dd * 132;
        float v = 0.f;
        if (c < 128)      v = W1[dd * 131 + 3 + c];
        else if (c < 131) v = W1[dd * 131 + (c - 128)];
        ws[dd][c] = v;
    }
    int r = t >> 2, q = t & 3;
    int g0 = blockIdx.x * 64;
    {
        int g = g0 + r;
        int b = g >> 16;                 // 65536 rows per batch
        int rem = g & 65535;
        int n = rem >> 5;
        int j = idx[g];
        const float* Frow = F + ((size_t)(b * N4 + j)) * CH;
#pragma unroll
        for (int m0 = 0; m0 < 8; ++m0) {
            int m = q + m0 * 4;
            *(float4*)&hs[r][m * 4] = *(const float4*)&Frow[m * 4];
        }
        if (q == 0) {
            const float* pj = xyz4 + (size_t)(b * N4 + j) * 3;
            const float* pn = xyz4 + (size_t)(b * N4 + n) * 3;
            hs[r][128] = pj[0] - pn[0];
            hs[r][129] = pj[1] - pn[1];
            hs[r][130] = pj[2] - pn[2];
            hs[r][131] = 0.f;
        }
    }
    __syncthreads();
    int tx = t & 15, ty = t >> 4;
    float acc[4][8];
#pragma unroll
    for (int i = 0; i < 4; ++i)
#pragma unroll
        for (int jj = 0; jj < 8; ++jj) acc[i][jj] = 0.f;
    for (int kb = 0; kb < 33; ++kb) {
        float4 a[4]; float4 w[8];
#pragma unroll
        for (int i = 0; i < 4; ++i) a[i] = *(float4*)&hs[ty * 4 + i][kb * 4];
#pragma unroll
        for (int jj = 0; jj < 8; ++jj) w[jj] = *(float4*)&ws[tx + 16 * jj][kb * 4];
#pragma unroll
        for (int i = 0; i < 4; ++i)
#pragma unroll
            for (int jj = 0; jj < 8; ++jj)
                acc[i][jj] += a[i].x * w[jj].x + a[i].y * w[jj].y
                            + a[i].z * w[jj].z + a[i].w * w[jj].w;
    }
#pragma unroll
    for (int jj = 0; jj < 8; ++jj) {
        int c = tx + 16 * jj;
        float bias = b1[c];
#pragma unroll
        for (int i = 0; i < 4; ++i) {
            int g = g0 + ty * 4 + i;
            ybuf[(size_t)g * CH + c] = __float2bfloat16(acc[i][jj] + bias);
        }
    }
}

// ---------------- per-(b,c) sum / sumsq over ybuf ----------------
__global__ void k_stats(const __hip_bfloat16* __restrict__ ybuf, float* __restrict__ stats) {
    __shared__ float red[1024];
    int blk = blockIdx.x;
    int b = blk >> 7, slab = blk & 127;  // 128 slabs x 512 rows
    int t = threadIdx.x;
    int p = t & 63;                      // uint (2 bf16) index within a 128-col row
    int rsub = t >> 6;
    const uint* base = (const uint*)(ybuf + ((size_t)b * ROWS_PER_B + slab * 512) * CH);
    float s0 = 0.f, s1 = 0.f, q0 = 0.f, q1 = 0.f;
    for (int rr = rsub; rr < 512; rr += 4) {
        uint v = base[rr * 64 + p];
        float f0 = bf2f((unsigned short)(v & 0xffff));
        float f1 = bf2f((unsigned short)(v >> 16));
        s0 += f0; q0 += f0 * f0; s1 += f1; q1 += f1 * f1;
    }
    red[t] = s0; __syncthreads();
    float S0 = (t < 64) ? red[t] + red[t + 64] + red[t + 128] + red[t + 192] : 0.f;
    __syncthreads(); red[t] = s1; __syncthreads();
    float S1 = (t < 64) ? red[t] + red[t + 64] + red[t + 128] + red[t + 192] : 0.f;
    __syncthreads(); red[t] = q0; __syncthreads();
    float Q0 = (t < 64) ? red[t] + red[t + 64] + red[t + 128] + red[t + 192] : 0.f;
    __syncthreads(); red[t] = q1; __syncthreads();
    float Q1 = (t < 64) ? red[t] + red[t + 64] + red[t + 128] + red[t + 192] : 0.f;
    if (t < 64) {
        int c0 = 2 * t, c1 = 2 * t + 1;
        atomicAdd(&stats[b * CH + c0], S0);
        atomicAdd(&stats[b * CH + c1], S1);
        atomicAdd(&stats[B * CH + b * CH + c0], Q0);
        atomicAdd(&stats[B * CH + b * CH + c1], Q1);
    }
}

// ---------------- SA pass B: norm+relu -> GEMM2 (K=128), in-place on ybuf ----------------
__global__ __launch_bounds__(256, 1) void k_gemmB(
    __hip_bfloat16* __restrict__ ybuf,
    const float* __restrict__ W2, const float* __restrict__ b2,
    const float* __restrict__ stats)
{
    __shared__ float hs[64][132];
    __shared__ float ws[128][132];
    __shared__ float smean[128], sinv[128];
    int t = threadIdx.x;
    int g0 = blockIdx.x * 64;
    int b = g0 >> 16;
    if (t < 128) {
        float s = stats[b * CH + t];
        float q2 = stats[B * CH + b * CH + t];
        float mean = s * (1.f / ROWS_PER_B);
        float var = q2 * (1.f / ROWS_PER_B) - mean * mean;
        smean[t] = mean;
        sinv[t] = rsqrtf(var + 1e-5f);
    }
    for (int i = t; i < 128 * 132; i += 256) {
        int dd = i / 132, c = i - dd * 132;
        ws[dd][c] = (c < 128) ? W2[dd * 128 + c] : 0.f;
    }
    __syncthreads();   // smean/sinv ready
    int r = t >> 2, q = t & 3;
    {
        int g = g0 + r;
        const uint2* yrow = (const uint2*)(ybuf + (size_t)g * CH);
#pragma unroll
        for (int m0 = 0; m0 < 8; ++m0) {
            int m = q + m0 * 4;          // uint2 index = 4 bf16
            uint2 v = yrow[m];
            int c = m * 4;
            float f0 = bf2f((unsigned short)(v.x & 0xffff));
            float f1 = bf2f((unsigned short)(v.x >> 16));
            float f2 = bf2f((unsigned short)(v.y & 0xffff));
            float f3 = bf2f((unsigned short)(v.y >> 16));
            float4 o;
            o.x = fmaxf((f0 - smean[c + 0]) * sinv[c + 0], 0.f);
            o.y = fmaxf((f1 - smean[c + 1]) * sinv[c + 1], 0.f);
            o.z = fmaxf((f2 - smean[c + 2]) * sinv[c + 2], 0.f);
            o.w = fmaxf((f3 - smean[c + 3]) * sinv[c + 3], 0.f);
            *(float4*)&hs[r][c] = o;
        }
        if (q == 0) *(float4*)&hs[r][128] = make_float4(0.f, 0.f, 0.f, 0.f);
    }
    __syncthreads();
    int tx = t & 15, ty = t >> 4;
    float acc[4][8];
#pragma unroll
    for (int i = 0; i < 4; ++i)
#pragma unroll
        for (int jj = 0; jj < 8; ++jj) acc[i][jj] = 0.f;
    for (int kb = 0; kb < 33; ++kb) {
        float4 a[4]; float4 w[8];
#pragma unroll
        for (int i = 0; i < 4; ++i) a[i] = *(float4*)&hs[ty * 4 + i][kb * 4];
#pragma unroll
        for (int jj = 0; jj < 8; ++jj) w[jj] = *(float4*)&ws[tx + 16 * jj][kb * 4];
#pragma unroll
        for (int i = 0; i < 4; ++i)
#pragma unroll
            for (int jj = 0; jj < 8; ++jj)
                acc[i][jj] += a[i].x * w[jj].x + a[i].y * w[jj].y
                            + a[i].z * w[jj].z + a[i].w * w[jj].w;
    }
#pragma unroll
    for (int jj = 0; jj < 8; ++jj) {
        int c = tx + 16 * jj;
        float bias = b2[c];
#pragma unroll
        for (int i = 0; i < 4; ++i) {
            int g = g0 + ty * 4 + i;
            ybuf[(size_t)g * CH + c] = __float2bfloat16(acc[i][jj] + bias);
        }
    }
}

// ---------------- SA pass C: max over k, then norm+relu (monotone, commutes) ----------------
__global__ void k_passC(const __hip_bfloat16* __restrict__ ybuf, const float* __restrict__ stats,
                        float* __restrict__ fout) {
    int g = blockIdx.x;                  // (b,n)
    int b = g >> 11;
    int c = threadIdx.x;                 // 128 threads
    const __hip_bfloat16* base = ybuf + (size_t)g * KNN * CH;
    float mx = -3.4e38f;
#pragma unroll 4
    for (int k = 0; k < KNN; ++k) mx = fmaxf(mx, bf2f(((const unsigned short*)base)[k * CH + c]));
    float s = stats[b * CH + c], q2 = stats[B * CH + b * CH + c];
    float mean = s * (1.f / ROWS_PER_B);
    float var = q2 * (1.f / ROWS_PER_B) - mean * mean;
    float inv = rsqrtf(var + 1e-5f);
    fout[(size_t)g * CH + c] = fmaxf((mx - mean) * inv, 0.f);
}

// ---------------- FC head: relu(X@W1^T+b1) @ W2^T + b2 -> flow_lr [B,3,N4] in d_out ----------------
__global__ __launch_bounds__(256, 1) void k_fc(
    const float* __restrict__ X, const float* __restrict__ W1,
    const float* __restrict__ b1, const float* __restrict__ W2,
    const float* __restrict__ b2, float* __restrict__ out)
{
    __shared__ float hs[64][132];
    __shared__ float ws[128][132];
    int t = threadIdx.x;
    for (int i = t; i < 128 * 132; i += 256) {
        int dd = i / 132, c = i - dd * 132;
        ws[dd][c] = (c < 128) ? W1[dd * 128 + c] : 0.f;
    }
    int r = t >> 2, q = t & 3;
    int g0 = blockIdx.x * 64;
    {
        const float* Xrow = X + (size_t)(g0 + r) * CH;
#pragma unroll
        for (int m0 = 0; m0 < 8; ++m0) {
            int m = q + m0 * 4;
            *(float4*)&hs[r][m * 4] = *(const float4*)&Xrow[m * 4];
        }
        if (q == 0) *(float4*)&hs[r][128] = make_float4(0.f, 0.f, 0.f, 0.f);
    }
    __syncthreads();
    int tx = t & 15, ty = t >> 4;
    float acc[4][8];
#pragma unroll
    for (int i = 0; i < 4; ++i)
#pragma unroll
        for (int jj = 0; jj < 8; ++jj) acc[i][jj] = 0.f;
    for (int kb = 0; kb < 33; ++kb) {
        float4 a[4]; float4 w[8];
#pragma unroll
        for (int i = 0; i < 4; ++i) a[i] = *(float4*)&hs[ty * 4 + i][kb * 4];
#pragma unroll
        for (int jj = 0; jj < 8; ++jj) w[jj] = *(float4*)&ws[tx + 16 * jj][kb * 4];
#pragma unroll
        for (int i = 0; i < 4; ++i)
#pragma unroll
            for (int jj = 0; jj < 8; ++jj)
                acc[i][jj] += a[i].x * w[jj].x + a[i].y * w[jj].y
                            + a[i].z * w[jj].z + a[i].w * w[jj].w;
    }
    __syncthreads();                     // done reading hs
#pragma unroll
    for (int jj = 0; jj < 8; ++jj) {
        int c = tx + 16 * jj;
        float bias = b1[c];
#pragma unroll
        for (int i = 0; i < 4; ++i)
            hs[ty * 4 + i][c] = fmaxf(acc[i][jj] + bias, 0.f);
    }
    __syncthreads();
    if (t < 192) {
        int rr = t / 3, o = t - rr * 3;
        float sum = b2[o];
        for (int c = 0; c < 128; ++c) sum += hs[rr][c] * W2[o * 128 + c];
        int g = g0 + rr;
        int b = g >> 11, n = g & (N4 - 1);
        out[FLOWLR_OFF + ((size_t)b * 3 + o) * N4 + n] = sum;
    }
}

// ---------------- feature propagation: 3-NN inverse-sqdist interp onto xyz1 ----------------
__global__ __launch_bounds__(256) void k_fp(
    const float* __restrict__ xyz_s1, const float* __restrict__ xyz4,
    float* __restrict__ out)
{
    __shared__ float pts[N4 * 3];
    int b = blockIdx.x >> 5;             // 32 blocks per batch
    int i = (blockIdx.x & 31) * 256 + threadIdx.x;
    for (int idx2 = threadIdx.x; idx2 < N4 * 3; idx2 += 256) pts[idx2] = xyz4[(size_t)b * N4 * 3 + idx2];
    __syncthreads();
    float qx = xyz_s1[((size_t)b * 3 + 0) * N1 + i];
    float qy = xyz_s1[((size_t)b * 3 + 1) * N1 + i];
    float qz = xyz_s1[((size_t)b * 3 + 2) * N1 + i];
    float d0 = 3.4e38f, d1 = 3.4e38f, d2 = 3.4e38f;
    int i0 = 0, i1 = 0, i2 = 0;
    for (int n = 0; n < N4; ++n) {
        float dx = pts[n * 3 + 0] - qx;
        float dy = pts[n * 3 + 1] - qy;
        float dz = pts[n * 3 + 2] - qz;
        float dd = dx * dx + dy * dy + dz * dz;
        if (dd < d2) {
            if (dd < d1) {
                if (dd < d0) { d2 = d1; i2 = i1; d1 = d0; i1 = i0; d0 = dd; i0 = n; }
                else         { d2 = d1; i2 = i1; d1 = dd; i1 = n; }
            } else           { d2 = dd; i2 = n; }
        }
    }
    float w0 = 1.f / (d0 + 1e-8f), w1 = 1.f / (d1 + 1e-8f), w2 = 1.f / (d2 + 1e-8f);
    float inv = 1.f / (w0 + w1 + w2);
    const float* flr = out + FLOWLR_OFF + (size_t)b * 3 * N4;
#pragma unroll
    for (int dmn = 0; dmn < 3; ++dmn) {
        float v = (w0 * flr[dmn * N4 + i0] + w1 * flr[dmn * N4 + i1] + w2 * flr[dmn * N4 + i2]) * inv;
        out[((size_t)b * 3 + dmn) * N1 + i] = v;
    }
}

extern "C" void kernel_launch(void* const* d_in, const int* in_sizes, int n_in,
                              void* d_out, int out_size, void* d_ws, size_t ws_size,
                              hipStream_t stream) {
    const float* xyz_s1 = (const float*)d_in[0];
    const float* xyz_s4 = (const float*)d_in[1];
    const float* feats  = (const float*)d_in[2];
    const float* sa1_W1 = (const float*)d_in[3];
    const float* sa1_b1 = (const float*)d_in[4];
    const float* sa1_W2 = (const float*)d_in[5];
    const float* sa1_b2 = (const float*)d_in[6];
    const float* sa2_W1 = (const float*)d_in[7];
    const float* sa2_b1 = (const float*)d_in[8];
    const float* sa2_W2 = (const float*)d_in[9];
    const float* sa2_b2 = (const float*)d_in[10];
    const float* fc_W1  = (const float*)d_in[11];
    const float* fc_b1  = (const float*)d_in[12];
    const float* fc_W2  = (const float*)d_in[13];
    const float* fc_b2  = (const float*)d_in[14];
    float* out = (float*)d_out;

    char* wsb = (char*)d_ws;
    float*          xyz4  = (float*)(wsb + 0);                 // 196608 B
    int*            idx   = (int*)(wsb + 196608);              // 2 MB
    float*          featA = (float*)(wsb + 2293760);           // 8 MB
    float*          featB = (float*)(wsb + 10682368);          // 8 MB
    float*          stats = (float*)(wsb + 19070976);          // 8 KB (sum[B*CH] then sq[B*CH])
    __hip_bfloat16* ybuf  = (__hip_bfloat16*)(wsb + 19079168); // 128 MB

    k_xyz_t<<<64, 256, 0, stream>>>(xyz_s4, xyz4);
    dim3 gt(B, N4 / 32, CH / 32), bt(32, 8);
    k_feat_t<<<gt, bt, 0, stream>>>(feats, featA);
    k_knn<<<B * (N4 / 4), 256, 0, stream>>>(xyz4, idx);

    // ---- SA1 ----
    k_gemmA<<<ROWS_TOTAL / 64, 256, 0, stream>>>(featA, xyz4, idx, sa1_W1, sa1_b1, ybuf);
    hipMemsetAsync(stats, 0, 2 * B * CH * sizeof(float), stream);
    k_stats<<<B * 128, 256, 0, stream>>>(ybuf, stats);
    k_gemmB<<<ROWS_TOTAL / 64, 256, 0, stream>>>(ybuf, sa1_W2, sa1_b2, stats);
    hipMemsetAsync(stats, 0, 2 * B * CH * sizeof(float), stream);
    k_stats<<<B * 128, 256, 0, stream>>>(ybuf, stats);
    k_passC<<<B * N4, 128, 0, stream>>>(ybuf, stats, featB);

    // ---- SA2 ----
    k_gemmA<<<ROWS_TOTAL / 64, 256, 0, stream>>>(featB, xyz4, idx, sa2_W1, sa2_b1, ybuf);
    hipMemsetAsync(stats, 0, 2 * B * CH * sizeof(float), stream);
    k_stats<<<B * 128, 256, 0, stream>>>(ybuf, stats);
    k_gemmB<<<ROWS_TOTAL / 64, 256, 0, stream>>>(ybuf, sa2_W2, sa2_b2, stats);
    hipMemsetAsync(stats, 0, 2 * B * CH * sizeof(float), stream);
    k_stats<<<B * 128, 256, 0, stream>>>(ybuf, stats);
    k_passC<<<B * N4, 128, 0, stream>>>(ybuf, stats, featA);

    // ---- FC head + flow_lr ----
    k_fc<<<(B * N4) / 64, 256, 0, stream>>>(featA, fc_W1, fc_b1, fc_W2, fc_b2, out);
    // ---- feature propagation -> flow ----
    k_fp<<<B * (N1 / 256), 256, 0, stream>>>(xyz_s1, xyz4, out);
}

// Round 2
// 878.337 us; speedup vs baseline: 4.0216x; 4.0216x over previous
//
#include <hip/hip_runtime.h>
#include <hip/hip_bf16.h>

#define B 8
#define N1 8192
#define N4 2048
#define CH 128
#define KNN 32
#define ROWS_PER_B (N4 * KNN)          // 65536 rows per batch in the [B,N,K] flattening
#define ROWS_TOTAL (B * ROWS_PER_B)    // 524288
#define FLOWLR_OFF (B * 3 * N1)        // flow_lr starts after flow in d_out

typedef unsigned int uint;
typedef unsigned short ushort;
typedef __attribute__((ext_vector_type(8))) short short8;
typedef __attribute__((ext_vector_type(4))) float f32x4;

union U16 { uint4 u; short8 s; };

__device__ __forceinline__ float bf2f(ushort u) {
    union { uint i; float f; } v; v.i = ((uint)u) << 16; return v.f;
}
__device__ __forceinline__ ushort f2b(float f) {
    __hip_bfloat16 h = __float2bfloat16(f);
    return *(ushort*)&h;
}

// ---------------- setup: transpose xyz_s4 [B,3,N4] -> xyz4 [B,N4,3] ----------------
__global__ void k_xyz_t(const float* __restrict__ xyz_s4, float* __restrict__ xyz4) {
    int g = blockIdx.x * 256 + threadIdx.x;
    if (g >= B * N4) return;
    int b = g >> 11, n = g & (N4 - 1);
    float x = xyz_s4[(b * 3 + 0) * N4 + n];
    float y = xyz_s4[(b * 3 + 1) * N4 + n];
    float z = xyz_s4[(b * 3 + 2) * N4 + n];
    xyz4[g * 3 + 0] = x; xyz4[g * 3 + 1] = y; xyz4[g * 3 + 2] = z;
}

// ---------------- transpose feats [B,C,N4] fp32 -> featTb [B,N4,C] bf16 ----------------
__global__ void k_feat_t(const float* __restrict__ feats, ushort* __restrict__ featTb) {
    __shared__ float tile[32][33];
    int b = blockIdx.x, nb = blockIdx.y, cb = blockIdx.z;
    int tx = threadIdx.x, ty = threadIdx.y; // 32 x 8
    int n0 = nb * 32, c0 = cb * 32;
#pragma unroll
    for (int i = 0; i < 4; ++i) {
        int c = c0 + ty + 8 * i;
        tile[ty + 8 * i][tx] = feats[((size_t)b * CH + c) * N4 + n0 + tx];
    }
    __syncthreads();
#pragma unroll
    for (int i = 0; i < 4; ++i) {
        int n = n0 + ty + 8 * i;
        featTb[((size_t)b * N4 + n) * CH + c0 + tx] = f2b(tile[tx][ty + 8 * i]);
    }
}

// ---------------- W converters: fp32 -> bf16, permuted/padded ----------------
// mode 0: W [128][131] -> Wb [128][168], col layout [feat k -> W[:,3+k] | gxyz -> W[:,0..2] | 0 pad]
// mode 1: W [128][128] -> Wb [128][136], zero pad
__global__ void k_wconv(const float* __restrict__ W, ushort* __restrict__ Wb, int mode) {
    int i = blockIdx.x * 256 + threadIdx.x;
    if (mode == 0) {
        if (i >= 128 * 168) return;
        int d = i / 168, c = i - d * 168;
        float v = 0.f;
        if (c < 128)      v = W[d * 131 + 3 + c];
        else if (c < 131) v = W[d * 131 + (c - 128)];
        Wb[i] = f2b(v);
    } else {
        if (i >= 128 * 136) return;
        int d = i / 136, c = i - d * 136;
        Wb[i] = (c < 128) ? f2b(W[d * 128 + c]) : (ushort)0;
    }
}

// ---------------- KNN: 32 nearest (incl self) among the 2048 points of each batch ----------------
__global__ __launch_bounds__(256) void k_knn(const float* __restrict__ xyz4, int* __restrict__ idxout) {
    __shared__ float pts[N4 * 3];
    int b = blockIdx.x >> 9;            // 512 blocks per batch
    int qbase = (blockIdx.x & 511) * 4;
    for (int i = threadIdx.x; i < N4 * 3; i += 256) pts[i] = xyz4[(size_t)b * N4 * 3 + i];
    __syncthreads();
    int wave = threadIdx.x >> 6, lane = threadIdx.x & 63;
    int qn = qbase + wave;
    float qx = pts[qn * 3 + 0], qy = pts[qn * 3 + 1], qz = pts[qn * 3 + 2];
    float d[32];
#pragma unroll
    for (int t = 0; t < 32; ++t) {
        int c = t * 64 + lane;
        float dx = pts[c * 3 + 0] - qx;
        float dy = pts[c * 3 + 1] - qy;
        float dz = pts[c * 3 + 2] - qz;
        d[t] = dx * dx + dy * dy + dz * dz;
    }
    int outbase = (b * N4 + qn) * KNN;
    for (int e = 0; e < KNN; ++e) {
        float lv = 3.4e38f; int li = 0x7fffffff;
#pragma unroll
        for (int t = 0; t < 32; ++t) {
            int ci = t * 64 + lane;
            if (d[t] < lv) { lv = d[t]; li = ci; }
        }
#pragma unroll
        for (int m = 1; m < 64; m <<= 1) {
            float ov = __shfl_xor(lv, m, 64);
            int   oi = __shfl_xor(li, m, 64);
            if (ov < lv || (ov == lv && oi < li)) { lv = ov; li = oi; }
        }
        if (lane == 0) idxout[outbase + e] = li;
        if ((li & 63) == lane) {
            int tt = li >> 6;
#pragma unroll
            for (int t = 0; t < 32; ++t) if (t == tt) d[t] = 3.4e38f;
        }
    }
}

// ---------------- SA gemm1 (MFMA): gather + h@W1^T -> ybuf bf16, fused per-(b,c) stats ----------------
// h-row K layout: [feat(128) | gxyz(3) | 0 pad] = 168 (5 chunks of 32, padded)
// SA biases are dropped: InstanceNorm is invariant to per-channel constant shifts.
__global__ __launch_bounds__(256) void k_sa_gemm1(
    const ushort* __restrict__ Fb, const float* __restrict__ xyz4,
    const int* __restrict__ idx, const ushort* __restrict__ W1b,
    ushort* __restrict__ ybuf, float* __restrict__ stats)
{
    __shared__ __align__(16) ushort hs[64][168];
    int t = threadIdx.x;
    int g0 = blockIdx.x * 64;
    int b = g0 >> 16;
    // --- stage gathered rows (bf16 direct copy) ---
    int r = t >> 2, q = t & 3;
    {
        int g = g0 + r;
        int n = (g & 65535) >> 5;
        int j = idx[g];
        const uint4* src = (const uint4*)(Fb + ((size_t)(b * N4 + j)) * CH) + q * 4;
        uint4* dst = (uint4*)&hs[r][q * 32];
#pragma unroll
        for (int m = 0; m < 4; ++m) dst[m] = src[m];
        uint4 z = make_uint4(0, 0, 0, 0);
        *(uint4*)&hs[r][128 + q * 8] = z;          // zero cols 128..159
        if (q == 0) {
            *(uint4*)&hs[r][160] = z;              // zero cols 160..167
            const float* pj = xyz4 + (size_t)(b * N4 + j) * 3;
            const float* pn = xyz4 + (size_t)(b * N4 + n) * 3;
            hs[r][128] = f2b(pj[0] - pn[0]);
            hs[r][129] = f2b(pj[1] - pn[1]);
            hs[r][130] = f2b(pj[2] - pn[2]);
        }
    }
    // --- W fragments to registers (per-wave 32-col slab), overlap with staging ---
    int l = t & 63, w = t >> 6;
    int lr = l & 15, lg = l >> 4;
    U16 bf[5][2];
#pragma unroll
    for (int kc = 0; kc < 5; ++kc)
#pragma unroll
        for (int jj = 0; jj < 2; ++jj)
            bf[kc][jj].u = *(const uint4*)&W1b[(size_t)(w * 32 + jj * 16 + lr) * 168 + kc * 32 + lg * 8];
    __syncthreads();
    f32x4 acc[4][2];
    f32x4 z4 = {0.f, 0.f, 0.f, 0.f};
#pragma unroll
    for (int i = 0; i < 4; ++i) { acc[i][0] = z4; acc[i][1] = z4; }
#pragma unroll
    for (int kc = 0; kc < 5; ++kc) {
        U16 a[4];
#pragma unroll
        for (int i = 0; i < 4; ++i) a[i].u = *(const uint4*)&hs[16 * i + lr][kc * 32 + lg * 8];
#pragma unroll
        for (int i = 0; i < 4; ++i)
#pragma unroll
            for (int jj = 0; jj < 2; ++jj)
                acc[i][jj] = __builtin_amdgcn_mfma_f32_16x16x32_bf16(a[i].s, bf[kc][jj].s, acc[i][jj], 0, 0, 0);
    }
    // --- epilogue: store bf16 + fused stats (each wave owns distinct 32 cols) ---
#pragma unroll
    for (int jj = 0; jj < 2; ++jj) {
        int c = w * 32 + jj * 16 + lr;
        float s = 0.f, sq = 0.f;
#pragma unroll
        for (int i = 0; i < 4; ++i)
#pragma unroll
            for (int rg = 0; rg < 4; ++rg) {
                float v = acc[i][jj][rg];
                s += v; sq += v * v;
                ybuf[(size_t)(g0 + 16 * i + lg * 4 + rg) * CH + c] = f2b(v);
            }
        s  += __shfl_xor(s, 16, 64);  s  += __shfl_xor(s, 32, 64);
        sq += __shfl_xor(sq, 16, 64); sq += __shfl_xor(sq, 32, 64);
        if (lg == 0) {
            atomicAdd(&stats[b * CH + c], s);
            atomicAdd(&stats[B * CH + b * CH + c], sq);
        }
    }
}

// ---------------- SA gemm2 (MFMA): norm+relu(ybuf) @ W2^T, fused stats2 + k-max ----------------
// Never materializes y2: block = 2 points x 32 neighbors; writes ymax bf16 [B*N4][128].
__global__ __launch_bounds__(256) void k_sa_gemm2(
    const ushort* __restrict__ ybuf, const ushort* __restrict__ W2b,
    const float* __restrict__ stats1, float* __restrict__ stats2,
    ushort* __restrict__ ymax)
{
    __shared__ __align__(16) ushort hs[64][136];
    __shared__ float smean[128], sinv[128];
    int t = threadIdx.x;
    int g0 = blockIdx.x * 64;
    int b = g0 >> 16;
    if (t < 128) {
        float s = stats1[b * CH + t], q2 = stats1[B * CH + b * CH + t];
        float mean = s * (1.f / ROWS_PER_B);
        float var = q2 * (1.f / ROWS_PER_B) - mean * mean;
        smean[t] = mean; sinv[t] = rsqrtf(var + 1e-5f);
    }
    int r = t >> 2, q = t & 3;
    uint4 raw[4];
    {
        const uint4* src = (const uint4*)(ybuf + (size_t)(g0 + r) * CH) + q * 4;
#pragma unroll
        for (int m = 0; m < 4; ++m) raw[m] = src[m];
    }
    int l = t & 63, w = t >> 6, lr = l & 15, lg = l >> 4;
    U16 bf[4][2];
#pragma unroll
    for (int kc = 0; kc < 4; ++kc)
#pragma unroll
        for (int jj = 0; jj < 2; ++jj)
            bf[kc][jj].u = *(const uint4*)&W2b[(size_t)(w * 32 + jj * 16 + lr) * 136 + kc * 32 + lg * 8];
    __syncthreads();   // smean/sinv ready
    // normalize + relu + repack to LDS
    {
#pragma unroll
        for (int m = 0; m < 4; ++m) {
            int c0 = q * 32 + m * 8;
            ushort o[8];
            const uint* pr = (const uint*)&raw[m];
#pragma unroll
            for (int e = 0; e < 4; ++e) {
                uint v = pr[e];
                int c = c0 + e * 2;
                float f0 = bf2f((ushort)(v & 0xffff));
                float f1 = bf2f((ushort)(v >> 16));
                o[e * 2]     = f2b(fmaxf((f0 - smean[c])     * sinv[c],     0.f));
                o[e * 2 + 1] = f2b(fmaxf((f1 - smean[c + 1]) * sinv[c + 1], 0.f));
            }
            *(uint4*)&hs[r][c0] = *(uint4*)o;
        }
        if (q == 0) { uint4 z = make_uint4(0, 0, 0, 0); *(uint4*)&hs[r][128] = z; }
    }
    __syncthreads();
    f32x4 acc[4][2];
    f32x4 z4 = {0.f, 0.f, 0.f, 0.f};
#pragma unroll
    for (int i = 0; i < 4; ++i) { acc[i][0] = z4; acc[i][1] = z4; }
#pragma unroll
    for (int kc = 0; kc < 4; ++kc) {
        U16 a[4];
#pragma unroll
        for (int i = 0; i < 4; ++i) a[i].u = *(const uint4*)&hs[16 * i + lr][kc * 32 + lg * 8];
#pragma unroll
        for (int i = 0; i < 4; ++i)
#pragma unroll
            for (int jj = 0; jj < 2; ++jj)
                acc[i][jj] = __builtin_amdgcn_mfma_f32_16x16x32_bf16(a[i].s, bf[kc][jj].s, acc[i][jj], 0, 0, 0);
    }
    // epilogue: fused stats2 (pre-max) + k-max over the 32 neighbors of each of the 2 points
    int gp0 = g0 >> 5;                 // global point index of first point in tile
#pragma unroll
    for (int jj = 0; jj < 2; ++jj) {
        int c = w * 32 + jj * 16 + lr;
        float s = 0.f, sq = 0.f;
        float m0 = -3.4e38f, m1 = -3.4e38f;
#pragma unroll
        for (int i = 0; i < 4; ++i)
#pragma unroll
            for (int rg = 0; rg < 4; ++rg) {
                float v = acc[i][jj][rg];
                s += v; sq += v * v;
                if (i < 2) m0 = fmaxf(m0, v); else m1 = fmaxf(m1, v);
            }
        s  += __shfl_xor(s, 16, 64);  s  += __shfl_xor(s, 32, 64);
        sq += __shfl_xor(sq, 16, 64); sq += __shfl_xor(sq, 32, 64);
        m0 = fmaxf(m0, __shfl_xor(m0, 16, 64)); m0 = fmaxf(m0, __shfl_xor(m0, 32, 64));
        m1 = fmaxf(m1, __shfl_xor(m1, 16, 64)); m1 = fmaxf(m1, __shfl_xor(m1, 32, 64));
        if (lg == 0) {
            atomicAdd(&stats2[b * CH + c], s);
            atomicAdd(&stats2[B * CH + b * CH + c], sq);
            ymax[(size_t)gp0 * CH + c] = f2b(m0);
            ymax[(size_t)(gp0 + 1) * CH + c] = f2b(m1);
        }
    }
}

// ---------------- pass C: norm+relu on pooled maxes -> bf16 features ----------------
__global__ void k_passC2(const ushort* __restrict__ ymax, const float* __restrict__ stats,
                         ushort* __restrict__ outp)
{
    int e = blockIdx.x * 256 + threadIdx.x;    // handles 4 cols; total B*N4*32 threads
    int row = e >> 5, cq = (e & 31) * 4;
    int b = row >> 11;
    uint2 v = *(const uint2*)&ymax[(size_t)row * CH + cq];
    float f[4] = { bf2f((ushort)(v.x & 0xffff)), bf2f((ushort)(v.x >> 16)),
                   bf2f((ushort)(v.y & 0xffff)), bf2f((ushort)(v.y >> 16)) };
    uint2 o2;
    ushort o[4];
#pragma unroll
    for (int j = 0; j < 4; ++j) {
        int c = cq + j;
        float mean = stats[b * CH + c] * (1.f / ROWS_PER_B);
        float var = stats[B * CH + b * CH + c] * (1.f / ROWS_PER_B) - mean * mean;
        o[j] = f2b(fmaxf((f[j] - mean) * rsqrtf(var + 1e-5f), 0.f));
    }
    o2.x = (uint)o[0] | ((uint)o[1] << 16);
    o2.y = (uint)o[2] | ((uint)o[3] << 16);
    *(uint2*)&outp[(size_t)row * CH + cq] = o2;
}

// ---------------- FC head: relu(X@W1^T+b1) @ W2^T + b2 -> flow_lr [B,3,N4] in d_out ----------------
__global__ __launch_bounds__(256, 1) void k_fc(
    const ushort* __restrict__ X, const float* __restrict__ W1,
    const float* __restrict__ b1, const float* __restrict__ W2,
    const float* __restrict__ b2, float* __restrict__ out)
{
    __shared__ float hs[64][132];
    __shared__ float ws[128][132];
    int t = threadIdx.x;
    for (int i = t; i < 128 * 132; i += 256) {
        int dd = i / 132, c = i - dd * 132;
        ws[dd][c] = (c < 128) ? W1[dd * 128 + c] : 0.f;
    }
    int r = t >> 2, q = t & 3;
    int g0 = blockIdx.x * 64;
    {
        const uint4* Xrow = (const uint4*)(X + (size_t)(g0 + r) * CH + q * 32);
#pragma unroll
        for (int m = 0; m < 4; ++m) {
            uint4 v = Xrow[m];
            const uint* pv = (const uint*)&v;
            int c0 = q * 32 + m * 8;
#pragma unroll
            for (int e = 0; e < 4; ++e) {
                hs[r][c0 + 2 * e]     = bf2f((ushort)(pv[e] & 0xffff));
                hs[r][c0 + 2 * e + 1] = bf2f((ushort)(pv[e] >> 16));
            }
        }
        if (q == 0) *(float4*)&hs[r][128] = make_float4(0.f, 0.f, 0.f, 0.f);
    }
    __syncthreads();
    int tx = t & 15, ty = t >> 4;
    float acc[4][8];
#pragma unroll
    for (int i = 0; i < 4; ++i)
#pragma unroll
        for (int jj = 0; jj < 8; ++jj) acc[i][jj] = 0.f;
    for (int kb = 0; kb < 33; ++kb) {
        float4 a[4]; float4 w[8];
#pragma unroll
        for (int i = 0; i < 4; ++i) a[i] = *(float4*)&hs[ty * 4 + i][kb * 4];
#pragma unroll
        for (int jj = 0; jj < 8; ++jj) w[jj] = *(float4*)&ws[tx + 16 * jj][kb * 4];
#pragma unroll
        for (int i = 0; i < 4; ++i)
#pragma unroll
            for (int jj = 0; jj < 8; ++jj)
                acc[i][jj] += a[i].x * w[jj].x + a[i].y * w[jj].y
                            + a[i].z * w[jj].z + a[i].w * w[jj].w;
    }
    __syncthreads();                     // done reading hs
#pragma unroll
    for (int jj = 0; jj < 8; ++jj) {
        int c = tx + 16 * jj;
        float bias = b1[c];
#pragma unroll
        for (int i = 0; i < 4; ++i)
            hs[ty * 4 + i][c] = fmaxf(acc[i][jj] + bias, 0.f);
    }
    __syncthreads();
    if (t < 192) {
        int rr = t / 3, o = t - rr * 3;
        float sum = b2[o];
        for (int c = 0; c < 128; ++c) sum += hs[rr][c] * W2[o * 128 + c];
        int g = g0 + rr;
        int b = g >> 11, n = g & (N4 - 1);
        out[FLOWLR_OFF + ((size_t)b * 3 + o) * N4 + n] = sum;
    }
}

// ---------------- feature propagation: 3-NN inverse-sqdist interp onto xyz1 ----------------
__global__ __launch_bounds__(256) void k_fp(
    const float* __restrict__ xyz_s1, const float* __restrict__ xyz4,
    float* __restrict__ out)
{
    __shared__ float pts[N4 * 3];
    int b = blockIdx.x >> 5;             // 32 blocks per batch
    int i = (blockIdx.x & 31) * 256 + threadIdx.x;
    for (int idx2 = threadIdx.x; idx2 < N4 * 3; idx2 += 256) pts[idx2] = xyz4[(size_t)b * N4 * 3 + idx2];
    __syncthreads();
    float qx = xyz_s1[((size_t)b * 3 + 0) * N1 + i];
    float qy = xyz_s1[((size_t)b * 3 + 1) * N1 + i];
    float qz = xyz_s1[((size_t)b * 3 + 2) * N1 + i];
    float d0 = 3.4e38f, d1 = 3.4e38f, d2 = 3.4e38f;
    int i0 = 0, i1 = 0, i2 = 0;
    for (int n = 0; n < N4; ++n) {
        float dx = pts[n * 3 + 0] - qx;
        float dy = pts[n * 3 + 1] - qy;
        float dz = pts[n * 3 + 2] - qz;
        float dd = dx * dx + dy * dy + dz * dz;
        if (dd < d2) {
            if (dd < d1) {
                if (dd < d0) { d2 = d1; i2 = i1; d1 = d0; i1 = i0; d0 = dd; i0 = n; }
                else         { d2 = d1; i2 = i1; d1 = dd; i1 = n; }
            } else           { d2 = dd; i2 = n; }
        }
    }
    float w0 = 1.f / (d0 + 1e-8f), w1 = 1.f / (d1 + 1e-8f), w2 = 1.f / (d2 + 1e-8f);
    float inv = 1.f / (w0 + w1 + w2);
    const float* flr = out + FLOWLR_OFF + (size_t)b * 3 * N4;
#pragma unroll
    for (int dmn = 0; dmn < 3; ++dmn) {
        float v = (w0 * flr[dmn * N4 + i0] + w1 * flr[dmn * N4 + i1] + w2 * flr[dmn * N4 + i2]) * inv;
        out[((size_t)b * 3 + dmn) * N1 + i] = v;
    }
}

extern "C" void kernel_launch(void* const* d_in, const int* in_sizes, int n_in,
                              void* d_out, int out_size, void* d_ws, size_t ws_size,
                              hipStream_t stream) {
    const float* xyz_s1 = (const float*)d_in[0];
    const float* xyz_s4 = (const float*)d_in[1];
    const float* feats  = (const float*)d_in[2];
    const float* sa1_W1 = (const float*)d_in[3];
    const float* sa1_W2 = (const float*)d_in[5];
    const float* sa2_W1 = (const float*)d_in[7];
    const float* sa2_W2 = (const float*)d_in[9];
    const float* fc_W1  = (const float*)d_in[11];
    const float* fc_b1  = (const float*)d_in[12];
    const float* fc_W2  = (const float*)d_in[13];
    const float* fc_b2  = (const float*)d_in[14];
    float* out = (float*)d_out;

    // workspace layout (stays within the round-1-proven 153.3 MB footprint)
    char* wsb = (char*)d_ws;
    float*  xyz4   = (float*)(wsb + 0);                  // 196608 B
    int*    idx    = (int*)(wsb + 196608);               // 2 MB   -> 2293760
    ushort* featTb = (ushort*)(wsb + 2293760);           // 4 MB   -> 6488064   (feats transposed bf16)
    ushort* ymax   = (ushort*)(wsb + 2293760);           // ALIAS: featTb dead after gemm1-SA1
    ushort* featB  = (ushort*)(wsb + 6488064);           // 4 MB   -> 10682368  (SA1 output)
    ushort* featC  = (ushort*)(wsb + 10682368);          // 4 MB   -> 14876672  (SA2 output)
    ushort* W1b1   = (ushort*)(wsb + 14876672);          // 64 KB  -> 14942208
    ushort* W1b2   = (ushort*)(wsb + 14942208);          // 64 KB  -> 15007744
    ushort* W2b1   = (ushort*)(wsb + 15007744);          // 64 KB  -> 15073280
    ushort* W2b2   = (ushort*)(wsb + 15073280);          // 64 KB  -> 15138816
    float*  statsA = (float*)(wsb + 15138816);           // 8 KB each x4
    float*  statsB = (float*)(wsb + 15147008);
    float*  statsC = (float*)(wsb + 15155200);
    float*  statsD = (float*)(wsb + 15163392);
    ushort* ybuf   = (ushort*)(wsb + 19079168);          // 128 MB -> 153296896

    // ---- setup ----
    k_xyz_t<<<64, 256, 0, stream>>>(xyz_s4, xyz4);
    dim3 gt(B, N4 / 32, CH / 32), bt(32, 8);
    k_feat_t<<<gt, bt, 0, stream>>>(feats, featTb);
    k_knn<<<B * (N4 / 4), 256, 0, stream>>>(xyz4, idx);
    k_wconv<<<84, 256, 0, stream>>>(sa1_W1, W1b1, 0);
    k_wconv<<<84, 256, 0, stream>>>(sa2_W1, W1b2, 0);
    k_wconv<<<68, 256, 0, stream>>>(sa1_W2, W2b1, 1);
    k_wconv<<<68, 256, 0, stream>>>(sa2_W2, W2b2, 1);
    hipMemsetAsync(statsA, 0, 4 * 2 * B * CH * sizeof(float), stream);

    // ---- SA1 ----
    k_sa_gemm1<<<ROWS_TOTAL / 64, 256, 0, stream>>>(featTb, xyz4, idx, W1b1, ybuf, statsA);
    k_sa_gemm2<<<ROWS_TOTAL / 64, 256, 0, stream>>>(ybuf, W2b1, statsA, statsB, ymax);
    k_passC2<<<(B * N4 * 32) / 256, 256, 0, stream>>>(ymax, statsB, featB);

    // ---- SA2 ----
    k_sa_gemm1<<<ROWS_TOTAL / 64, 256, 0, stream>>>(featB, xyz4, idx, W1b2, ybuf, statsC);
    k_sa_gemm2<<<ROWS_TOTAL / 64, 256, 0, stream>>>(ybuf, W2b2, statsC, statsD, ymax);
    k_passC2<<<(B * N4 * 32) / 256, 256, 0, stream>>>(ymax, statsD, featC);

    // ---- FC head + flow_lr ----
    k_fc<<<(B * N4) / 64, 256, 0, stream>>>(featC, fc_W1, fc_b1, fc_W2, fc_b2, out);
    // ---- feature propagation -> flow ----
    k_fp<<<B * (N1 / 256), 256, 0, stream>>>(xyz_s1, xyz4, out);
}

// Round 4
// 712.883 us; speedup vs baseline: 4.9550x; 1.2321x over previous
//
#include <hip/hip_runtime.h>
#include <hip/hip_bf16.h>

#define B 8
#define N1 8192
#define N4 2048
#define CH 128
#define KNN 32
#define ROWS_PER_B (N4 * KNN)          // 65536 rows per batch in the [B,N,K] flattening
#define ROWS_TOTAL (B * ROWS_PER_B)    // 524288
#define FLOWLR_OFF (B * 3 * N1)        // flow_lr starts after flow in d_out

typedef unsigned int uint;
typedef unsigned short ushort;
typedef __attribute__((ext_vector_type(8))) short short8;
typedef __attribute__((ext_vector_type(4))) float f32x4;

union U16 { uint4 u; short8 s; };

__device__ __forceinline__ float bf2f(ushort u) {
    union { uint i; float f; } v; v.i = ((uint)u) << 16; return v.f;
}
__device__ __forceinline__ ushort f2b(float f) {
    __hip_bfloat16 h = __float2bfloat16(f);
    return *(ushort*)&h;
}

// ---------------- setup: transpose xyz_s4 [B,3,N4] -> xyz4 [B,N4,3] ----------------
__global__ void k_xyz_t(const float* __restrict__ xyz_s4, float* __restrict__ xyz4) {
    int g = blockIdx.x * 256 + threadIdx.x;
    if (g >= B * N4) return;
    int b = g >> 11, n = g & (N4 - 1);
    float x = xyz_s4[(b * 3 + 0) * N4 + n];
    float y = xyz_s4[(b * 3 + 1) * N4 + n];
    float z = xyz_s4[(b * 3 + 2) * N4 + n];
    xyz4[g * 3 + 0] = x; xyz4[g * 3 + 1] = y; xyz4[g * 3 + 2] = z;
}

// ---------------- transpose feats [B,C,N4] fp32 -> featTb [B,N4,C] bf16 ----------------
__global__ void k_feat_t(const float* __restrict__ feats, ushort* __restrict__ featTb) {
    __shared__ float tile[32][33];
    int b = blockIdx.x, nb = blockIdx.y, cb = blockIdx.z;
    int tx = threadIdx.x, ty = threadIdx.y; // 32 x 8
    int n0 = nb * 32, c0 = cb * 32;
#pragma unroll
    for (int i = 0; i < 4; ++i) {
        int c = c0 + ty + 8 * i;
        tile[ty + 8 * i][tx] = feats[((size_t)b * CH + c) * N4 + n0 + tx];
    }
    __syncthreads();
#pragma unroll
    for (int i = 0; i < 4; ++i) {
        int n = n0 + ty + 8 * i;
        featTb[((size_t)b * N4 + n) * CH + c0 + tx] = f2b(tile[tx][ty + 8 * i]);
    }
}

// ---------------- W converters: fp32 -> bf16, permuted/padded ----------------
__global__ void k_wconv(const float* __restrict__ W, ushort* __restrict__ Wb, int mode) {
    int i = blockIdx.x * 256 + threadIdx.x;
    if (mode == 0) {
        if (i >= 128 * 168) return;
        int d = i / 168, c = i - d * 168;
        float v = 0.f;
        if (c < 128)      v = W[d * 131 + 3 + c];
        else if (c < 131) v = W[d * 131 + (c - 128)];
        Wb[i] = f2b(v);
    } else {
        if (i >= 128 * 136) return;
        int d = i / 136, c = i - d * 136;
        Wb[i] = (c < 128) ? f2b(W[d * 128 + c]) : (ushort)0;
    }
}

// ---------------- KNN: 32 nearest (incl self) among the 2048 points of each batch ----------------
__global__ __launch_bounds__(256) void k_knn(const float* __restrict__ xyz4, int* __restrict__ idxout) {
    __shared__ float pts[N4 * 3];
    int b = blockIdx.x >> 9;            // 512 blocks per batch
    int qbase = (blockIdx.x & 511) * 4;
    for (int i = threadIdx.x; i < N4 * 3; i += 256) pts[i] = xyz4[(size_t)b * N4 * 3 + i];
    __syncthreads();
    int wave = threadIdx.x >> 6, lane = threadIdx.x & 63;
    int qn = qbase + wave;
    float qx = pts[qn * 3 + 0], qy = pts[qn * 3 + 1], qz = pts[qn * 3 + 2];
    float d[32];
#pragma unroll
    for (int t = 0; t < 32; ++t) {
        int c = t * 64 + lane;
        float dx = pts[c * 3 + 0] - qx;
        float dy = pts[c * 3 + 1] - qy;
        float dz = pts[c * 3 + 2] - qz;
        d[t] = dx * dx + dy * dy + dz * dz;
    }
    int outbase = (b * N4 + qn) * KNN;
    for (int e = 0; e < KNN; ++e) {
        float lv = 3.4e38f; int li = 0x7fffffff;
#pragma unroll
        for (int t = 0; t < 32; ++t) {
            int ci = t * 64 + lane;
            if (d[t] < lv) { lv = d[t]; li = ci; }
        }
#pragma unroll
        for (int m = 1; m < 64; m <<= 1) {
            float ov = __shfl_xor(lv, m, 64);
            int   oi = __shfl_xor(li, m, 64);
            if (ov < lv || (ov == lv && oi < li)) { lv = ov; li = oi; }
        }
        if (lane == 0) idxout[outbase + e] = li;
        if ((li & 63) == lane) {
            int tt = li >> 6;
#pragma unroll
            for (int t = 0; t < 32; ++t) if (t == tt) d[t] = 3.4e38f;
        }
    }
}

// ---------------- SA gemm1 (MFMA): gather + h@W1^T -> ybuf bf16, fused per-(b,c) stats ----------------
// h-row K layout: [feat(128) | gxyz(3) | 0 pad] = 168 (5 chunks of 32, padded)
// SA biases are dropped: InstanceNorm is invariant to per-channel constant shifts.
__global__ __launch_bounds__(256) void k_sa_gemm1(
    const ushort* __restrict__ Fb, const float* __restrict__ xyz4,
    const int* __restrict__ idx, const ushort* __restrict__ W1b,
    ushort* __restrict__ ybuf, float* __restrict__ stats)
{
    __shared__ __align__(16) ushort hs[64][168];
    int t = threadIdx.x;
    int g0 = blockIdx.x * 64;
    int b = g0 >> 16;
    // --- stage gathered rows (bf16 direct copy) ---
    int r = t >> 2, q = t & 3;
    {
        int g = g0 + r;
        int n = (g & 65535) >> 5;
        int j = idx[g];
        const uint4* src = (const uint4*)(Fb + ((size_t)(b * N4 + j)) * CH) + q * 4;
        uint4* dst = (uint4*)&hs[r][q * 32];
#pragma unroll
        for (int m = 0; m < 4; ++m) dst[m] = src[m];
        uint4 z = make_uint4(0, 0, 0, 0);
        *(uint4*)&hs[r][128 + q * 8] = z;          // zero cols 128..159
        if (q == 0) {
            *(uint4*)&hs[r][160] = z;              // zero cols 160..167
            const float* pj = xyz4 + (size_t)(b * N4 + j) * 3;
            const float* pn = xyz4 + (size_t)(b * N4 + n) * 3;
            hs[r][128] = f2b(pj[0] - pn[0]);
            hs[r][129] = f2b(pj[1] - pn[1]);
            hs[r][130] = f2b(pj[2] - pn[2]);
        }
    }
    // --- W fragments to registers (per-wave 32-col slab), overlap with staging ---
    int l = t & 63, w = t >> 6;
    int lr = l & 15, lg = l >> 4;
    U16 bf[5][2];
#pragma unroll
    for (int kc = 0; kc < 5; ++kc)
#pragma unroll
        for (int jj = 0; jj < 2; ++jj)
            bf[kc][jj].u = *(const uint4*)&W1b[(size_t)(w * 32 + jj * 16 + lr) * 168 + kc * 32 + lg * 8];
    __syncthreads();
    f32x4 acc[4][2];
    f32x4 z4 = {0.f, 0.f, 0.f, 0.f};
#pragma unroll
    for (int i = 0; i < 4; ++i) { acc[i][0] = z4; acc[i][1] = z4; }
#pragma unroll
    for (int kc = 0; kc < 5; ++kc) {
        U16 a[4];
#pragma unroll
        for (int i = 0; i < 4; ++i) a[i].u = *(const uint4*)&hs[16 * i + lr][kc * 32 + lg * 8];
#pragma unroll
        for (int i = 0; i < 4; ++i)
#pragma unroll
            for (int jj = 0; jj < 2; ++jj)
                acc[i][jj] = __builtin_amdgcn_mfma_f32_16x16x32_bf16(a[i].s, bf[kc][jj].s, acc[i][jj], 0, 0, 0);
    }
    __syncthreads();   // hs reads complete -> reuse hs as bf16 repack buffer
    // --- epilogue: fused stats + LDS repack of the C tile (2B LDS writes are ~free; the
    //     old path's 64 scattered 2-byte global stores were partial-cacheline writes) ---
#pragma unroll
    for (int jj = 0; jj < 2; ++jj) {
        int c = w * 32 + jj * 16 + lr;
        float s = 0.f, sq = 0.f;
#pragma unroll
        for (int i = 0; i < 4; ++i)
#pragma unroll
            for (int rg = 0; rg < 4; ++rg) {
                float v = acc[i][jj][rg];
                s += v; sq += v * v;
                hs[16 * i + lg * 4 + rg][c] = f2b(v);
            }
        s  += __shfl_xor(s, 16, 64);  s  += __shfl_xor(s, 32, 64);
        sq += __shfl_xor(sq, 16, 64); sq += __shfl_xor(sq, 32, 64);
        if (lg == 0) {
            atomicAdd(&stats[b * CH + c], s);
            atomicAdd(&stats[B * CH + b * CH + c], sq);
        }
    }
    __syncthreads();
    // --- coalesced writeout: thread -> (row r, 32-col chunk q) as 4x uint4 ---
    {
        uint4* dst = (uint4*)(ybuf + (size_t)(g0 + r) * CH + q * 32);
#pragma unroll
        for (int m = 0; m < 4; ++m) dst[m] = *(const uint4*)&hs[r][q * 32 + m * 8];
    }
}

// ---------------- SA gemm2 (MFMA): norm+relu(ybuf) @ W2^T, fused stats2 + k-max ----------------
// Never materializes y2: block = 2 points x 32 neighbors; writes ymax bf16 [B*N4][128].
__global__ __launch_bounds__(256) void k_sa_gemm2(
    const ushort* __restrict__ ybuf, const ushort* __restrict__ W2b,
    const float* __restrict__ stats1, float* __restrict__ stats2,
    ushort* __restrict__ ymax)
{
    __shared__ __align__(16) ushort hs[64][136];
    __shared__ float smean[128], sinv[128];
    int t = threadIdx.x;
    int g0 = blockIdx.x * 64;
    int b = g0 >> 16;
    if (t < 128) {
        float s = stats1[b * CH + t], q2 = stats1[B * CH + b * CH + t];
        float mean = s * (1.f / ROWS_PER_B);
        float var = q2 * (1.f / ROWS_PER_B) - mean * mean;
        smean[t] = mean; sinv[t] = rsqrtf(var + 1e-5f);
    }
    int r = t >> 2, q = t & 3;
    uint4 raw[4];
    {
        const uint4* src = (const uint4*)(ybuf + (size_t)(g0 + r) * CH) + q * 4;
#pragma unroll
        for (int m = 0; m < 4; ++m) raw[m] = src[m];
    }
    int l = t & 63, w = t >> 6, lr = l & 15, lg = l >> 4;
    U16 bf[4][2];
#pragma unroll
    for (int kc = 0; kc < 4; ++kc)
#pragma unroll
        for (int jj = 0; jj < 2; ++jj)
            bf[kc][jj].u = *(const uint4*)&W2b[(size_t)(w * 32 + jj * 16 + lr) * 136 + kc * 32 + lg * 8];
    __syncthreads();   // smean/sinv ready
    // normalize + relu + repack to LDS
    {
#pragma unroll
        for (int m = 0; m < 4; ++m) {
            int c0 = q * 32 + m * 8;
            ushort o[8];
            const uint* pr = (const uint*)&raw[m];
#pragma unroll
            for (int e = 0; e < 4; ++e) {
                uint v = pr[e];
                int c = c0 + e * 2;
                float f0 = bf2f((ushort)(v & 0xffff));
                float f1 = bf2f((ushort)(v >> 16));
                o[e * 2]     = f2b(fmaxf((f0 - smean[c])     * sinv[c],     0.f));
                o[e * 2 + 1] = f2b(fmaxf((f1 - smean[c + 1]) * sinv[c + 1], 0.f));
            }
            *(uint4*)&hs[r][c0] = *(uint4*)o;
        }
        if (q == 0) { uint4 z = make_uint4(0, 0, 0, 0); *(uint4*)&hs[r][128] = z; }
    }
    __syncthreads();
    f32x4 acc[4][2];
    f32x4 z4 = {0.f, 0.f, 0.f, 0.f};
#pragma unroll
    for (int i = 0; i < 4; ++i) { acc[i][0] = z4; acc[i][1] = z4; }
#pragma unroll
    for (int kc = 0; kc < 4; ++kc) {
        U16 a[4];
#pragma unroll
        for (int i = 0; i < 4; ++i) a[i].u = *(const uint4*)&hs[16 * i + lr][kc * 32 + lg * 8];
#pragma unroll
        for (int i = 0; i < 4; ++i)
#pragma unroll
            for (int jj = 0; jj < 2; ++jj)
                acc[i][jj] = __builtin_amdgcn_mfma_f32_16x16x32_bf16(a[i].s, bf[kc][jj].s, acc[i][jj], 0, 0, 0);
    }
    // epilogue: fused stats2 (pre-max) + k-max over the 32 neighbors of each of the 2 points
    int gp0 = g0 >> 5;                 // global point index of first point in tile
#pragma unroll
    for (int jj = 0; jj < 2; ++jj) {
        int c = w * 32 + jj * 16 + lr;
        float s = 0.f, sq = 0.f;
        float m0 = -3.4e38f, m1 = -3.4e38f;
#pragma unroll
        for (int i = 0; i < 4; ++i)
#pragma unroll
            for (int rg = 0; rg < 4; ++rg) {
                float v = acc[i][jj][rg];
                s += v; sq += v * v;
                if (i < 2) m0 = fmaxf(m0, v); else m1 = fmaxf(m1, v);
            }
        s  += __shfl_xor(s, 16, 64);  s  += __shfl_xor(s, 32, 64);
        sq += __shfl_xor(sq, 16, 64); sq += __shfl_xor(sq, 32, 64);
        m0 = fmaxf(m0, __shfl_xor(m0, 16, 64)); m0 = fmaxf(m0, __shfl_xor(m0, 32, 64));
        m1 = fmaxf(m1, __shfl_xor(m1, 16, 64)); m1 = fmaxf(m1, __shfl_xor(m1, 32, 64));
        if (lg == 0) {
            atomicAdd(&stats2[b * CH + c], s);
            atomicAdd(&stats2[B * CH + b * CH + c], sq);
            ymax[(size_t)gp0 * CH + c] = f2b(m0);
            ymax[(size_t)(gp0 + 1) * CH + c] = f2b(m1);
        }
    }
}

// ---------------- pass C: norm+relu on pooled maxes -> bf16 features ----------------
__global__ void k_passC2(const ushort* __restrict__ ymax, const float* __restrict__ stats,
                         ushort* __restrict__ outp)
{
    int e = blockIdx.x * 256 + threadIdx.x;    // handles 4 cols; total B*N4*32 threads
    int row = e >> 5, cq = (e & 31) * 4;
    int b = row >> 11;
    uint2 v = *(const uint2*)&ymax[(size_t)row * CH + cq];
    float f[4] = { bf2f((ushort)(v.x & 0xffff)), bf2f((ushort)(v.x >> 16)),
                   bf2f((ushort)(v.y & 0xffff)), bf2f((ushort)(v.y >> 16)) };
    uint2 o2;
    ushort o[4];
#pragma unroll
    for (int j = 0; j < 4; ++j) {
        int c = cq + j;
        float mean = stats[b * CH + c] * (1.f / ROWS_PER_B);
        float var = stats[B * CH + b * CH + c] * (1.f / ROWS_PER_B) - mean * mean;
        o[j] = f2b(fmaxf((f[j] - mean) * rsqrtf(var + 1e-5f), 0.f));
    }
    o2.x = (uint)o[0] | ((uint)o[1] << 16);
    o2.y = (uint)o[2] | ((uint)o[3] << 16);
    *(uint2*)&outp[(size_t)row * CH + cq] = o2;
}

// ---------------- FC head: relu(X@W1^T+b1) @ W2^T + b2 -> flow_lr [B,3,N4] in d_out ----------------
__global__ __launch_bounds__(256, 1) void k_fc(
    const ushort* __restrict__ X, const float* __restrict__ W1,
    const float* __restrict__ b1, const float* __restrict__ W2,
    const float* __restrict__ b2, float* __restrict__ out)
{
    __shared__ float hs[64][132];
    __shared__ float ws[128][132];
    int t = threadIdx.x;
    for (int i = t; i < 128 * 132; i += 256) {
        int dd = i / 132, c = i - dd * 132;
        ws[dd][c] = (c < 128) ? W1[dd * 128 + c] : 0.f;
    }
    int r = t >> 2, q = t & 3;
    int g0 = blockIdx.x * 64;
    {
        const uint4* Xrow = (const uint4*)(X + (size_t)(g0 + r) * CH + q * 32);
#pragma unroll
        for (int m = 0; m < 4; ++m) {
            uint4 v = Xrow[m];
            const uint* pv = (const uint*)&v;
            int c0 = q * 32 + m * 8;
#pragma unroll
            for (int e = 0; e < 4; ++e) {
                hs[r][c0 + 2 * e]     = bf2f((ushort)(pv[e] & 0xffff));
                hs[r][c0 + 2 * e + 1] = bf2f((ushort)(pv[e] >> 16));
            }
        }
        if (q == 0) *(float4*)&hs[r][128] = make_float4(0.f, 0.f, 0.f, 0.f);
    }
    __syncthreads();
    int tx = t & 15, ty = t >> 4;
    float acc[4][8];
#pragma unroll
    for (int i = 0; i < 4; ++i)
#pragma unroll
        for (int jj = 0; jj < 8; ++jj) acc[i][jj] = 0.f;
    for (int kb = 0; kb < 33; ++kb) {
        float4 a[4]; float4 w[8];
#pragma unroll
        for (int i = 0; i < 4; ++i) a[i] = *(float4*)&hs[ty * 4 + i][kb * 4];
#pragma unroll
        for (int jj = 0; jj < 8; ++jj) w[jj] = *(float4*)&ws[tx + 16 * jj][kb * 4];
#pragma unroll
        for (int i = 0; i < 4; ++i)
#pragma unroll
            for (int jj = 0; jj < 8; ++jj)
                acc[i][jj] += a[i].x * w[jj].x + a[i].y * w[jj].y
                            + a[i].z * w[jj].z + a[i].w * w[jj].w;
    }
    __syncthreads();                     // done reading hs
#pragma unroll
    for (int jj = 0; jj < 8; ++jj) {
        int c = tx + 16 * jj;
        float bias = b1[c];
#pragma unroll
        for (int i = 0; i < 4; ++i)
            hs[ty * 4 + i][c] = fmaxf(acc[i][jj] + bias, 0.f);
    }
    __syncthreads();
    if (t < 192) {
        int rr = t / 3, o = t - rr * 3;
        float sum = b2[o];
        for (int c = 0; c < 128; ++c) sum += hs[rr][c] * W2[o * 128 + c];
        int g = g0 + rr;
        int b = g >> 11, n = g & (N4 - 1);
        out[FLOWLR_OFF + ((size_t)b * 3 + o) * N4 + n] = sum;
    }
}

// ---------------- feature propagation: 3-NN inverse-sqdist interp onto xyz1 ----------------
// 4 threads per query, each scanning a 512-point chunk; lexicographic (d,idx) shfl merge.
// GRID: B * (N1/64) = 1024 blocks (64 queries per block).
__global__ __launch_bounds__(256) void k_fp(
    const float* __restrict__ xyz_s1, const float* __restrict__ xyz4,
    float* __restrict__ out)
{
    __shared__ float xs[4 * 528], ys[4 * 528], zs[4 * 528];   // chunk c at c*528 (pad kills bank aliasing)
    int b = blockIdx.x >> 7;             // 128 blocks per batch
    int q0 = (blockIdx.x & 127) * 64;
    int t = threadIdx.x;
    for (int i = t; i < N4; i += 256) {
        int p = (i >> 9) * 528 + (i & 511);
        const float* s = xyz4 + (size_t)b * N4 * 3 + (size_t)i * 3;
        xs[p] = s[0]; ys[p] = s[1]; zs[p] = s[2];
    }
    __syncthreads();
    int q = q0 + (t >> 2), c = t & 3;
    float qx = xyz_s1[((size_t)b * 3 + 0) * N1 + q];
    float qy = xyz_s1[((size_t)b * 3 + 1) * N1 + q];
    float qz = xyz_s1[((size_t)b * 3 + 2) * N1 + q];
    float d0 = 3.4e38f, d1 = 3.4e38f, d2 = 3.4e38f;
    int i0 = 0, i1 = 0, i2 = 0;
    int base = c * 528, nb = c * 512;
    for (int ii = 0; ii < 512; ii += 4) {
        float4 x4 = *(float4*)&xs[base + ii];
        float4 y4 = *(float4*)&ys[base + ii];
        float4 z4 = *(float4*)&zs[base + ii];
#pragma unroll
        for (int j = 0; j < 4; ++j) {
            float dx = ((const float*)&x4)[j] - qx;
            float dy = ((const float*)&y4)[j] - qy;
            float dz = ((const float*)&z4)[j] - qz;
            float dd = dx * dx + dy * dy + dz * dz;
            if (dd < d2) {               // strict < is tie-correct for ascending index scan
                int n = nb + ii + j;
                if (dd < d0)      { d2 = d1; i2 = i1; d1 = d0; i1 = i0; d0 = dd; i0 = n; }
                else if (dd < d1) { d2 = d1; i2 = i1; d1 = dd; i1 = n; }
                else              { d2 = dd; i2 = n; }
            }
        }
    }
    // merge the 4 chunk-local top-3 lists (lexicographic (d, idx) insertion)
#pragma unroll
    for (int m = 1; m <= 2; m <<= 1) {
        float e0 = __shfl_xor(d0, m, 64), e1 = __shfl_xor(d1, m, 64), e2 = __shfl_xor(d2, m, 64);
        int   j0 = __shfl_xor(i0, m, 64), j1 = __shfl_xor(i1, m, 64), j2 = __shfl_xor(i2, m, 64);
        float ed[3] = { e0, e1, e2 }; int ej[3] = { j0, j1, j2 };
#pragma unroll
        for (int s = 0; s < 3; ++s) {
            float dd = ed[s]; int jn = ej[s];
            bool lt2 = dd < d2 || (dd == d2 && jn < i2);
            if (lt2) {
                bool lt0 = dd < d0 || (dd == d0 && jn < i0);
                bool lt1 = dd < d1 || (dd == d1 && jn < i1);
                if (lt0)      { d2 = d1; i2 = i1; d1 = d0; i1 = i0; d0 = dd; i0 = jn; }
                else if (lt1) { d2 = d1; i2 = i1; d1 = dd; i1 = jn; }
                else          { d2 = dd; i2 = jn; }
            }
        }
    }
    float w0 = 1.f / (d0 + 1e-8f), w1 = 1.f / (d1 + 1e-8f), w2 = 1.f / (d2 + 1e-8f);
    float inv = 1.f / (w0 + w1 + w2);
    const float* flr = out + FLOWLR_OFF + (size_t)b * 3 * N4;
    if (c < 3) {
        float v = (w0 * flr[c * N4 + i0] + w1 * flr[c * N4 + i1] + w2 * flr[c * N4 + i2]) * inv;
        out[((size_t)b * 3 + c) * N1 + q] = v;
    }
}

extern "C" void kernel_launch(void* const* d_in, const int* in_sizes, int n_in,
                              void* d_out, int out_size, void* d_ws, size_t ws_size,
                              hipStream_t stream) {
    const float* xyz_s1 = (const float*)d_in[0];
    const float* xyz_s4 = (const float*)d_in[1];
    const float* feats  = (const float*)d_in[2];
    const float* sa1_W1 = (const float*)d_in[3];
    const float* sa1_W2 = (const float*)d_in[5];
    const float* sa2_W1 = (const float*)d_in[7];
    const float* sa2_W2 = (const float*)d_in[9];
    const float* fc_W1  = (const float*)d_in[11];
    const float* fc_b1  = (const float*)d_in[12];
    const float* fc_W2  = (const float*)d_in[13];
    const float* fc_b2  = (const float*)d_in[14];
    float* out = (float*)d_out;

    // workspace layout (stays within the round-1-proven 153.3 MB footprint)
    char* wsb = (char*)d_ws;
    float*  xyz4   = (float*)(wsb + 0);                  // 196608 B
    int*    idx    = (int*)(wsb + 196608);               // 2 MB   -> 2293760
    ushort* featTb = (ushort*)(wsb + 2293760);           // 4 MB   -> 6488064   (feats transposed bf16)
    ushort* ymax   = (ushort*)(wsb + 2293760);           // ALIAS: featTb dead after gemm1-SA1
    ushort* featB  = (ushort*)(wsb + 6488064);           // 4 MB   -> 10682368  (SA1 output)
    ushort* featC  = (ushort*)(wsb + 10682368);          // 4 MB   -> 14876672  (SA2 output)
    ushort* W1b1   = (ushort*)(wsb + 14876672);          // 64 KB  -> 14942208
    ushort* W1b2   = (ushort*)(wsb + 14942208);          // 64 KB  -> 15007744
    ushort* W2b1   = (ushort*)(wsb + 15007744);          // 64 KB  -> 15073280
    ushort* W2b2   = (ushort*)(wsb + 15073280);          // 64 KB  -> 15138816
    float*  statsA = (float*)(wsb + 15138816);           // 8 KB each x4
    float*  statsB = (float*)(wsb + 15147008);
    float*  statsC = (float*)(wsb + 15155200);
    float*  statsD = (float*)(wsb + 15163392);
    ushort* ybuf   = (ushort*)(wsb + 19079168);          // 128 MB -> 153296896

    // ---- setup ----
    k_xyz_t<<<64, 256, 0, stream>>>(xyz_s4, xyz4);
    dim3 gt(B, N4 / 32, CH / 32), bt(32, 8);
    k_feat_t<<<gt, bt, 0, stream>>>(feats, featTb);
    k_knn<<<B * (N4 / 4), 256, 0, stream>>>(xyz4, idx);
    k_wconv<<<84, 256, 0, stream>>>(sa1_W1, W1b1, 0);
    k_wconv<<<84, 256, 0, stream>>>(sa2_W1, W1b2, 0);
    k_wconv<<<68, 256, 0, stream>>>(sa1_W2, W2b1, 1);
    k_wconv<<<68, 256, 0, stream>>>(sa2_W2, W2b2, 1);
    hipMemsetAsync(statsA, 0, 4 * 2 * B * CH * sizeof(float), stream);

    // ---- SA1 ----
    k_sa_gemm1<<<ROWS_TOTAL / 64, 256, 0, stream>>>(featTb, xyz4, idx, W1b1, ybuf, statsA);
    k_sa_gemm2<<<ROWS_TOTAL / 64, 256, 0, stream>>>(ybuf, W2b1, statsA, statsB, ymax);
    k_passC2<<<(B * N4 * 32) / 256, 256, 0, stream>>>(ymax, statsB, featB);

    // ---- SA2 ----
    k_sa_gemm1<<<ROWS_TOTAL / 64, 256, 0, stream>>>(featB, xyz4, idx, W1b2, ybuf, statsC);
    k_sa_gemm2<<<ROWS_TOTAL / 64, 256, 0, stream>>>(ybuf, W2b2, statsC, statsD, ymax);
    k_passC2<<<(B * N4 * 32) / 256, 256, 0, stream>>>(ymax, statsD, featC);

    // ---- FC head + flow_lr ----
    k_fc<<<(B * N4) / 64, 256, 0, stream>>>(featC, fc_W1, fc_b1, fc_W2, fc_b2, out);
    // ---- feature propagation -> flow (1024 blocks: 64 queries/block x 4 threads each) ----
    k_fp<<<B * (N1 / 64), 256, 0, stream>>>(xyz_s1, xyz4, out);
}

// Round 5
// 662.009 us; speedup vs baseline: 5.3358x; 1.0768x over previous
//
#include <hip/hip_runtime.h>
#include <hip/hip_bf16.h>

#define B 8
#define N1 8192
#define N4 2048
#define CH 128
#define KNN 32
#define ROWS_PER_B (N4 * KNN)          // 65536 rows per batch in the [B,N,K] flattening
#define ROWS_TOTAL (B * ROWS_PER_B)    // 524288
#define FLOWLR_OFF (B * 3 * N1)        // flow_lr starts after flow in d_out

typedef unsigned int uint;
typedef unsigned short ushort;
typedef __attribute__((ext_vector_type(8))) short short8;
typedef __attribute__((ext_vector_type(4))) float f32x4;

union U16 { uint4 u; short8 s; };

__device__ __forceinline__ float bf2f(ushort u) {
    union { uint i; float f; } v; v.i = ((uint)u) << 16; return v.f;
}
__device__ __forceinline__ ushort f2b(float f) {
    __hip_bfloat16 h = __float2bfloat16(f);
    return *(ushort*)&h;
}

// ---------------- prep: fused W converters (bf16, permuted/padded) + xyz transpose + stats zero ----------------
// ranges: [0,21504) W1b1 mode0 | [21504,43008) W1b2 mode0 | [43008,60416) W2b1 mode1
//         [60416,77824) W2b2 mode1 | [77824,94208) xyz_s4 transpose | [94208,102400) stats=0
__global__ void k_prep(const float* __restrict__ xyz_s4, float* __restrict__ xyz4,
                       const float* __restrict__ sa1_W1, const float* __restrict__ sa2_W1,
                       const float* __restrict__ sa1_W2, const float* __restrict__ sa2_W2,
                       ushort* __restrict__ W1b1, ushort* __restrict__ W1b2,
                       ushort* __restrict__ W2b1, ushort* __restrict__ W2b2,
                       float* __restrict__ stats)
{
    int i = blockIdx.x * 256 + threadIdx.x;
    if (i < 43008) {
        const float* W = (i < 21504) ? sa1_W1 : sa2_W1;
        ushort* o = (i < 21504) ? W1b1 : W1b2;
        int j = (i < 21504) ? i : i - 21504;
        int d = j / 168, c = j - d * 168;
        float v = 0.f;
        if (c < 128)      v = W[d * 131 + 3 + c];
        else if (c < 131) v = W[d * 131 + (c - 128)];
        o[j] = f2b(v);
    } else if (i < 77824) {
        const float* W = (i < 60416) ? sa1_W2 : sa2_W2;
        ushort* o = (i < 60416) ? W2b1 : W2b2;
        int j = (i < 60416) ? i - 43008 : i - 60416;
        int d = j / 136, c = j - d * 136;
        o[j] = (c < 128) ? f2b(W[d * 128 + c]) : (ushort)0;
    } else if (i < 94208) {
        int g = i - 77824;
        int b = g >> 11, n = g & (N4 - 1);
        xyz4[g * 3 + 0] = xyz_s4[(b * 3 + 0) * N4 + n];
        xyz4[g * 3 + 1] = xyz_s4[(b * 3 + 1) * N4 + n];
        xyz4[g * 3 + 2] = xyz_s4[(b * 3 + 2) * N4 + n];
    } else if (i < 102400) {
        stats[i - 94208] = 0.f;        // zeros statsA..statsD (contiguous 8192 floats)
    }
}

// ---------------- transpose feats [B,C,N4] fp32 -> featTb [B,N4,C] bf16 ----------------
__global__ void k_feat_t(const float* __restrict__ feats, ushort* __restrict__ featTb) {
    __shared__ float tile[32][33];
    int b = blockIdx.x, nb = blockIdx.y, cb = blockIdx.z;
    int tx = threadIdx.x, ty = threadIdx.y; // 32 x 8
    int n0 = nb * 32, c0 = cb * 32;
#pragma unroll
    for (int i = 0; i < 4; ++i) {
        int c = c0 + ty + 8 * i;
        tile[ty + 8 * i][tx] = feats[((size_t)b * CH + c) * N4 + n0 + tx];
    }
    __syncthreads();
#pragma unroll
    for (int i = 0; i < 4; ++i) {
        int n = n0 + ty + 8 * i;
        featTb[((size_t)b * N4 + n) * CH + c0 + tx] = f2b(tile[tx][ty + 8 * i]);
    }
}

// ---------------- KNN via exact threshold-select (bisection on fp32 bit pattern) ----------------
// Downstream is permutation-invariant in k, so only the SET of 32 indices matters.
// Set emitted = {d < T} + lowest-index ties at T  ==  exact lax.top_k(-d, 32) index set.
__global__ __launch_bounds__(256) void k_knn(const float* __restrict__ xyz4, int* __restrict__ idxout) {
    __shared__ float pts[N4 * 3];
    int b = blockIdx.x >> 9;            // 512 blocks per batch
    int qbase = (blockIdx.x & 511) * 4;
    for (int i = threadIdx.x; i < N4 * 3; i += 256) pts[i] = xyz4[(size_t)b * N4 * 3 + i];
    __syncthreads();
    int wave = threadIdx.x >> 6, lane = threadIdx.x & 63;
    int qn = qbase + wave;
    float qx = pts[qn * 3 + 0], qy = pts[qn * 3 + 1], qz = pts[qn * 3 + 2];
    float d[32];
#pragma unroll
    for (int t = 0; t < 32; ++t) {
        int c = t * 64 + lane;
        float dx = pts[c * 3 + 0] - qx;
        float dy = pts[c * 3 + 1] - qy;
        float dz = pts[c * 3 + 2] - qz;
        d[t] = dx * dx + dy * dy + dz * dz;
    }
    // bisection: invariant count(d < f(lo)) < 32 <= count(d < f(hi)); d>=0 so uint order == float order
    uint lo = 0u, hi = 0x7F800000u;
    int cLT = 0;
    while (hi - lo > 1u) {
        uint mid = (lo + hi) >> 1;
        float fmid = __uint_as_float(mid);
        int c = 0;
#pragma unroll
        for (int t = 0; t < 32; ++t) c += (d[t] < fmid) ? 1 : 0;
#pragma unroll
        for (int m = 1; m < 64; m <<= 1) c += __shfl_xor(c, m, 64);
        c = __builtin_amdgcn_readfirstlane(c);
        if (c < KNN) { lo = mid; cLT = c; } else hi = mid;
    }
    float T = __uint_as_float(lo);      // T = exact 32nd smallest value; cLT = count(d < T)
    // compaction: d<T at ranks [0,cLT); ties d==T fill [cLT,32) in ascending (t,lane) = ascending index
    int outb = (b * N4 + qn) * KNN;
    unsigned long long lmlt = (1ull << lane) - 1ull;
    int baseLT = 0, baseEQ = cLT;
#pragma unroll
    for (int t = 0; t < 32; ++t) {
        bool lt = d[t] < T;
        unsigned long long m = __ballot(lt);
        if (lt) idxout[outb + baseLT + __popcll(m & lmlt)] = t * 64 + lane;
        baseLT += __popcll(m);
        bool eq = (d[t] == T);
        unsigned long long me = __ballot(eq);
        if (eq) {
            int rk = baseEQ + __popcll(me & lmlt);
            if (rk < KNN) idxout[outb + rk] = t * 64 + lane;
        }
        baseEQ += __popcll(me);
    }
}

// ---------------- SA gemm1 (MFMA): gather + h@W1^T -> ybuf bf16, fused per-(b,c) stats ----------------
// h-row K layout: [feat(128) | gxyz(3) | 0 pad] = 168 (5 chunks of 32, padded)
// SA biases are dropped: InstanceNorm is invariant to per-channel constant shifts.
__global__ __launch_bounds__(256) void k_sa_gemm1(
    const ushort* __restrict__ Fb, const float* __restrict__ xyz4,
    const int* __restrict__ idx, const ushort* __restrict__ W1b,
    ushort* __restrict__ ybuf, float* __restrict__ stats)
{
    __shared__ __align__(16) ushort hs[64][168];
    int t = threadIdx.x;
    int g0 = blockIdx.x * 64;
    int b = g0 >> 16;
    // --- stage gathered rows (bf16 direct copy) ---
    int r = t >> 2, q = t & 3;
    {
        int g = g0 + r;
        int n = (g & 65535) >> 5;
        int j = idx[g];
        const uint4* src = (const uint4*)(Fb + ((size_t)(b * N4 + j)) * CH) + q * 4;
        uint4* dst = (uint4*)&hs[r][q * 32];
#pragma unroll
        for (int m = 0; m < 4; ++m) dst[m] = src[m];
        uint4 z = make_uint4(0, 0, 0, 0);
        *(uint4*)&hs[r][128 + q * 8] = z;          // zero cols 128..159
        if (q == 0) {
            *(uint4*)&hs[r][160] = z;              // zero cols 160..167
            const float* pj = xyz4 + (size_t)(b * N4 + j) * 3;
            const float* pn = xyz4 + (size_t)(b * N4 + n) * 3;
            hs[r][128] = f2b(pj[0] - pn[0]);
            hs[r][129] = f2b(pj[1] - pn[1]);
            hs[r][130] = f2b(pj[2] - pn[2]);
        }
    }
    // --- W fragments to registers (per-wave 32-col slab), overlap with staging ---
    int l = t & 63, w = t >> 6;
    int lr = l & 15, lg = l >> 4;
    U16 bf[5][2];
#pragma unroll
    for (int kc = 0; kc < 5; ++kc)
#pragma unroll
        for (int jj = 0; jj < 2; ++jj)
            bf[kc][jj].u = *(const uint4*)&W1b[(size_t)(w * 32 + jj * 16 + lr) * 168 + kc * 32 + lg * 8];
    __syncthreads();
    f32x4 acc[4][2];
    f32x4 z4 = {0.f, 0.f, 0.f, 0.f};
#pragma unroll
    for (int i = 0; i < 4; ++i) { acc[i][0] = z4; acc[i][1] = z4; }
#pragma unroll
    for (int kc = 0; kc < 5; ++kc) {
        U16 a[4];
#pragma unroll
        for (int i = 0; i < 4; ++i) a[i].u = *(const uint4*)&hs[16 * i + lr][kc * 32 + lg * 8];
#pragma unroll
        for (int i = 0; i < 4; ++i)
#pragma unroll
            for (int jj = 0; jj < 2; ++jj)
                acc[i][jj] = __builtin_amdgcn_mfma_f32_16x16x32_bf16(a[i].s, bf[kc][jj].s, acc[i][jj], 0, 0, 0);
    }
    __syncthreads();   // hs reads complete -> reuse hs as bf16 repack buffer
    // --- epilogue: fused stats + LDS repack of the C tile ---
#pragma unroll
    for (int jj = 0; jj < 2; ++jj) {
        int c = w * 32 + jj * 16 + lr;
        float s = 0.f, sq = 0.f;
#pragma unroll
        for (int i = 0; i < 4; ++i)
#pragma unroll
            for (int rg = 0; rg < 4; ++rg) {
                float v = acc[i][jj][rg];
                s += v; sq += v * v;
                hs[16 * i + lg * 4 + rg][c] = f2b(v);
            }
        s  += __shfl_xor(s, 16, 64);  s  += __shfl_xor(s, 32, 64);
        sq += __shfl_xor(sq, 16, 64); sq += __shfl_xor(sq, 32, 64);
        if (lg == 0) {
            atomicAdd(&stats[b * CH + c], s);
            atomicAdd(&stats[B * CH + b * CH + c], sq);
        }
    }
    __syncthreads();
    // --- coalesced writeout: thread -> (row r, 32-col chunk q) as 4x uint4 ---
    {
        uint4* dst = (uint4*)(ybuf + (size_t)(g0 + r) * CH + q * 32);
#pragma unroll
        for (int m = 0; m < 4; ++m) dst[m] = *(const uint4*)&hs[r][q * 32 + m * 8];
    }
}

// ---------------- SA gemm2 (MFMA): norm+relu(ybuf) @ W2^T, fused stats2 + k-max ----------------
// Never materializes y2: block = 2 points x 32 neighbors; writes ymax bf16 [B*N4][128].
__global__ __launch_bounds__(256) void k_sa_gemm2(
    const ushort* __restrict__ ybuf, const ushort* __restrict__ W2b,
    const float* __restrict__ stats1, float* __restrict__ stats2,
    ushort* __restrict__ ymax)
{
    __shared__ __align__(16) ushort hs[64][136];
    __shared__ float smean[128], sinv[128];
    int t = threadIdx.x;
    int g0 = blockIdx.x * 64;
    int b = g0 >> 16;
    if (t < 128) {
        float s = stats1[b * CH + t], q2 = stats1[B * CH + b * CH + t];
        float mean = s * (1.f / ROWS_PER_B);
        float var = q2 * (1.f / ROWS_PER_B) - mean * mean;
        smean[t] = mean; sinv[t] = rsqrtf(var + 1e-5f);
    }
    int r = t >> 2, q = t & 3;
    uint4 raw[4];
    {
        const uint4* src = (const uint4*)(ybuf + (size_t)(g0 + r) * CH) + q * 4;
#pragma unroll
        for (int m = 0; m < 4; ++m) raw[m] = src[m];
    }
    int l = t & 63, w = t >> 6, lr = l & 15, lg = l >> 4;
    U16 bf[4][2];
#pragma unroll
    for (int kc = 0; kc < 4; ++kc)
#pragma unroll
        for (int jj = 0; jj < 2; ++jj)
            bf[kc][jj].u = *(const uint4*)&W2b[(size_t)(w * 32 + jj * 16 + lr) * 136 + kc * 32 + lg * 8];
    __syncthreads();   // smean/sinv ready
    // normalize + relu + repack to LDS
    {
#pragma unroll
        for (int m = 0; m < 4; ++m) {
            int c0 = q * 32 + m * 8;
            ushort o[8];
            const uint* pr = (const uint*)&raw[m];
#pragma unroll
            for (int e = 0; e < 4; ++e) {
                uint v = pr[e];
                int c = c0 + e * 2;
                float f0 = bf2f((ushort)(v & 0xffff));
                float f1 = bf2f((ushort)(v >> 16));
                o[e * 2]     = f2b(fmaxf((f0 - smean[c])     * sinv[c],     0.f));
                o[e * 2 + 1] = f2b(fmaxf((f1 - smean[c + 1]) * sinv[c + 1], 0.f));
            }
            *(uint4*)&hs[r][c0] = *(uint4*)o;
        }
        if (q == 0) { uint4 z = make_uint4(0, 0, 0, 0); *(uint4*)&hs[r][128] = z; }
    }
    __syncthreads();
    f32x4 acc[4][2];
    f32x4 z4 = {0.f, 0.f, 0.f, 0.f};
#pragma unroll
    for (int i = 0; i < 4; ++i) { acc[i][0] = z4; acc[i][1] = z4; }
#pragma unroll
    for (int kc = 0; kc < 4; ++kc) {
        U16 a[4];
#pragma unroll
        for (int i = 0; i < 4; ++i) a[i].u = *(const uint4*)&hs[16 * i + lr][kc * 32 + lg * 8];
#pragma unroll
        for (int i = 0; i < 4; ++i)
#pragma unroll
            for (int jj = 0; jj < 2; ++jj)
                acc[i][jj] = __builtin_amdgcn_mfma_f32_16x16x32_bf16(a[i].s, bf[kc][jj].s, acc[i][jj], 0, 0, 0);
    }
    // epilogue: fused stats2 (pre-max) + k-max over the 32 neighbors of each of the 2 points
    int gp0 = g0 >> 5;                 // global point index of first point in tile
#pragma unroll
    for (int jj = 0; jj < 2; ++jj) {
        int c = w * 32 + jj * 16 + lr;
        float s = 0.f, sq = 0.f;
        float m0 = -3.4e38f, m1 = -3.4e38f;
#pragma unroll
        for (int i = 0; i < 4; ++i)
#pragma unroll
            for (int rg = 0; rg < 4; ++rg) {
                float v = acc[i][jj][rg];
                s += v; sq += v * v;
                if (i < 2) m0 = fmaxf(m0, v); else m1 = fmaxf(m1, v);
            }
        s  += __shfl_xor(s, 16, 64);  s  += __shfl_xor(s, 32, 64);
        sq += __shfl_xor(sq, 16, 64); sq += __shfl_xor(sq, 32, 64);
        m0 = fmaxf(m0, __shfl_xor(m0, 16, 64)); m0 = fmaxf(m0, __shfl_xor(m0, 32, 64));
        m1 = fmaxf(m1, __shfl_xor(m1, 16, 64)); m1 = fmaxf(m1, __shfl_xor(m1, 32, 64));
        if (lg == 0) {
            atomicAdd(&stats2[b * CH + c], s);
            atomicAdd(&stats2[B * CH + b * CH + c], sq);
            ymax[(size_t)gp0 * CH + c] = f2b(m0);
            ymax[(size_t)(gp0 + 1) * CH + c] = f2b(m1);
        }
    }
}

// ---------------- pass C: norm+relu on pooled maxes -> bf16 features ----------------
__global__ void k_passC2(const ushort* __restrict__ ymax, const float* __restrict__ stats,
                         ushort* __restrict__ outp)
{
    int e = blockIdx.x * 256 + threadIdx.x;    // handles 4 cols; total B*N4*32 threads
    int row = e >> 5, cq = (e & 31) * 4;
    int b = row >> 11;
    uint2 v = *(const uint2*)&ymax[(size_t)row * CH + cq];
    float f[4] = { bf2f((ushort)(v.x & 0xffff)), bf2f((ushort)(v.x >> 16)),
                   bf2f((ushort)(v.y & 0xffff)), bf2f((ushort)(v.y >> 16)) };
    uint2 o2;
    ushort o[4];
#pragma unroll
    for (int j = 0; j < 4; ++j) {
        int c = cq + j;
        float mean = stats[b * CH + c] * (1.f / ROWS_PER_B);
        float var = stats[B * CH + b * CH + c] * (1.f / ROWS_PER_B) - mean * mean;
        o[j] = f2b(fmaxf((f[j] - mean) * rsqrtf(var + 1e-5f), 0.f));
    }
    o2.x = (uint)o[0] | ((uint)o[1] << 16);
    o2.y = (uint)o[2] | ((uint)o[3] << 16);
    *(uint2*)&outp[(size_t)row * CH + cq] = o2;
}

// ---------------- FC head: relu(X@W1^T+b1) @ W2^T + b2 -> flow_lr [B,3,N4] in d_out ----------------
__global__ __launch_bounds__(256, 1) void k_fc(
    const ushort* __restrict__ X, const float* __restrict__ W1,
    const float* __restrict__ b1, const float* __restrict__ W2,
    const float* __restrict__ b2, float* __restrict__ out)
{
    __shared__ float hs[64][132];
    __shared__ float ws[128][132];
    int t = threadIdx.x;
    for (int i = t; i < 128 * 132; i += 256) {
        int dd = i / 132, c = i - dd * 132;
        ws[dd][c] = (c < 128) ? W1[dd * 128 + c] : 0.f;
    }
    int r = t >> 2, q = t & 3;
    int g0 = blockIdx.x * 64;
    {
        const uint4* Xrow = (const uint4*)(X + (size_t)(g0 + r) * CH + q * 32);
#pragma unroll
        for (int m = 0; m < 4; ++m) {
            uint4 v = Xrow[m];
            const uint* pv = (const uint*)&v;
            int c0 = q * 32 + m * 8;
#pragma unroll
            for (int e = 0; e < 4; ++e) {
                hs[r][c0 + 2 * e]     = bf2f((ushort)(pv[e] & 0xffff));
                hs[r][c0 + 2 * e + 1] = bf2f((ushort)(pv[e] >> 16));
            }
        }
        if (q == 0) *(float4*)&hs[r][128] = make_float4(0.f, 0.f, 0.f, 0.f);
    }
    __syncthreads();
    int tx = t & 15, ty = t >> 4;
    float acc[4][8];
#pragma unroll
    for (int i = 0; i < 4; ++i)
#pragma unroll
        for (int jj = 0; jj < 8; ++jj) acc[i][jj] = 0.f;
    for (int kb = 0; kb < 33; ++kb) {
        float4 a[4]; float4 w[8];
#pragma unroll
        for (int i = 0; i < 4; ++i) a[i] = *(float4*)&hs[ty * 4 + i][kb * 4];
#pragma unroll
        for (int jj = 0; jj < 8; ++jj) w[jj] = *(float4*)&ws[tx + 16 * jj][kb * 4];
#pragma unroll
        for (int i = 0; i < 4; ++i)
#pragma unroll
            for (int jj = 0; jj < 8; ++jj)
                acc[i][jj] += a[i].x * w[jj].x + a[i].y * w[jj].y
                            + a[i].z * w[jj].z + a[i].w * w[jj].w;
    }
    __syncthreads();                     // done reading hs
#pragma unroll
    for (int jj = 0; jj < 8; ++jj) {
        int c = tx + 16 * jj;
        float bias = b1[c];
#pragma unroll
        for (int i = 0; i < 4; ++i)
            hs[ty * 4 + i][c] = fmaxf(acc[i][jj] + bias, 0.f);
    }
    __syncthreads();
    if (t < 192) {
        int rr = t / 3, o = t - rr * 3;
        float sum = b2[o];
        for (int c = 0; c < 128; ++c) sum += hs[rr][c] * W2[o * 128 + c];
        int g = g0 + rr;
        int b = g >> 11, n = g & (N4 - 1);
        out[FLOWLR_OFF + ((size_t)b * 3 + o) * N4 + n] = sum;
    }
}

// ---------------- feature propagation: 3-NN inverse-sqdist interp onto xyz1 ----------------
// 4 threads per query, each scanning a 512-point chunk; lexicographic (d,idx) shfl merge.
// GRID: B * (N1/64) = 1024 blocks (64 queries per block).
__global__ __launch_bounds__(256) void k_fp(
    const float* __restrict__ xyz_s1, const float* __restrict__ xyz4,
    float* __restrict__ out)
{
    __shared__ float xs[4 * 528], ys[4 * 528], zs[4 * 528];   // chunk c at c*528 (pad kills bank aliasing)
    int b = blockIdx.x >> 7;             // 128 blocks per batch
    int q0 = (blockIdx.x & 127) * 64;
    int t = threadIdx.x;
    for (int i = t; i < N4; i += 256) {
        int p = (i >> 9) * 528 + (i & 511);
        const float* s = xyz4 + (size_t)b * N4 * 3 + (size_t)i * 3;
        xs[p] = s[0]; ys[p] = s[1]; zs[p] = s[2];
    }
    __syncthreads();
    int q = q0 + (t >> 2), c = t & 3;
    float qx = xyz_s1[((size_t)b * 3 + 0) * N1 + q];
    float qy = xyz_s1[((size_t)b * 3 + 1) * N1 + q];
    float qz = xyz_s1[((size_t)b * 3 + 2) * N1 + q];
    float d0 = 3.4e38f, d1 = 3.4e38f, d2 = 3.4e38f;
    int i0 = 0, i1 = 0, i2 = 0;
    int base = c * 528, nb = c * 512;
    for (int ii = 0; ii < 512; ii += 4) {
        float4 x4 = *(float4*)&xs[base + ii];
        float4 y4 = *(float4*)&ys[base + ii];
        float4 z4 = *(float4*)&zs[base + ii];
#pragma unroll
        for (int j = 0; j < 4; ++j) {
            float dx = ((const float*)&x4)[j] - qx;
            float dy = ((const float*)&y4)[j] - qy;
            float dz = ((const float*)&z4)[j] - qz;
            float dd = dx * dx + dy * dy + dz * dz;
            if (dd < d2) {               // strict < is tie-correct for ascending index scan
                int n = nb + ii + j;
                if (dd < d0)      { d2 = d1; i2 = i1; d1 = d0; i1 = i0; d0 = dd; i0 = n; }
                else if (dd < d1) { d2 = d1; i2 = i1; d1 = dd; i1 = n; }
                else              { d2 = dd; i2 = n; }
            }
        }
    }
    // merge the 4 chunk-local top-3 lists (lexicographic (d, idx) insertion)
#pragma unroll
    for (int m = 1; m <= 2; m <<= 1) {
        float e0 = __shfl_xor(d0, m, 64), e1 = __shfl_xor(d1, m, 64), e2 = __shfl_xor(d2, m, 64);
        int   j0 = __shfl_xor(i0, m, 64), j1 = __shfl_xor(i1, m, 64), j2 = __shfl_xor(i2, m, 64);
        float ed[3] = { e0, e1, e2 }; int ej[3] = { j0, j1, j2 };
#pragma unroll
        for (int s = 0; s < 3; ++s) {
            float dd = ed[s]; int jn = ej[s];
            bool lt2 = dd < d2 || (dd == d2 && jn < i2);
            if (lt2) {
                bool lt0 = dd < d0 || (dd == d0 && jn < i0);
                bool lt1 = dd < d1 || (dd == d1 && jn < i1);
                if (lt0)      { d2 = d1; i2 = i1; d1 = d0; i1 = i0; d0 = dd; i0 = jn; }
                else if (lt1) { d2 = d1; i2 = i1; d1 = dd; i1 = jn; }
                else          { d2 = dd; i2 = jn; }
            }
        }
    }
    float w0 = 1.f / (d0 + 1e-8f), w1 = 1.f / (d1 + 1e-8f), w2 = 1.f / (d2 + 1e-8f);
    float inv = 1.f / (w0 + w1 + w2);
    const float* flr = out + FLOWLR_OFF + (size_t)b * 3 * N4;
    if (c < 3) {
        float v = (w0 * flr[c * N4 + i0] + w1 * flr[c * N4 + i1] + w2 * flr[c * N4 + i2]) * inv;
        out[((size_t)b * 3 + c) * N1 + q] = v;
    }
}

extern "C" void kernel_launch(void* const* d_in, const int* in_sizes, int n_in,
                              void* d_out, int out_size, void* d_ws, size_t ws_size,
                              hipStream_t stream) {
    const float* xyz_s1 = (const float*)d_in[0];
    const float* xyz_s4 = (const float*)d_in[1];
    const float* feats  = (const float*)d_in[2];
    const float* sa1_W1 = (const float*)d_in[3];
    const float* sa1_W2 = (const float*)d_in[5];
    const float* sa2_W1 = (const float*)d_in[7];
    const float* sa2_W2 = (const float*)d_in[9];
    const float* fc_W1  = (const float*)d_in[11];
    const float* fc_b1  = (const float*)d_in[12];
    const float* fc_W2  = (const float*)d_in[13];
    const float* fc_b2  = (const float*)d_in[14];
    float* out = (float*)d_out;

    // workspace layout (stays within the round-1-proven 153.3 MB footprint)
    char* wsb = (char*)d_ws;
    float*  xyz4   = (float*)(wsb + 0);                  // 196608 B
    int*    idx    = (int*)(wsb + 196608);               // 2 MB   -> 2293760
    ushort* featTb = (ushort*)(wsb + 2293760);           // 4 MB   -> 6488064   (feats transposed bf16)
    ushort* ymax   = (ushort*)(wsb + 2293760);           // ALIAS: featTb dead after gemm1-SA1
    ushort* featB  = (ushort*)(wsb + 6488064);           // 4 MB   -> 10682368  (SA1 output)
    ushort* featC  = (ushort*)(wsb + 10682368);          // 4 MB   -> 14876672  (SA2 output)
    ushort* W1b1   = (ushort*)(wsb + 14876672);          // 64 KB  -> 14942208
    ushort* W1b2   = (ushort*)(wsb + 14942208);          // 64 KB  -> 15007744
    ushort* W2b1   = (ushort*)(wsb + 15007744);          // 64 KB  -> 15073280
    ushort* W2b2   = (ushort*)(wsb + 15073280);          // 64 KB  -> 15138816
    float*  statsA = (float*)(wsb + 15138816);           // 8 KB each x4 (contiguous)
    float*  statsB = (float*)(wsb + 15147008);
    float*  statsC = (float*)(wsb + 15155200);
    float*  statsD = (float*)(wsb + 15163392);
    ushort* ybuf   = (ushort*)(wsb + 19079168);          // 128 MB -> 153296896

    // ---- setup (fused prep: wconv x4 + xyz transpose + stats zero) ----
    k_prep<<<400, 256, 0, stream>>>(xyz_s4, xyz4, sa1_W1, sa2_W1, sa1_W2, sa2_W2,
                                    W1b1, W1b2, W2b1, W2b2, statsA);
    k_knn<<<B * (N4 / 4), 256, 0, stream>>>(xyz4, idx);
    dim3 gt(B, N4 / 32, CH / 32), bt(32, 8);
    k_feat_t<<<gt, bt, 0, stream>>>(feats, featTb);

    // ---- SA1 ----
    k_sa_gemm1<<<ROWS_TOTAL / 64, 256, 0, stream>>>(featTb, xyz4, idx, W1b1, ybuf, statsA);
    k_sa_gemm2<<<ROWS_TOTAL / 64, 256, 0, stream>>>(ybuf, W2b1, statsA, statsB, ymax);
    k_passC2<<<(B * N4 * 32) / 256, 256, 0, stream>>>(ymax, statsB, featB);

    // ---- SA2 ----
    k_sa_gemm1<<<ROWS_TOTAL / 64, 256, 0, stream>>>(featB, xyz4, idx, W1b2, ybuf, statsC);
    k_sa_gemm2<<<ROWS_TOTAL / 64, 256, 0, stream>>>(ybuf, W2b2, statsC, statsD, ymax);
    k_passC2<<<(B * N4 * 32) / 256, 256, 0, stream>>>(ymax, statsD, featC);

    // ---- FC head + flow_lr ----
    k_fc<<<(B * N4) / 64, 256, 0, stream>>>(featC, fc_W1, fc_b1, fc_W2, fc_b2, out);
    // ---- feature propagation -> flow (1024 blocks: 64 queries/block x 4 threads each) ----
    k_fp<<<B * (N1 / 64), 256, 0, stream>>>(xyz_s1, xyz4, out);
}

// Round 6
// 612.362 us; speedup vs baseline: 5.7684x; 1.0811x over previous
//
#include <hip/hip_runtime.h>
#include <hip/hip_bf16.h>

#define B 8
#define N1 8192
#define N4 2048
#define CH 128
#define KNN 32
#define ROWS_PER_B (N4 * KNN)          // 65536 rows per batch in the [B,N,K] flattening
#define ROWS_TOTAL (B * ROWS_PER_B)    // 524288
#define FLOWLR_OFF (B * 3 * N1)        // flow_lr starts after flow in d_out

typedef unsigned int uint;
typedef unsigned short ushort;
typedef __attribute__((ext_vector_type(8))) short short8;
typedef __attribute__((ext_vector_type(4))) float f32x4;

union U16 { uint4 u; short8 s; };

__device__ __forceinline__ float bf2f(ushort u) {
    union { uint i; float f; } v; v.i = ((uint)u) << 16; return v.f;
}
__device__ __forceinline__ ushort f2b(float f) {
    __hip_bfloat16 h = __float2bfloat16(f);
    return *(ushort*)&h;
}

// ---------------- prep: fused W converters (bf16, permuted/padded) + xyz transpose + stats zero ----------------
// ranges: [0,21504) W1b1 mode0 | [21504,43008) W1b2 mode0 | [43008,60416) W2b1 mode1
//         [60416,77824) W2b2 mode1 | [77824,94208) xyz_s4 transpose | [94208,102400) stats=0
__global__ void k_prep(const float* __restrict__ xyz_s4, float* __restrict__ xyz4,
                       const float* __restrict__ sa1_W1, const float* __restrict__ sa2_W1,
                       const float* __restrict__ sa1_W2, const float* __restrict__ sa2_W2,
                       ushort* __restrict__ W1b1, ushort* __restrict__ W1b2,
                       ushort* __restrict__ W2b1, ushort* __restrict__ W2b2,
                       float* __restrict__ stats)
{
    int i = blockIdx.x * 256 + threadIdx.x;
    if (i < 43008) {
        const float* W = (i < 21504) ? sa1_W1 : sa2_W1;
        ushort* o = (i < 21504) ? W1b1 : W1b2;
        int j = (i < 21504) ? i : i - 21504;
        int d = j / 168, c = j - d * 168;
        float v = 0.f;
        if (c < 128)      v = W[d * 131 + 3 + c];
        else if (c < 131) v = W[d * 131 + (c - 128)];
        o[j] = f2b(v);
    } else if (i < 77824) {
        const float* W = (i < 60416) ? sa1_W2 : sa2_W2;
        ushort* o = (i < 60416) ? W2b1 : W2b2;
        int j = (i < 60416) ? i - 43008 : i - 60416;
        int d = j / 136, c = j - d * 136;
        o[j] = (c < 128) ? f2b(W[d * 128 + c]) : (ushort)0;
    } else if (i < 94208) {
        int g = i - 77824;
        int b = g >> 11, n = g & (N4 - 1);
        xyz4[g * 3 + 0] = xyz_s4[(b * 3 + 0) * N4 + n];
        xyz4[g * 3 + 1] = xyz_s4[(b * 3 + 1) * N4 + n];
        xyz4[g * 3 + 2] = xyz_s4[(b * 3 + 2) * N4 + n];
    } else if (i < 102400) {
        stats[i - 94208] = 0.f;        // zeros statsA..statsD (contiguous 8192 floats)
    }
}

// ---------------- transpose feats [B,C,N4] fp32 -> featTb [B,N4,C] bf16 ----------------
__global__ void k_feat_t(const float* __restrict__ feats, ushort* __restrict__ featTb) {
    __shared__ float tile[32][33];
    int b = blockIdx.x, nb = blockIdx.y, cb = blockIdx.z;
    int tx = threadIdx.x, ty = threadIdx.y; // 32 x 8
    int n0 = nb * 32, c0 = cb * 32;
#pragma unroll
    for (int i = 0; i < 4; ++i) {
        int c = c0 + ty + 8 * i;
        tile[ty + 8 * i][tx] = feats[((size_t)b * CH + c) * N4 + n0 + tx];
    }
    __syncthreads();
#pragma unroll
    for (int i = 0; i < 4; ++i) {
        int n = n0 + ty + 8 * i;
        featTb[((size_t)b * N4 + n) * CH + c0 + tx] = f2b(tile[tx][ty + 8 * i]);
    }
}

// ---------------- KNN via exact threshold-select (bisection on fp32 bit pattern) ----------------
// Downstream is permutation-invariant in k, so only the SET of 32 indices matters.
// Set emitted = {d < T} + lowest-index ties at T  ==  exact lax.top_k(-d, 32) index set.
// Count per bisection step = sum_t popcount(ballot(d[t] < mid)): v_cmp->SGPR + s_bcnt1
// on the SALU pipe (co-issues with VALU), no cross-lane reduce, wave-uniform for free.
__global__ __launch_bounds__(256) void k_knn(const float* __restrict__ xyz4, int* __restrict__ idxout) {
    __shared__ float pts[N4 * 3];
    int b = blockIdx.x >> 9;            // 512 blocks per batch
    int qbase = (blockIdx.x & 511) * 4;
    for (int i = threadIdx.x; i < N4 * 3; i += 256) pts[i] = xyz4[(size_t)b * N4 * 3 + i];
    __syncthreads();
    int wave = threadIdx.x >> 6, lane = threadIdx.x & 63;
    int qn = qbase + wave;
    float qx = pts[qn * 3 + 0], qy = pts[qn * 3 + 1], qz = pts[qn * 3 + 2];
    float d[32];
#pragma unroll
    for (int t = 0; t < 32; ++t) {
        int c = t * 64 + lane;
        float dx = pts[c * 3 + 0] - qx;
        float dy = pts[c * 3 + 1] - qy;
        float dz = pts[c * 3 + 2] - qz;
        d[t] = dx * dx + dy * dy + dz * dz;
    }
    // bisection: invariant count(d < f(lo)) < 32 <= count(d < f(hi)); d>=0 so uint order == float order
    uint lo = 0u, hi = 0x7F800000u;
    int cLT = 0;
    while (hi - lo > 1u) {
        uint mid = (lo + hi) >> 1;
        float fmid = __uint_as_float(mid);
        int c = 0;
#pragma unroll
        for (int t = 0; t < 32; ++t) c += __popcll(__ballot(d[t] < fmid));
        if (c < KNN) { lo = mid; cLT = c; } else hi = mid;
    }
    float T = __uint_as_float(lo);      // T = exact 32nd smallest value; cLT = count(d < T)
    // compaction: d<T at ranks [0,cLT); ties d==T fill [cLT,32) in ascending (t,lane) = ascending index
    int outb = (b * N4 + qn) * KNN;
    unsigned long long lmlt = (1ull << lane) - 1ull;
    int baseLT = 0, baseEQ = cLT;
#pragma unroll
    for (int t = 0; t < 32; ++t) {
        bool lt = d[t] < T;
        unsigned long long m = __ballot(lt);
        if (lt) idxout[outb + baseLT + __popcll(m & lmlt)] = t * 64 + lane;
        baseLT += __popcll(m);
        bool eq = (d[t] == T);
        unsigned long long me = __ballot(eq);
        if (eq) {
            int rk = baseEQ + __popcll(me & lmlt);
            if (rk < KNN) idxout[outb + rk] = t * 64 + lane;
        }
        baseEQ += __popcll(me);
    }
}

// ---------------- SA gemm1 (MFMA): gather + h@W1^T -> ybuf bf16, fused per-(b,c) stats ----------------
// h-row K layout: [feat(128) | gxyz(3) | 0 pad] = 168 (5 chunks of 32, padded)
// SA biases are dropped: InstanceNorm is invariant to per-channel constant shifts.
__global__ __launch_bounds__(256) void k_sa_gemm1(
    const ushort* __restrict__ Fb, const float* __restrict__ xyz4,
    const int* __restrict__ idx, const ushort* __restrict__ W1b,
    ushort* __restrict__ ybuf, float* __restrict__ stats)
{
    __shared__ __align__(16) ushort hs[64][168];
    int t = threadIdx.x;
    int g0 = blockIdx.x * 64;
    int b = g0 >> 16;
    // --- stage gathered rows (bf16 direct copy) ---
    int r = t >> 2, q = t & 3;
    {
        int g = g0 + r;
        int n = (g & 65535) >> 5;
        int j = idx[g];
        const uint4* src = (const uint4*)(Fb + ((size_t)(b * N4 + j)) * CH) + q * 4;
        uint4* dst = (uint4*)&hs[r][q * 32];
#pragma unroll
        for (int m = 0; m < 4; ++m) dst[m] = src[m];
        uint4 z = make_uint4(0, 0, 0, 0);
        *(uint4*)&hs[r][128 + q * 8] = z;          // zero cols 128..159
        if (q == 0) {
            *(uint4*)&hs[r][160] = z;              // zero cols 160..167
            const float* pj = xyz4 + (size_t)(b * N4 + j) * 3;
            const float* pn = xyz4 + (size_t)(b * N4 + n) * 3;
            hs[r][128] = f2b(pj[0] - pn[0]);
            hs[r][129] = f2b(pj[1] - pn[1]);
            hs[r][130] = f2b(pj[2] - pn[2]);
        }
    }
    // --- W fragments to registers (per-wave 32-col slab), overlap with staging ---
    int l = t & 63, w = t >> 6;
    int lr = l & 15, lg = l >> 4;
    U16 bf[5][2];
#pragma unroll
    for (int kc = 0; kc < 5; ++kc)
#pragma unroll
        for (int jj = 0; jj < 2; ++jj)
            bf[kc][jj].u = *(const uint4*)&W1b[(size_t)(w * 32 + jj * 16 + lr) * 168 + kc * 32 + lg * 8];
    __syncthreads();
    f32x4 acc[4][2];
    f32x4 z4 = {0.f, 0.f, 0.f, 0.f};
#pragma unroll
    for (int i = 0; i < 4; ++i) { acc[i][0] = z4; acc[i][1] = z4; }
#pragma unroll
    for (int kc = 0; kc < 5; ++kc) {
        U16 a[4];
#pragma unroll
        for (int i = 0; i < 4; ++i) a[i].u = *(const uint4*)&hs[16 * i + lr][kc * 32 + lg * 8];
#pragma unroll
        for (int i = 0; i < 4; ++i)
#pragma unroll
            for (int jj = 0; jj < 2; ++jj)
                acc[i][jj] = __builtin_amdgcn_mfma_f32_16x16x32_bf16(a[i].s, bf[kc][jj].s, acc[i][jj], 0, 0, 0);
    }
    __syncthreads();   // hs reads complete -> reuse hs as bf16 repack buffer
    // --- epilogue: fused stats + LDS repack of the C tile ---
#pragma unroll
    for (int jj = 0; jj < 2; ++jj) {
        int c = w * 32 + jj * 16 + lr;
        float s = 0.f, sq = 0.f;
#pragma unroll
        for (int i = 0; i < 4; ++i)
#pragma unroll
            for (int rg = 0; rg < 4; ++rg) {
                float v = acc[i][jj][rg];
                s += v; sq += v * v;
                hs[16 * i + lg * 4 + rg][c] = f2b(v);
            }
        s  += __shfl_xor(s, 16, 64);  s  += __shfl_xor(s, 32, 64);
        sq += __shfl_xor(sq, 16, 64); sq += __shfl_xor(sq, 32, 64);
        if (lg == 0) {
            atomicAdd(&stats[b * CH + c], s);
            atomicAdd(&stats[B * CH + b * CH + c], sq);
        }
    }
    __syncthreads();
    // --- coalesced writeout: thread -> (row r, 32-col chunk q) as 4x uint4 ---
    {
        uint4* dst = (uint4*)(ybuf + (size_t)(g0 + r) * CH + q * 32);
#pragma unroll
        for (int m = 0; m < 4; ++m) dst[m] = *(const uint4*)&hs[r][q * 32 + m * 8];
    }
}

// ---------------- SA gemm2 (MFMA): norm+relu(ybuf) @ W2^T, fused stats2 + k-max ----------------
// Never materializes y2: block = 2 points x 32 neighbors; writes ymax bf16 [B*N4][128].
__global__ __launch_bounds__(256) void k_sa_gemm2(
    const ushort* __restrict__ ybuf, const ushort* __restrict__ W2b,
    const float* __restrict__ stats1, float* __restrict__ stats2,
    ushort* __restrict__ ymax)
{
    __shared__ __align__(16) ushort hs[64][136];
    __shared__ float smean[128], sinv[128];
    int t = threadIdx.x;
    int g0 = blockIdx.x * 64;
    int b = g0 >> 16;
    if (t < 128) {
        float s = stats1[b * CH + t], q2 = stats1[B * CH + b * CH + t];
        float mean = s * (1.f / ROWS_PER_B);
        float var = q2 * (1.f / ROWS_PER_B) - mean * mean;
        smean[t] = mean; sinv[t] = rsqrtf(var + 1e-5f);
    }
    int r = t >> 2, q = t & 3;
    uint4 raw[4];
    {
        const uint4* src = (const uint4*)(ybuf + (size_t)(g0 + r) * CH) + q * 4;
#pragma unroll
        for (int m = 0; m < 4; ++m) raw[m] = src[m];
    }
    int l = t & 63, w = t >> 6, lr = l & 15, lg = l >> 4;
    U16 bf[4][2];
#pragma unroll
    for (int kc = 0; kc < 4; ++kc)
#pragma unroll
        for (int jj = 0; jj < 2; ++jj)
            bf[kc][jj].u = *(const uint4*)&W2b[(size_t)(w * 32 + jj * 16 + lr) * 136 + kc * 32 + lg * 8];
    __syncthreads();   // smean/sinv ready
    // normalize + relu + repack to LDS
    {
#pragma unroll
        for (int m = 0; m < 4; ++m) {
            int c0 = q * 32 + m * 8;
            ushort o[8];
            const uint* pr = (const uint*)&raw[m];
#pragma unroll
            for (int e = 0; e < 4; ++e) {
                uint v = pr[e];
                int c = c0 + e * 2;
                float f0 = bf2f((ushort)(v & 0xffff));
                float f1 = bf2f((ushort)(v >> 16));
                o[e * 2]     = f2b(fmaxf((f0 - smean[c])     * sinv[c],     0.f));
                o[e * 2 + 1] = f2b(fmaxf((f1 - smean[c + 1]) * sinv[c + 1], 0.f));
            }
            *(uint4*)&hs[r][c0] = *(uint4*)o;
        }
        if (q == 0) { uint4 z = make_uint4(0, 0, 0, 0); *(uint4*)&hs[r][128] = z; }
    }
    __syncthreads();
    f32x4 acc[4][2];
    f32x4 z4 = {0.f, 0.f, 0.f, 0.f};
#pragma unroll
    for (int i = 0; i < 4; ++i) { acc[i][0] = z4; acc[i][1] = z4; }
#pragma unroll
    for (int kc = 0; kc < 4; ++kc) {
        U16 a[4];
#pragma unroll
        for (int i = 0; i < 4; ++i) a[i].u = *(const uint4*)&hs[16 * i + lr][kc * 32 + lg * 8];
#pragma unroll
        for (int i = 0; i < 4; ++i)
#pragma unroll
            for (int jj = 0; jj < 2; ++jj)
                acc[i][jj] = __builtin_amdgcn_mfma_f32_16x16x32_bf16(a[i].s, bf[kc][jj].s, acc[i][jj], 0, 0, 0);
    }
    // epilogue: fused stats2 (pre-max) + k-max over the 32 neighbors of each of the 2 points
    int gp0 = g0 >> 5;                 // global point index of first point in tile
#pragma unroll
    for (int jj = 0; jj < 2; ++jj) {
        int c = w * 32 + jj * 16 + lr;
        float s = 0.f, sq = 0.f;
        float m0 = -3.4e38f, m1 = -3.4e38f;
#pragma unroll
        for (int i = 0; i < 4; ++i)
#pragma unroll
            for (int rg = 0; rg < 4; ++rg) {
                float v = acc[i][jj][rg];
                s += v; sq += v * v;
                if (i < 2) m0 = fmaxf(m0, v); else m1 = fmaxf(m1, v);
            }
        s  += __shfl_xor(s, 16, 64);  s  += __shfl_xor(s, 32, 64);
        sq += __shfl_xor(sq, 16, 64); sq += __shfl_xor(sq, 32, 64);
        m0 = fmaxf(m0, __shfl_xor(m0, 16, 64)); m0 = fmaxf(m0, __shfl_xor(m0, 32, 64));
        m1 = fmaxf(m1, __shfl_xor(m1, 16, 64)); m1 = fmaxf(m1, __shfl_xor(m1, 32, 64));
        if (lg == 0) {
            atomicAdd(&stats2[b * CH + c], s);
            atomicAdd(&stats2[B * CH + b * CH + c], sq);
            ymax[(size_t)gp0 * CH + c] = f2b(m0);
            ymax[(size_t)(gp0 + 1) * CH + c] = f2b(m1);
        }
    }
}

// ---------------- pass C: norm+relu on pooled maxes -> bf16 features ----------------
__global__ void k_passC2(const ushort* __restrict__ ymax, const float* __restrict__ stats,
                         ushort* __restrict__ outp)
{
    int e = blockIdx.x * 256 + threadIdx.x;    // handles 4 cols; total B*N4*32 threads
    int row = e >> 5, cq = (e & 31) * 4;
    int b = row >> 11;
    uint2 v = *(const uint2*)&ymax[(size_t)row * CH + cq];
    float f[4] = { bf2f((ushort)(v.x & 0xffff)), bf2f((ushort)(v.x >> 16)),
                   bf2f((ushort)(v.y & 0xffff)), bf2f((ushort)(v.y >> 16)) };
    uint2 o2;
    ushort o[4];
#pragma unroll
    for (int j = 0; j < 4; ++j) {
        int c = cq + j;
        float mean = stats[b * CH + c] * (1.f / ROWS_PER_B);
        float var = stats[B * CH + b * CH + c] * (1.f / ROWS_PER_B) - mean * mean;
        o[j] = f2b(fmaxf((f[j] - mean) * rsqrtf(var + 1e-5f), 0.f));
    }
    o2.x = (uint)o[0] | ((uint)o[1] << 16);
    o2.y = (uint)o[2] | ((uint)o[3] << 16);
    *(uint2*)&outp[(size_t)row * CH + cq] = o2;
}

// ---------------- FC head: relu(X@W1^T+b1) @ W2^T + b2 -> flow_lr [B,3,N4] in d_out ----------------
__global__ __launch_bounds__(256, 1) void k_fc(
    const ushort* __restrict__ X, const float* __restrict__ W1,
    const float* __restrict__ b1, const float* __restrict__ W2,
    const float* __restrict__ b2, float* __restrict__ out)
{
    __shared__ float hs[64][132];
    __shared__ float ws[128][132];
    int t = threadIdx.x;
    for (int i = t; i < 128 * 132; i += 256) {
        int dd = i / 132, c = i - dd * 132;
        ws[dd][c] = (c < 128) ? W1[dd * 128 + c] : 0.f;
    }
    int r = t >> 2, q = t & 3;
    int g0 = blockIdx.x * 64;
    {
        const uint4* Xrow = (const uint4*)(X + (size_t)(g0 + r) * CH + q * 32);
#pragma unroll
        for (int m = 0; m < 4; ++m) {
            uint4 v = Xrow[m];
            const uint* pv = (const uint*)&v;
            int c0 = q * 32 + m * 8;
#pragma unroll
            for (int e = 0; e < 4; ++e) {
                hs[r][c0 + 2 * e]     = bf2f((ushort)(pv[e] & 0xffff));
                hs[r][c0 + 2 * e + 1] = bf2f((ushort)(pv[e] >> 16));
            }
        }
        if (q == 0) *(float4*)&hs[r][128] = make_float4(0.f, 0.f, 0.f, 0.f);
    }
    __syncthreads();
    int tx = t & 15, ty = t >> 4;
    float acc[4][8];
#pragma unroll
    for (int i = 0; i < 4; ++i)
#pragma unroll
        for (int jj = 0; jj < 8; ++jj) acc[i][jj] = 0.f;
    for (int kb = 0; kb < 33; ++kb) {
        float4 a[4]; float4 w[8];
#pragma unroll
        for (int i = 0; i < 4; ++i) a[i] = *(float4*)&hs[ty * 4 + i][kb * 4];
#pragma unroll
        for (int jj = 0; jj < 8; ++jj) w[jj] = *(float4*)&ws[tx + 16 * jj][kb * 4];
#pragma unroll
        for (int i = 0; i < 4; ++i)
#pragma unroll
            for (int jj = 0; jj < 8; ++jj)
                acc[i][jj] += a[i].x * w[jj].x + a[i].y * w[jj].y
                            + a[i].z * w[jj].z + a[i].w * w[jj].w;
    }
    __syncthreads();                     // done reading hs
#pragma unroll
    for (int jj = 0; jj < 8; ++jj) {
        int c = tx + 16 * jj;
        float bias = b1[c];
#pragma unroll
        for (int i = 0; i < 4; ++i)
            hs[ty * 4 + i][c] = fmaxf(acc[i][jj] + bias, 0.f);
    }
    __syncthreads();
    if (t < 192) {
        int rr = t / 3, o = t - rr * 3;
        float sum = b2[o];
        for (int c = 0; c < 128; ++c) sum += hs[rr][c] * W2[o * 128 + c];
        int g = g0 + rr;
        int b = g >> 11, n = g & (N4 - 1);
        out[FLOWLR_OFF + ((size_t)b * 3 + o) * N4 + n] = sum;
    }
}

// ---------------- feature propagation: 3-NN inverse-sqdist interp onto xyz1 ----------------
// 4 threads per query, each scanning a 512-point chunk; lexicographic (d,idx) shfl merge.
// GRID: B * (N1/64) = 1024 blocks (64 queries per block).
__global__ __launch_bounds__(256) void k_fp(
    const float* __restrict__ xyz_s1, const float* __restrict__ xyz4,
    float* __restrict__ out)
{
    __shared__ float xs[4 * 528], ys[4 * 528], zs[4 * 528];   // chunk c at c*528 (pad kills bank aliasing)
    int b = blockIdx.x >> 7;             // 128 blocks per batch
    int q0 = (blockIdx.x & 127) * 64;
    int t = threadIdx.x;
    for (int i = t; i < N4; i += 256) {
        int p = (i >> 9) * 528 + (i & 511);
        const float* s = xyz4 + (size_t)b * N4 * 3 + (size_t)i * 3;
        xs[p] = s[0]; ys[p] = s[1]; zs[p] = s[2];
    }
    __syncthreads();
    int q = q0 + (t >> 2), c = t & 3;
    float qx = xyz_s1[((size_t)b * 3 + 0) * N1 + q];
    float qy = xyz_s1[((size_t)b * 3 + 1) * N1 + q];
    float qz = xyz_s1[((size_t)b * 3 + 2) * N1 + q];
    float d0 = 3.4e38f, d1 = 3.4e38f, d2 = 3.4e38f;
    int i0 = 0, i1 = 0, i2 = 0;
    int base = c * 528, nb = c * 512;
    for (int ii = 0; ii < 512; ii += 4) {
        float4 x4 = *(float4*)&xs[base + ii];
        float4 y4 = *(float4*)&ys[base + ii];
        float4 z4 = *(float4*)&zs[base + ii];
#pragma unroll
        for (int j = 0; j < 4; ++j) {
            float dx = ((const float*)&x4)[j] - qx;
            float dy = ((const float*)&y4)[j] - qy;
            float dz = ((const float*)&z4)[j] - qz;
            float dd = dx * dx + dy * dy + dz * dz;
            if (dd < d2) {               // strict < is tie-correct for ascending index scan
                int n = nb + ii + j;
                if (dd < d0)      { d2 = d1; i2 = i1; d1 = d0; i1 = i0; d0 = dd; i0 = n; }
                else if (dd < d1) { d2 = d1; i2 = i1; d1 = dd; i1 = n; }
                else              { d2 = dd; i2 = n; }
            }
        }
    }
    // merge the 4 chunk-local top-3 lists (lexicographic (d, idx) insertion)
#pragma unroll
    for (int m = 1; m <= 2; m <<= 1) {
        float e0 = __shfl_xor(d0, m, 64), e1 = __shfl_xor(d1, m, 64), e2 = __shfl_xor(d2, m, 64);
        int   j0 = __shfl_xor(i0, m, 64), j1 = __shfl_xor(i1, m, 64), j2 = __shfl_xor(i2, m, 64);
        float ed[3] = { e0, e1, e2 }; int ej[3] = { j0, j1, j2 };
#pragma unroll
        for (int s = 0; s < 3; ++s) {
            float dd = ed[s]; int jn = ej[s];
            bool lt2 = dd < d2 || (dd == d2 && jn < i2);
            if (lt2) {
                bool lt0 = dd < d0 || (dd == d0 && jn < i0);
                bool lt1 = dd < d1 || (dd == d1 && jn < i1);
                if (lt0)      { d2 = d1; i2 = i1; d1 = d0; i1 = i0; d0 = dd; i0 = jn; }
                else if (lt1) { d2 = d1; i2 = i1; d1 = dd; i1 = jn; }
                else          { d2 = dd; i2 = jn; }
            }
        }
    }
    float w0 = 1.f / (d0 + 1e-8f), w1 = 1.f / (d1 + 1e-8f), w2 = 1.f / (d2 + 1e-8f);
    float inv = 1.f / (w0 + w1 + w2);
    const float* flr = out + FLOWLR_OFF + (size_t)b * 3 * N4;
    if (c < 3) {
        float v = (w0 * flr[c * N4 + i0] + w1 * flr[c * N4 + i1] + w2 * flr[c * N4 + i2]) * inv;
        out[((size_t)b * 3 + c) * N1 + q] = v;
    }
}

extern "C" void kernel_launch(void* const* d_in, const int* in_sizes, int n_in,
                              void* d_out, int out_size, void* d_ws, size_t ws_size,
                              hipStream_t stream) {
    const float* xyz_s1 = (const float*)d_in[0];
    const float* xyz_s4 = (const float*)d_in[1];
    const float* feats  = (const float*)d_in[2];
    const float* sa1_W1 = (const float*)d_in[3];
    const float* sa1_W2 = (const float*)d_in[5];
    const float* sa2_W1 = (const float*)d_in[7];
    const float* sa2_W2 = (const float*)d_in[9];
    const float* fc_W1  = (const float*)d_in[11];
    const float* fc_b1  = (const float*)d_in[12];
    const float* fc_W2  = (const float*)d_in[13];
    const float* fc_b2  = (const float*)d_in[14];
    float* out = (float*)d_out;

    // workspace layout (stays within the round-1-proven 153.3 MB footprint)
    char* wsb = (char*)d_ws;
    float*  xyz4   = (float*)(wsb + 0);                  // 196608 B
    int*    idx    = (int*)(wsb + 196608);               // 2 MB   -> 2293760
    ushort* featTb = (ushort*)(wsb + 2293760);           // 4 MB   -> 6488064   (feats transposed bf16)
    ushort* ymax   = (ushort*)(wsb + 2293760);           // ALIAS: featTb dead after gemm1-SA1
    ushort* featB  = (ushort*)(wsb + 6488064);           // 4 MB   -> 10682368  (SA1 output)
    ushort* featC  = (ushort*)(wsb + 10682368);          // 4 MB   -> 14876672  (SA2 output)
    ushort* W1b1   = (ushort*)(wsb + 14876672);          // 64 KB  -> 14942208
    ushort* W1b2   = (ushort*)(wsb + 14942208);          // 64 KB  -> 15007744
    ushort* W2b1   = (ushort*)(wsb + 15007744);          // 64 KB  -> 15073280
    ushort* W2b2   = (ushort*)(wsb + 15073280);          // 64 KB  -> 15138816
    float*  statsA = (float*)(wsb + 15138816);           // 8 KB each x4 (contiguous)
    float*  statsB = (float*)(wsb + 15147008);
    float*  statsC = (float*)(wsb + 15155200);
    float*  statsD = (float*)(wsb + 15163392);
    ushort* ybuf   = (ushort*)(wsb + 19079168);          // 128 MB -> 153296896

    // ---- setup (fused prep: wconv x4 + xyz transpose + stats zero) ----
    k_prep<<<400, 256, 0, stream>>>(xyz_s4, xyz4, sa1_W1, sa2_W1, sa1_W2, sa2_W2,
                                    W1b1, W1b2, W2b1, W2b2, statsA);
    k_knn<<<B * (N4 / 4), 256, 0, stream>>>(xyz4, idx);
    dim3 gt(B, N4 / 32, CH / 32), bt(32, 8);
    k_feat_t<<<gt, bt, 0, stream>>>(feats, featTb);

    // ---- SA1 ----
    k_sa_gemm1<<<ROWS_TOTAL / 64, 256, 0, stream>>>(featTb, xyz4, idx, W1b1, ybuf, statsA);
    k_sa_gemm2<<<ROWS_TOTAL / 64, 256, 0, stream>>>(ybuf, W2b1, statsA, statsB, ymax);
    k_passC2<<<(B * N4 * 32) / 256, 256, 0, stream>>>(ymax, statsB, featB);

    // ---- SA2 ----
    k_sa_gemm1<<<ROWS_TOTAL / 64, 256, 0, stream>>>(featB, xyz4, idx, W1b2, ybuf, statsC);
    k_sa_gemm2<<<ROWS_TOTAL / 64, 256, 0, stream>>>(ybuf, W2b2, statsC, statsD, ymax);
    k_passC2<<<(B * N4 * 32) / 256, 256, 0, stream>>>(ymax, statsD, featC);

    // ---- FC head + flow_lr ----
    k_fc<<<(B * N4) / 64, 256, 0, stream>>>(featC, fc_W1, fc_b1, fc_W2, fc_b2, out);
    // ---- feature propagation -> flow (1024 blocks: 64 queries/block x 4 threads each) ----
    k_fp<<<B * (N1 / 64), 256, 0, stream>>>(xyz_s1, xyz4, out);
}

// Round 8
// 582.713 us; speedup vs baseline: 6.0619x; 1.0509x over previous
//
#include <hip/hip_runtime.h>
#include <hip/hip_bf16.h>

#define B 8
#define N1 8192
#define N4 2048
#define CH 128
#define KNN 32
#define ROWS_PER_B (N4 * KNN)          // 65536 rows per batch in the [B,N,K] flattening
#define ROWS_TOTAL (B * ROWS_PER_B)    // 524288
#define FLOWLR_OFF (B * 3 * N1)        // flow_lr starts after flow in d_out

typedef unsigned int uint;
typedef unsigned short ushort;
typedef __attribute__((ext_vector_type(8))) short short8;
typedef __attribute__((ext_vector_type(4))) float f32x4;

union U16 { uint4 u; short8 s; };

__device__ __forceinline__ float bf2f(ushort u) {
    union { uint i; float f; } v; v.i = ((uint)u) << 16; return v.f;
}
__device__ __forceinline__ ushort f2b(float f) {
    __hip_bfloat16 h = __float2bfloat16(f);
    return *(ushort*)&h;
}

// ---------------- prep: fused W converters (bf16, permuted/padded) + xyz transpose + stats zero ----------------
__global__ void k_prep(const float* __restrict__ xyz_s4, float* __restrict__ xyz4,
                       const float* __restrict__ sa1_W1, const float* __restrict__ sa2_W1,
                       const float* __restrict__ sa1_W2, const float* __restrict__ sa2_W2,
                       ushort* __restrict__ W1b1, ushort* __restrict__ W1b2,
                       ushort* __restrict__ W2b1, ushort* __restrict__ W2b2,
                       float* __restrict__ stats)
{
    int i = blockIdx.x * 256 + threadIdx.x;
    if (i < 43008) {
        const float* W = (i < 21504) ? sa1_W1 : sa2_W1;
        ushort* o = (i < 21504) ? W1b1 : W1b2;
        int j = (i < 21504) ? i : i - 21504;
        int d = j / 168, c = j - d * 168;
        float v = 0.f;
        if (c < 128)      v = W[d * 131 + 3 + c];
        else if (c < 131) v = W[d * 131 + (c - 128)];
        o[j] = f2b(v);
    } else if (i < 77824) {
        const float* W = (i < 60416) ? sa1_W2 : sa2_W2;
        ushort* o = (i < 60416) ? W2b1 : W2b2;
        int j = (i < 60416) ? i - 43008 : i - 60416;
        int d = j / 136, c = j - d * 136;
        o[j] = (c < 128) ? f2b(W[d * 128 + c]) : (ushort)0;
    } else if (i < 94208) {
        int g = i - 77824;
        int b = g >> 11, n = g & (N4 - 1);
        xyz4[g * 3 + 0] = xyz_s4[(b * 3 + 0) * N4 + n];
        xyz4[g * 3 + 1] = xyz_s4[(b * 3 + 1) * N4 + n];
        xyz4[g * 3 + 2] = xyz_s4[(b * 3 + 2) * N4 + n];
    } else if (i < 102400) {
        stats[i - 94208] = 0.f;        // zeros statsA..statsD (contiguous 8192 floats)
    }
}

// ---------------- transpose feats [B,C,N4] fp32 -> featTb [B,N4,C] bf16 ----------------
__global__ void k_feat_t(const float* __restrict__ feats, ushort* __restrict__ featTb) {
    __shared__ float tile[32][33];
    int b = blockIdx.x, nb = blockIdx.y, cb = blockIdx.z;
    int tx = threadIdx.x, ty = threadIdx.y; // 32 x 8
    int n0 = nb * 32, c0 = cb * 32;
#pragma unroll
    for (int i = 0; i < 4; ++i) {
        int c = c0 + ty + 8 * i;
        tile[ty + 8 * i][tx] = feats[((size_t)b * CH + c) * N4 + n0 + tx];
    }
    __syncthreads();
#pragma unroll
    for (int i = 0; i < 4; ++i) {
        int n = n0 + ty + 8 * i;
        featTb[((size_t)b * N4 + n) * CH + c0 + tx] = f2b(tile[tx][ty + 8 * i]);
    }
}

// ---------------- KNN via exact threshold-select (bisection on fp32 bit pattern) ----------------
__global__ __launch_bounds__(256) void k_knn(const float* __restrict__ xyz4, int* __restrict__ idxout) {
    __shared__ float pts[N4 * 3];
    int b = blockIdx.x >> 9;            // 512 blocks per batch
    int qbase = (blockIdx.x & 511) * 4;
    for (int i = threadIdx.x; i < N4 * 3; i += 256) pts[i] = xyz4[(size_t)b * N4 * 3 + i];
    __syncthreads();
    int wave = threadIdx.x >> 6, lane = threadIdx.x & 63;
    int qn = qbase + wave;
    float qx = pts[qn * 3 + 0], qy = pts[qn * 3 + 1], qz = pts[qn * 3 + 2];
    float d[32];
#pragma unroll
    for (int t = 0; t < 32; ++t) {
        int c = t * 64 + lane;
        float dx = pts[c * 3 + 0] - qx;
        float dy = pts[c * 3 + 1] - qy;
        float dz = pts[c * 3 + 2] - qz;
        d[t] = dx * dx + dy * dy + dz * dz;
    }
    uint lo = 0u, hi = 0x7F800000u;
    int cLT = 0;
    while (hi - lo > 1u) {
        uint mid = (lo + hi) >> 1;
        float fmid = __uint_as_float(mid);
        int c = 0;
#pragma unroll
        for (int t = 0; t < 32; ++t) c += __popcll(__ballot(d[t] < fmid));
        if (c < KNN) { lo = mid; cLT = c; } else hi = mid;
    }
    float T = __uint_as_float(lo);      // T = exact 32nd smallest value; cLT = count(d < T)
    int outb = (b * N4 + qn) * KNN;
    unsigned long long lmlt = (1ull << lane) - 1ull;
    int baseLT = 0, baseEQ = cLT;
#pragma unroll
    for (int t = 0; t < 32; ++t) {
        bool lt = d[t] < T;
        unsigned long long m = __ballot(lt);
        if (lt) idxout[outb + baseLT + __popcll(m & lmlt)] = t * 64 + lane;
        baseLT += __popcll(m);
        bool eq = (d[t] == T);
        unsigned long long me = __ballot(eq);
        if (eq) {
            int rk = baseEQ + __popcll(me & lmlt);
            if (rk < KNN) idxout[outb + rk] = t * 64 + lane;
        }
        baseEQ += __popcll(me);
    }
}

// ---------------- SA stats pass: gather + MFMA1, fused per-(b,c) sum/sumsq, NO output write ----------------
// 256 rows per block (4 sub-tiles of 64): amortizes W-frag loads, 4x fewer atomics.
__global__ __launch_bounds__(256) void k_sa_stats1(
    const ushort* __restrict__ Fb, const float* __restrict__ xyz4,
    const int* __restrict__ idx, const ushort* __restrict__ W1b,
    float* __restrict__ stats)
{
    __shared__ __align__(16) ushort hs[64][168];
    int t = threadIdx.x;
    int r = t >> 2, q = t & 3;
    int l = t & 63, w = t >> 6, lr = l & 15, lg = l >> 4;
    int g0 = blockIdx.x * 256;
    int b = g0 >> 16;
    // zero pad cols 128..167 ONCE (per-subtile staging only touches 0..130)
    {
        uint4 z = make_uint4(0, 0, 0, 0);
        *(uint4*)&hs[r][128 + q * 8] = z;
        if (q == 0) *(uint4*)&hs[r][160] = z;
    }
    // W fragments (held across all 4 sub-tiles)
    U16 bf[5][2];
#pragma unroll
    for (int kc = 0; kc < 5; ++kc)
#pragma unroll
        for (int jj = 0; jj < 2; ++jj)
            bf[kc][jj].u = *(const uint4*)&W1b[(size_t)(w * 32 + jj * 16 + lr) * 168 + kc * 32 + lg * 8];
    float s[2] = {0.f, 0.f}, sq[2] = {0.f, 0.f};
    f32x4 z4 = {0.f, 0.f, 0.f, 0.f};
    for (int st = 0; st < 4; ++st) {
        int g = g0 + st * 64 + r;
        int n = (g & 65535) >> 5;
        int j = idx[g];
        const uint4* src = (const uint4*)(Fb + ((size_t)(b * N4 + j)) * CH) + q * 4;
        uint4* dst = (uint4*)&hs[r][q * 32];
#pragma unroll
        for (int m = 0; m < 4; ++m) dst[m] = src[m];
        if (q == 0) {
            const float* pj = xyz4 + (size_t)(b * N4 + j) * 3;
            const float* pn = xyz4 + (size_t)(b * N4 + n) * 3;
            hs[r][128] = f2b(pj[0] - pn[0]);
            hs[r][129] = f2b(pj[1] - pn[1]);
            hs[r][130] = f2b(pj[2] - pn[2]);
        }
        __syncthreads();
        f32x4 acc[4][2];
#pragma unroll
        for (int i = 0; i < 4; ++i) { acc[i][0] = z4; acc[i][1] = z4; }
#pragma unroll
        for (int kc = 0; kc < 5; ++kc) {
            U16 a[4];
#pragma unroll
            for (int i = 0; i < 4; ++i) a[i].u = *(const uint4*)&hs[16 * i + lr][kc * 32 + lg * 8];
#pragma unroll
            for (int i = 0; i < 4; ++i)
#pragma unroll
                for (int jj = 0; jj < 2; ++jj)
                    acc[i][jj] = __builtin_amdgcn_mfma_f32_16x16x32_bf16(a[i].s, bf[kc][jj].s, acc[i][jj], 0, 0, 0);
        }
#pragma unroll
        for (int jj = 0; jj < 2; ++jj)
#pragma unroll
            for (int i = 0; i < 4; ++i)
#pragma unroll
                for (int rg = 0; rg < 4; ++rg) {
                    float v = acc[i][jj][rg];
                    s[jj] += v; sq[jj] += v * v;
                }
        __syncthreads();   // all reads done before next sub-tile's staging
    }
#pragma unroll
    for (int jj = 0; jj < 2; ++jj) {
        int c = w * 32 + jj * 16 + lr;
        float ss = s[jj], qq = sq[jj];
        ss += __shfl_xor(ss, 16, 64); ss += __shfl_xor(ss, 32, 64);
        qq += __shfl_xor(qq, 16, 64); qq += __shfl_xor(qq, 32, 64);
        if (lg == 0) {
            atomicAdd(&stats[b * CH + c], ss);
            atomicAdd(&stats[B * CH + b * CH + c], qq);
        }
    }
}

// ---------------- SA fused pass: gather + MFMA1 recompute + in-reg norm+relu + MFMA2 + stats2 + k-max ----------------
// Never materializes y1 or y2: block = 2 points x 32 neighbors; writes ymax bf16 [B*N4][128].
// NOTE: ymax must NOT alias Fb — this kernel reads Fb and writes ymax concurrently across blocks.
__global__ __launch_bounds__(256) void k_sa_fused(
    const ushort* __restrict__ Fb, const float* __restrict__ xyz4,
    const int* __restrict__ idx, const ushort* __restrict__ W1b,
    const ushort* __restrict__ W2b, const float* __restrict__ stats1,
    float* __restrict__ stats2, ushort* __restrict__ ymax)
{
    __shared__ __align__(16) ushort hs[64][168];
    __shared__ float smean[128], sinv[128];
    int t = threadIdx.x;
    int g0 = blockIdx.x * 64;
    int b = g0 >> 16;
    if (t < 128) {
        float s = stats1[b * CH + t], q2 = stats1[B * CH + b * CH + t];
        float mean = s * (1.f / ROWS_PER_B);
        float var = q2 * (1.f / ROWS_PER_B) - mean * mean;
        smean[t] = mean; sinv[t] = rsqrtf(var + 1e-5f);
    }
    // --- stage gathered h1 rows ---
    int r = t >> 2, q = t & 3;
    {
        int g = g0 + r;
        int n = (g & 65535) >> 5;
        int j = idx[g];
        const uint4* src = (const uint4*)(Fb + ((size_t)(b * N4 + j)) * CH) + q * 4;
        uint4* dst = (uint4*)&hs[r][q * 32];
#pragma unroll
        for (int m = 0; m < 4; ++m) dst[m] = src[m];
        uint4 z = make_uint4(0, 0, 0, 0);
        *(uint4*)&hs[r][128 + q * 8] = z;
        if (q == 0) {
            *(uint4*)&hs[r][160] = z;
            const float* pj = xyz4 + (size_t)(b * N4 + j) * 3;
            const float* pn = xyz4 + (size_t)(b * N4 + n) * 3;
            hs[r][128] = f2b(pj[0] - pn[0]);
            hs[r][129] = f2b(pj[1] - pn[1]);
            hs[r][130] = f2b(pj[2] - pn[2]);
        }
    }
    int l = t & 63, w = t >> 6, lr = l & 15, lg = l >> 4;
    // W1 + W2 fragments
    U16 b1f[5][2], b2f[4][2];
#pragma unroll
    for (int kc = 0; kc < 5; ++kc)
#pragma unroll
        for (int jj = 0; jj < 2; ++jj)
            b1f[kc][jj].u = *(const uint4*)&W1b[(size_t)(w * 32 + jj * 16 + lr) * 168 + kc * 32 + lg * 8];
#pragma unroll
    for (int kc = 0; kc < 4; ++kc)
#pragma unroll
        for (int jj = 0; jj < 2; ++jj)
            b2f[kc][jj].u = *(const uint4*)&W2b[(size_t)(w * 32 + jj * 16 + lr) * 136 + kc * 32 + lg * 8];
    __syncthreads();   // staging + smean/sinv ready
    float smc[2], sic[2];
#pragma unroll
    for (int jj = 0; jj < 2; ++jj) {
        int c = w * 32 + jj * 16 + lr;
        smc[jj] = smean[c]; sic[jj] = sinv[c];
    }
    // --- MFMA1: y1 = h1 @ W1^T ---
    f32x4 acc[4][2];
    f32x4 z4 = {0.f, 0.f, 0.f, 0.f};
#pragma unroll
    for (int i = 0; i < 4; ++i) { acc[i][0] = z4; acc[i][1] = z4; }
#pragma unroll
    for (int kc = 0; kc < 5; ++kc) {
        U16 a[4];
#pragma unroll
        for (int i = 0; i < 4; ++i) a[i].u = *(const uint4*)&hs[16 * i + lr][kc * 32 + lg * 8];
#pragma unroll
        for (int i = 0; i < 4; ++i)
#pragma unroll
            for (int jj = 0; jj < 2; ++jj)
                acc[i][jj] = __builtin_amdgcn_mfma_f32_16x16x32_bf16(a[i].s, b1f[kc][jj].s, acc[i][jj], 0, 0, 0);
    }
    __syncthreads();   // h1 reads complete -> reuse hs for normalized h2
    // --- normalize+relu on fp32 acc, repack transposed into LDS ---
#pragma unroll
    for (int jj = 0; jj < 2; ++jj) {
        int c = w * 32 + jj * 16 + lr;
#pragma unroll
        for (int i = 0; i < 4; ++i)
#pragma unroll
            for (int rg = 0; rg < 4; ++rg)
                hs[16 * i + lg * 4 + rg][c] = f2b(fmaxf((acc[i][jj][rg] - smc[jj]) * sic[jj], 0.f));
    }
    __syncthreads();
    // --- MFMA2: y2 = h2 @ W2^T (K=128: chunks 0..3 of hs) ---
#pragma unroll
    for (int i = 0; i < 4; ++i) { acc[i][0] = z4; acc[i][1] = z4; }
#pragma unroll
    for (int kc = 0; kc < 4; ++kc) {
        U16 a[4];
#pragma unroll
        for (int i = 0; i < 4; ++i) a[i].u = *(const uint4*)&hs[16 * i + lr][kc * 32 + lg * 8];
#pragma unroll
        for (int i = 0; i < 4; ++i)
#pragma unroll
            for (int jj = 0; jj < 2; ++jj)
                acc[i][jj] = __builtin_amdgcn_mfma_f32_16x16x32_bf16(a[i].s, b2f[kc][jj].s, acc[i][jj], 0, 0, 0);
    }
    // --- epilogue: fused stats2 (pre-max) + k-max over 32 neighbors of each of the 2 points ---
    int gp0 = g0 >> 5;
#pragma unroll
    for (int jj = 0; jj < 2; ++jj) {
        int c = w * 32 + jj * 16 + lr;
        float s = 0.f, sq = 0.f;
        float m0 = -3.4e38f, m1 = -3.4e38f;
#pragma unroll
        for (int i = 0; i < 4; ++i)
#pragma unroll
            for (int rg = 0; rg < 4; ++rg) {
                float v = acc[i][jj][rg];
                s += v; sq += v * v;
                if (i < 2) m0 = fmaxf(m0, v); else m1 = fmaxf(m1, v);
            }
        s  += __shfl_xor(s, 16, 64);  s  += __shfl_xor(s, 32, 64);
        sq += __shfl_xor(sq, 16, 64); sq += __shfl_xor(sq, 32, 64);
        m0 = fmaxf(m0, __shfl_xor(m0, 16, 64)); m0 = fmaxf(m0, __shfl_xor(m0, 32, 64));
        m1 = fmaxf(m1, __shfl_xor(m1, 16, 64)); m1 = fmaxf(m1, __shfl_xor(m1, 32, 64));
        if (lg == 0) {
            atomicAdd(&stats2[b * CH + c], s);
            atomicAdd(&stats2[B * CH + b * CH + c], sq);
            ymax[(size_t)gp0 * CH + c] = f2b(m0);
            ymax[(size_t)(gp0 + 1) * CH + c] = f2b(m1);
        }
    }
}

// ---------------- pass C: norm+relu on pooled maxes -> bf16 features ----------------
__global__ void k_passC2(const ushort* __restrict__ ymax, const float* __restrict__ stats,
                         ushort* __restrict__ outp)
{
    int e = blockIdx.x * 256 + threadIdx.x;    // handles 4 cols; total B*N4*32 threads
    int row = e >> 5, cq = (e & 31) * 4;
    int b = row >> 11;
    uint2 v = *(const uint2*)&ymax[(size_t)row * CH + cq];
    float f[4] = { bf2f((ushort)(v.x & 0xffff)), bf2f((ushort)(v.x >> 16)),
                   bf2f((ushort)(v.y & 0xffff)), bf2f((ushort)(v.y >> 16)) };
    uint2 o2;
    ushort o[4];
#pragma unroll
    for (int j = 0; j < 4; ++j) {
        int c = cq + j;
        float mean = stats[b * CH + c] * (1.f / ROWS_PER_B);
        float var = stats[B * CH + b * CH + c] * (1.f / ROWS_PER_B) - mean * mean;
        o[j] = f2b(fmaxf((f[j] - mean) * rsqrtf(var + 1e-5f), 0.f));
    }
    o2.x = (uint)o[0] | ((uint)o[1] << 16);
    o2.y = (uint)o[2] | ((uint)o[3] << 16);
    *(uint2*)&outp[(size_t)row * CH + cq] = o2;
}

// ---------------- FC head: relu(X@W1^T+b1) @ W2^T + b2 -> flow_lr [B,3,N4] in d_out ----------------
__global__ __launch_bounds__(256, 1) void k_fc(
    const ushort* __restrict__ X, const float* __restrict__ W1,
    const float* __restrict__ b1, const float* __restrict__ W2,
    const float* __restrict__ b2, float* __restrict__ out)
{
    __shared__ float hs[64][132];
    __shared__ float ws[128][132];
    int t = threadIdx.x;
    for (int i = t; i < 128 * 132; i += 256) {
        int dd = i / 132, c = i - dd * 132;
        ws[dd][c] = (c < 128) ? W1[dd * 128 + c] : 0.f;
    }
    int r = t >> 2, q = t & 3;
    int g0 = blockIdx.x * 64;
    {
        const uint4* Xrow = (const uint4*)(X + (size_t)(g0 + r) * CH + q * 32);
#pragma unroll
        for (int m = 0; m < 4; ++m) {
            uint4 v = Xrow[m];
            const uint* pv = (const uint*)&v;
            int c0 = q * 32 + m * 8;
#pragma unroll
            for (int e = 0; e < 4; ++e) {
                hs[r][c0 + 2 * e]     = bf2f((ushort)(pv[e] & 0xffff));
                hs[r][c0 + 2 * e + 1] = bf2f((ushort)(pv[e] >> 16));
            }
        }
        if (q == 0) *(float4*)&hs[r][128] = make_float4(0.f, 0.f, 0.f, 0.f);
    }
    __syncthreads();
    int tx = t & 15, ty = t >> 4;
    float acc[4][8];
#pragma unroll
    for (int i = 0; i < 4; ++i)
#pragma unroll
        for (int jj = 0; jj < 8; ++jj) acc[i][jj] = 0.f;
    for (int kb = 0; kb < 33; ++kb) {
        float4 a[4]; float4 w[8];
#pragma unroll
        for (int i = 0; i < 4; ++i) a[i] = *(float4*)&hs[ty * 4 + i][kb * 4];
#pragma unroll
        for (int jj = 0; jj < 8; ++jj) w[jj] = *(float4*)&ws[tx + 16 * jj][kb * 4];
#pragma unroll
        for (int i = 0; i < 4; ++i)
#pragma unroll
            for (int jj = 0; jj < 8; ++jj)
                acc[i][jj] += a[i].x * w[jj].x + a[i].y * w[jj].y
                            + a[i].z * w[jj].z + a[i].w * w[jj].w;
    }
    __syncthreads();                     // done reading hs
#pragma unroll
    for (int jj = 0; jj < 8; ++jj) {
        int c = tx + 16 * jj;
        float bias = b1[c];
#pragma unroll
        for (int i = 0; i < 4; ++i)
            hs[ty * 4 + i][c] = fmaxf(acc[i][jj] + bias, 0.f);
    }
    __syncthreads();
    if (t < 192) {
        int rr = t / 3, o = t - rr * 3;
        float sum = b2[o];
        for (int c = 0; c < 128; ++c) sum += hs[rr][c] * W2[o * 128 + c];
        int g = g0 + rr;
        int b = g >> 11, n = g & (N4 - 1);
        out[FLOWLR_OFF + ((size_t)b * 3 + o) * N4 + n] = sum;
    }
}

// ---------------- feature propagation: 3-NN inverse-sqdist interp onto xyz1 ----------------
// GRID: B * (N1/64) = 1024 blocks (64 queries per block, 4 threads each).
__global__ __launch_bounds__(256) void k_fp(
    const float* __restrict__ xyz_s1, const float* __restrict__ xyz4,
    float* __restrict__ out)
{
    __shared__ float xs[4 * 528], ys[4 * 528], zs[4 * 528];
    int b = blockIdx.x >> 7;             // 128 blocks per batch
    int q0 = (blockIdx.x & 127) * 64;
    int t = threadIdx.x;
    for (int i = t; i < N4; i += 256) {
        int p = (i >> 9) * 528 + (i & 511);
        const float* s = xyz4 + (size_t)b * N4 * 3 + (size_t)i * 3;
        xs[p] = s[0]; ys[p] = s[1]; zs[p] = s[2];
    }
    __syncthreads();
    int q = q0 + (t >> 2), c = t & 3;
    float qx = xyz_s1[((size_t)b * 3 + 0) * N1 + q];
    float qy = xyz_s1[((size_t)b * 3 + 1) * N1 + q];
    float qz = xyz_s1[((size_t)b * 3 + 2) * N1 + q];
    float d0 = 3.4e38f, d1 = 3.4e38f, d2 = 3.4e38f;
    int i0 = 0, i1 = 0, i2 = 0;
    int base = c * 528, nb = c * 512;
    for (int ii = 0; ii < 512; ii += 4) {
        float4 x4 = *(float4*)&xs[base + ii];
        float4 y4 = *(float4*)&ys[base + ii];
        float4 z4 = *(float4*)&zs[base + ii];
#pragma unroll
        for (int j = 0; j < 4; ++j) {
            float dx = ((const float*)&x4)[j] - qx;
            float dy = ((const float*)&y4)[j] - qy;
            float dz = ((const float*)&z4)[j] - qz;
            float dd = dx * dx + dy * dy + dz * dz;
            if (dd < d2) {
                int n = nb + ii + j;
                if (dd < d0)      { d2 = d1; i2 = i1; d1 = d0; i1 = i0; d0 = dd; i0 = n; }
                else if (dd < d1) { d2 = d1; i2 = i1; d1 = dd; i1 = n; }
                else              { d2 = dd; i2 = n; }
            }
        }
    }
#pragma unroll
    for (int m = 1; m <= 2; m <<= 1) {
        float e0 = __shfl_xor(d0, m, 64), e1 = __shfl_xor(d1, m, 64), e2 = __shfl_xor(d2, m, 64);
        int   j0 = __shfl_xor(i0, m, 64), j1 = __shfl_xor(i1, m, 64), j2 = __shfl_xor(i2, m, 64);
        float ed[3] = { e0, e1, e2 }; int ej[3] = { j0, j1, j2 };
#pragma unroll
        for (int s = 0; s < 3; ++s) {
            float dd = ed[s]; int jn = ej[s];
            bool lt2 = dd < d2 || (dd == d2 && jn < i2);
            if (lt2) {
                bool lt0 = dd < d0 || (dd == d0 && jn < i0);
                bool lt1 = dd < d1 || (dd == d1 && jn < i1);
                if (lt0)      { d2 = d1; i2 = i1; d1 = d0; i1 = i0; d0 = dd; i0 = jn; }
                else if (lt1) { d2 = d1; i2 = i1; d1 = dd; i1 = jn; }
                else          { d2 = dd; i2 = jn; }
            }
        }
    }
    float w0 = 1.f / (d0 + 1e-8f), w1 = 1.f / (d1 + 1e-8f), w2 = 1.f / (d2 + 1e-8f);
    float inv = 1.f / (w0 + w1 + w2);
    const float* flr = out + FLOWLR_OFF + (size_t)b * 3 * N4;
    if (c < 3) {
        float v = (w0 * flr[c * N4 + i0] + w1 * flr[c * N4 + i1] + w2 * flr[c * N4 + i2]) * inv;
        out[((size_t)b * 3 + c) * N1 + q] = v;
    }
}

extern "C" void kernel_launch(void* const* d_in, const int* in_sizes, int n_in,
                              void* d_out, int out_size, void* d_ws, size_t ws_size,
                              hipStream_t stream) {
    const float* xyz_s1 = (const float*)d_in[0];
    const float* xyz_s4 = (const float*)d_in[1];
    const float* feats  = (const float*)d_in[2];
    const float* sa1_W1 = (const float*)d_in[3];
    const float* sa1_W2 = (const float*)d_in[5];
    const float* sa2_W1 = (const float*)d_in[7];
    const float* sa2_W2 = (const float*)d_in[9];
    const float* fc_W1  = (const float*)d_in[11];
    const float* fc_b1  = (const float*)d_in[12];
    const float* fc_W2  = (const float*)d_in[13];
    const float* fc_b2  = (const float*)d_in[14];
    float* out = (float*)d_out;

    char* wsb = (char*)d_ws;
    float*  xyz4   = (float*)(wsb + 0);                  // 196608 B
    int*    idx    = (int*)(wsb + 196608);               // 2 MB   -> 2293760
    ushort* featTb = (ushort*)(wsb + 2293760);           // 4 MB   -> 6488064   (feats transposed bf16)
    ushort* featB  = (ushort*)(wsb + 6488064);           // 4 MB   -> 10682368  (SA1 output)
    ushort* featC  = (ushort*)(wsb + 10682368);          // 4 MB   -> 14876672  (SA2 output)
    ushort* W1b1   = (ushort*)(wsb + 14876672);          // 64 KB  -> 14942208
    ushort* W1b2   = (ushort*)(wsb + 14942208);          // 64 KB  -> 15007744
    ushort* W2b1   = (ushort*)(wsb + 15007744);          // 64 KB  -> 15073280
    ushort* W2b2   = (ushort*)(wsb + 15073280);          // 64 KB  -> 15138816
    float*  statsA = (float*)(wsb + 15138816);           // 8 KB each x4 (contiguous)
    float*  statsB = (float*)(wsb + 15147008);
    float*  statsC = (float*)(wsb + 15155200);
    float*  statsD = (float*)(wsb + 15163392);
    ushort* ymax   = (ushort*)(wsb + 15171584);          // 4 MB -> 19365888  (DEDICATED: k_sa_fused
                                                         // reads feat* and writes ymax concurrently)

    // ---- setup (fused prep: wconv x4 + xyz transpose + stats zero) ----
    k_prep<<<400, 256, 0, stream>>>(xyz_s4, xyz4, sa1_W1, sa2_W1, sa1_W2, sa2_W2,
                                    W1b1, W1b2, W2b1, W2b2, statsA);
    k_knn<<<B * (N4 / 4), 256, 0, stream>>>(xyz4, idx);
    dim3 gt(B, N4 / 32, CH / 32), bt(32, 8);
    k_feat_t<<<gt, bt, 0, stream>>>(feats, featTb);

    // ---- SA1: stats pass (no write) + fused recompute pass ----
    k_sa_stats1<<<ROWS_TOTAL / 256, 256, 0, stream>>>(featTb, xyz4, idx, W1b1, statsA);
    k_sa_fused<<<ROWS_TOTAL / 64, 256, 0, stream>>>(featTb, xyz4, idx, W1b1, W2b1,
                                                    statsA, statsB, ymax);
    k_passC2<<<(B * N4 * 32) / 256, 256, 0, stream>>>(ymax, statsB, featB);

    // ---- SA2 ----
    k_sa_stats1<<<ROWS_TOTAL / 256, 256, 0, stream>>>(featB, xyz4, idx, W1b2, statsC);
    k_sa_fused<<<ROWS_TOTAL / 64, 256, 0, stream>>>(featB, xyz4, idx, W1b2, W2b2,
                                                    statsC, statsD, ymax);
    k_passC2<<<(B * N4 * 32) / 256, 256, 0, stream>>>(ymax, statsD, featC);

    // ---- FC head + flow_lr ----
    k_fc<<<(B * N4) / 64, 256, 0, stream>>>(featC, fc_W1, fc_b1, fc_W2, fc_b2, out);
    // ---- feature propagation -> flow ----
    k_fp<<<B * (N1 / 64), 256, 0, stream>>>(xyz_s1, xyz4, out);
}

// Round 9
// 540.317 us; speedup vs baseline: 6.5375x; 1.0785x over previous
//
#include <hip/hip_runtime.h>
#include <hip/hip_bf16.h>

#define B 8
#define N1 8192
#define N4 2048
#define CH 128
#define KNN 32
#define ROWS_PER_B (N4 * KNN)          // 65536 rows per batch in the [B,N,K] flattening
#define ROWS_TOTAL (B * ROWS_PER_B)    // 524288
#define NPTS (B * N4)                  // 16384 total points
#define FLOWLR_OFF (B * 3 * N1)        // flow_lr starts after flow in d_out

typedef unsigned int uint;
typedef unsigned short ushort;
typedef __attribute__((ext_vector_type(8))) short short8;
typedef __attribute__((ext_vector_type(4))) float f32x4;

union U16 { uint4 u; short8 s; };

__device__ __forceinline__ float bf2f(ushort u) {
    union { uint i; float f; } v; v.i = ((uint)u) << 16; return v.f;
}
__device__ __forceinline__ ushort f2b(float f) {
    __hip_bfloat16 h = __float2bfloat16(f);
    return *(ushort*)&h;
}

// ---------------- prep: fused W converters (bf16, permuted/padded) + xyz transpose + stats zero ----------------
__global__ void k_prep(const float* __restrict__ xyz_s4, float* __restrict__ xyz4,
                       const float* __restrict__ sa1_W1, const float* __restrict__ sa2_W1,
                       const float* __restrict__ sa1_W2, const float* __restrict__ sa2_W2,
                       ushort* __restrict__ W1b1, ushort* __restrict__ W1b2,
                       ushort* __restrict__ W2b1, ushort* __restrict__ W2b2,
                       float* __restrict__ stats)
{
    int i = blockIdx.x * 256 + threadIdx.x;
    if (i < 43008) {
        const float* W = (i < 21504) ? sa1_W1 : sa2_W1;
        ushort* o = (i < 21504) ? W1b1 : W1b2;
        int j = (i < 21504) ? i : i - 21504;
        int d = j / 168, c = j - d * 168;
        float v = 0.f;
        if (c < 128)      v = W[d * 131 + 3 + c];
        else if (c < 131) v = W[d * 131 + (c - 128)];
        o[j] = f2b(v);
    } else if (i < 77824) {
        const float* W = (i < 60416) ? sa1_W2 : sa2_W2;
        ushort* o = (i < 60416) ? W2b1 : W2b2;
        int j = (i < 60416) ? i - 43008 : i - 60416;
        int d = j / 136, c = j - d * 136;
        o[j] = (c < 128) ? f2b(W[d * 128 + c]) : (ushort)0;
    } else if (i < 94208) {
        int g = i - 77824;
        int b = g >> 11, n = g & (N4 - 1);
        xyz4[g * 3 + 0] = xyz_s4[(b * 3 + 0) * N4 + n];
        xyz4[g * 3 + 1] = xyz_s4[(b * 3 + 1) * N4 + n];
        xyz4[g * 3 + 2] = xyz_s4[(b * 3 + 2) * N4 + n];
    } else if (i < 102400) {
        stats[i - 94208] = 0.f;        // zeros statsA..statsD (contiguous 8192 floats)
    }
}

// ---------------- transpose feats [B,C,N4] fp32 -> featTb [B,N4,C] bf16 ----------------
__global__ void k_feat_t(const float* __restrict__ feats, ushort* __restrict__ featTb) {
    __shared__ float tile[32][33];
    int b = blockIdx.x, nb = blockIdx.y, cb = blockIdx.z;
    int tx = threadIdx.x, ty = threadIdx.y; // 32 x 8
    int n0 = nb * 32, c0 = cb * 32;
#pragma unroll
    for (int i = 0; i < 4; ++i) {
        int c = c0 + ty + 8 * i;
        tile[ty + 8 * i][tx] = feats[((size_t)b * CH + c) * N4 + n0 + tx];
    }
    __syncthreads();
#pragma unroll
    for (int i = 0; i < 4; ++i) {
        int n = n0 + ty + 8 * i;
        featTb[((size_t)b * N4 + n) * CH + c0 + tx] = f2b(tile[tx][ty + 8 * i]);
    }
}

// ---------------- KNN via exact threshold-select (bisection on fp32 bit pattern) ----------------
__global__ __launch_bounds__(256) void k_knn(const float* __restrict__ xyz4, int* __restrict__ idxout) {
    __shared__ float pts[N4 * 3];
    int b = blockIdx.x >> 9;            // 512 blocks per batch
    int qbase = (blockIdx.x & 511) * 4;
    for (int i = threadIdx.x; i < N4 * 3; i += 256) pts[i] = xyz4[(size_t)b * N4 * 3 + i];
    __syncthreads();
    int wave = threadIdx.x >> 6, lane = threadIdx.x & 63;
    int qn = qbase + wave;
    float qx = pts[qn * 3 + 0], qy = pts[qn * 3 + 1], qz = pts[qn * 3 + 2];
    float d[32];
#pragma unroll
    for (int t = 0; t < 32; ++t) {
        int c = t * 64 + lane;
        float dx = pts[c * 3 + 0] - qx;
        float dy = pts[c * 3 + 1] - qy;
        float dz = pts[c * 3 + 2] - qz;
        d[t] = dx * dx + dy * dy + dz * dz;
    }
    uint lo = 0u, hi = 0x7F800000u;
    int cLT = 0;
    while (hi - lo > 1u) {
        uint mid = (lo + hi) >> 1;
        float fmid = __uint_as_float(mid);
        int c = 0;
#pragma unroll
        for (int t = 0; t < 32; ++t) c += __popcll(__ballot(d[t] < fmid));
        if (c < KNN) { lo = mid; cLT = c; } else hi = mid;
    }
    float T = __uint_as_float(lo);      // T = exact 32nd smallest value; cLT = count(d < T)
    int outb = (b * N4 + qn) * KNN;
    unsigned long long lmlt = (1ull << lane) - 1ull;
    int baseLT = 0, baseEQ = cLT;
#pragma unroll
    for (int t = 0; t < 32; ++t) {
        bool lt = d[t] < T;
        unsigned long long m = __ballot(lt);
        if (lt) idxout[outb + baseLT + __popcll(m & lmlt)] = t * 64 + lane;
        baseLT += __popcll(m);
        bool eq = (d[t] == T);
        unsigned long long me = __ballot(eq);
        if (eq) {
            int rk = baseEQ + __popcll(me & lmlt);
            if (rk < KNN) idxout[outb + rk] = t * 64 + lane;
        }
        baseEQ += __popcll(me);
    }
}

// ---------------- dense z GEMM: z[p] = [feat_p | xyz_p] @ W1^T (fp32 out) ----------------
// Decomposition: y1[n,k] = z[j(n,k)] - u[n]. 16384 dense rows instead of 524288 gathered.
__global__ __launch_bounds__(256) void k_dense(
    const ushort* __restrict__ Fb, const float* __restrict__ xyz4,
    const ushort* __restrict__ W1b, float* __restrict__ z)
{
    __shared__ __align__(16) ushort hs[64][168];
    int t = threadIdx.x;
    int r = t >> 2, q = t & 3;
    int l = t & 63, w = t >> 6, lr = l & 15, lg = l >> 4;
    int g0 = blockIdx.x * 64;
    {
        int p = g0 + r;
        const uint4* src = (const uint4*)(Fb + (size_t)p * CH) + q * 4;
        uint4* dst = (uint4*)&hs[r][q * 32];
#pragma unroll
        for (int m = 0; m < 4; ++m) dst[m] = src[m];
        uint4 zz = make_uint4(0, 0, 0, 0);
        *(uint4*)&hs[r][128 + q * 8] = zz;
        if (q == 0) {
            *(uint4*)&hs[r][160] = zz;
            hs[r][128] = f2b(xyz4[p * 3 + 0]);
            hs[r][129] = f2b(xyz4[p * 3 + 1]);
            hs[r][130] = f2b(xyz4[p * 3 + 2]);
        }
    }
    U16 bf[5][2];
#pragma unroll
    for (int kc = 0; kc < 5; ++kc)
#pragma unroll
        for (int jj = 0; jj < 2; ++jj)
            bf[kc][jj].u = *(const uint4*)&W1b[(size_t)(w * 32 + jj * 16 + lr) * 168 + kc * 32 + lg * 8];
    __syncthreads();
    f32x4 acc[4][2];
    f32x4 z4 = {0.f, 0.f, 0.f, 0.f};
#pragma unroll
    for (int i = 0; i < 4; ++i) { acc[i][0] = z4; acc[i][1] = z4; }
#pragma unroll
    for (int kc = 0; kc < 5; ++kc) {
        U16 a[4];
#pragma unroll
        for (int i = 0; i < 4; ++i) a[i].u = *(const uint4*)&hs[16 * i + lr][kc * 32 + lg * 8];
#pragma unroll
        for (int i = 0; i < 4; ++i)
#pragma unroll
            for (int jj = 0; jj < 2; ++jj)
                acc[i][jj] = __builtin_amdgcn_mfma_f32_16x16x32_bf16(a[i].s, bf[kc][jj].s, acc[i][jj], 0, 0, 0);
    }
#pragma unroll
    for (int jj = 0; jj < 2; ++jj)
#pragma unroll
        for (int i = 0; i < 4; ++i)
#pragma unroll
            for (int rg = 0; rg < 4; ++rg)
                z[(size_t)(g0 + 16 * i + lg * 4 + rg) * CH + w * 32 + jj * 16 + lr] = acc[i][jj][rg];
}

// ---------------- u[p] = bf16(xyz_p) @ bf16(W1x)^T (fp32, matches z's rounding) ----------------
__global__ void k_u(const float* __restrict__ xyz4, const ushort* __restrict__ W1b,
                    float* __restrict__ u)
{
    int e = blockIdx.x * 256 + threadIdx.x;   // NPTS*32 threads; 4 cols each
    int p = e >> 5, i = e & 31;
    float x = bf2f(f2b(xyz4[p * 3 + 0]));
    float y = bf2f(f2b(xyz4[p * 3 + 1]));
    float zc = bf2f(f2b(xyz4[p * 3 + 2]));
    float4 o;
#pragma unroll
    for (int jj = 0; jj < 4; ++jj) {
        int c = i * 4 + jj;
        ((float*)&o)[jj] = x * bf2f(W1b[c * 168 + 128])
                         + y * bf2f(W1b[c * 168 + 129])
                         + zc * bf2f(W1b[c * 168 + 130]);
    }
    *(float4*)&u[(size_t)p * CH + i * 4] = o;
}

// ---------------- gather-stats: per-(b,c) sum/sumsq of y1 = z[j]-u[n], NO MFMA ----------------
// Block = 32 points; thread = (point, 16-col slice). S = sum_n(s_n - 32 u_n),
// SQ = sum_n(q_n - 2 u_n s_n + 32 u_n^2) with s_n,q_n = per-point gather sums of z, z^2.
__global__ __launch_bounds__(256) void k_gstats(
    const float* __restrict__ z, const float* __restrict__ u,
    const int* __restrict__ idx, float* __restrict__ stats)
{
    __shared__ int idxs[32 * KNN];
    __shared__ float sacc[128], sqacc[128];
    int t = threadIdx.x;
    int gpb = blockIdx.x * 32;
    int b = gpb >> 11;
    for (int ii = t; ii < 32 * KNN; ii += 256) idxs[ii] = idx[(size_t)gpb * KNN + ii];
    if (t < 128) { sacc[t] = 0.f; sqacc[t] = 0.f; }
    __syncthreads();
    int li = t >> 3, cq = (t & 7) * 16;
    int gp = gpb + li;
    float s[16], qa[16];
#pragma unroll
    for (int m = 0; m < 16; ++m) { s[m] = 0.f; qa[m] = 0.f; }
    int zb = b * N4;
#pragma unroll 4
    for (int k = 0; k < KNN; ++k) {
        int j = idxs[li * KNN + k];
        const float4* zr = (const float4*)(z + (size_t)(zb + j) * CH + cq);
#pragma unroll
        for (int m = 0; m < 4; ++m) {
            float4 v = zr[m];
#pragma unroll
            for (int e = 0; e < 4; ++e) {
                float vv = ((const float*)&v)[e];
                s[m * 4 + e] += vv; qa[m * 4 + e] += vv * vv;
            }
        }
    }
    const float4* ur = (const float4*)(u + (size_t)gp * CH + cq);
#pragma unroll
    for (int m = 0; m < 4; ++m) {
        float4 uv = ur[m];
#pragma unroll
        for (int e = 0; e < 4; ++e) {
            float uu = ((const float*)&uv)[e];
            float ss = s[m * 4 + e], qq = qa[m * 4 + e];
            atomicAdd(&sacc[cq + m * 4 + e], ss - 32.f * uu);
            atomicAdd(&sqacc[cq + m * 4 + e], qq - 2.f * uu * ss + 32.f * uu * uu);
        }
    }
    __syncthreads();
    if (t < 128) {
        atomicAdd(&stats[b * CH + t], sacc[t]);
        atomicAdd(&stats[B * CH + b * CH + t], sqacc[t]);
    }
}

// ---------------- fused pass: gather z, y1=z-u, norm+relu -> bf16 LDS, MFMA2, stats2 + k-max ----------------
__global__ __launch_bounds__(256) void k_fused2(
    const float* __restrict__ z, const float* __restrict__ u,
    const int* __restrict__ idx, const ushort* __restrict__ W2b,
    const float* __restrict__ stats1, float* __restrict__ stats2,
    ushort* __restrict__ ymax)
{
    __shared__ __align__(16) ushort hs[64][136];
    __shared__ float smean[128], sinv[128];
    __shared__ float us[2][128];
    int t = threadIdx.x;
    int g0 = blockIdx.x * 64;
    int b = g0 >> 16;
    int gp0 = g0 >> 5;
    int l = t & 63, w = t >> 6, lr = l & 15, lg = l >> 4;
    U16 b2f[4][2];
#pragma unroll
    for (int kc = 0; kc < 4; ++kc)
#pragma unroll
        for (int jj = 0; jj < 2; ++jj)
            b2f[kc][jj].u = *(const uint4*)&W2b[(size_t)(w * 32 + jj * 16 + lr) * 136 + kc * 32 + lg * 8];
    if (t < 128) {
        float s = stats1[b * CH + t], q2 = stats1[B * CH + b * CH + t];
        float mean = s * (1.f / ROWS_PER_B);
        float var = q2 * (1.f / ROWS_PER_B) - mean * mean;
        smean[t] = mean; sinv[t] = rsqrtf(var + 1e-5f);
    }
    if (t < 64) {
        int row = t >> 5, i = t & 31;
        *(float4*)&us[row][i * 4] = *(const float4*)&u[(size_t)(gp0 + row) * CH + i * 4];
    }
    int r = t >> 2, q = t & 3;
    int j = idx[g0 + r];
    float4 zv[8];
    {
        const float4* zr = (const float4*)(z + (size_t)(b * N4 + j) * CH + q * 32);
#pragma unroll
        for (int m = 0; m < 8; ++m) zv[m] = zr[m];
    }
    __syncthreads();   // smean/sinv/us ready
    {
        int urow = r >> 5;
#pragma unroll
        for (int mm = 0; mm < 4; ++mm) {
            ushort o[8];
#pragma unroll
            for (int h = 0; h < 2; ++h) {
                float4 v = zv[mm * 2 + h];
#pragma unroll
                for (int e = 0; e < 4; ++e) {
                    int c = q * 32 + mm * 8 + h * 4 + e;
                    float val = (((const float*)&v)[e] - us[urow][c] - smean[c]) * sinv[c];
                    o[h * 4 + e] = f2b(fmaxf(val, 0.f));
                }
            }
            *(uint4*)&hs[r][q * 32 + mm * 8] = *(uint4*)o;
        }
        if (q == 0) { uint4 zz = make_uint4(0, 0, 0, 0); *(uint4*)&hs[r][128] = zz; }
    }
    __syncthreads();
    f32x4 acc[4][2];
    f32x4 z4 = {0.f, 0.f, 0.f, 0.f};
#pragma unroll
    for (int i = 0; i < 4; ++i) { acc[i][0] = z4; acc[i][1] = z4; }
#pragma unroll
    for (int kc = 0; kc < 4; ++kc) {
        U16 a[4];
#pragma unroll
        for (int i = 0; i < 4; ++i) a[i].u = *(const uint4*)&hs[16 * i + lr][kc * 32 + lg * 8];
#pragma unroll
        for (int i = 0; i < 4; ++i)
#pragma unroll
            for (int jj = 0; jj < 2; ++jj)
                acc[i][jj] = __builtin_amdgcn_mfma_f32_16x16x32_bf16(a[i].s, b2f[kc][jj].s, acc[i][jj], 0, 0, 0);
    }
    // epilogue: fused stats2 (pre-max) + k-max over 32 neighbors of each of the 2 points
#pragma unroll
    for (int jj = 0; jj < 2; ++jj) {
        int c = w * 32 + jj * 16 + lr;
        float s = 0.f, sq = 0.f;
        float m0 = -3.4e38f, m1 = -3.4e38f;
#pragma unroll
        for (int i = 0; i < 4; ++i)
#pragma unroll
            for (int rg = 0; rg < 4; ++rg) {
                float v = acc[i][jj][rg];
                s += v; sq += v * v;
                if (i < 2) m0 = fmaxf(m0, v); else m1 = fmaxf(m1, v);
            }
        s  += __shfl_xor(s, 16, 64);  s  += __shfl_xor(s, 32, 64);
        sq += __shfl_xor(sq, 16, 64); sq += __shfl_xor(sq, 32, 64);
        m0 = fmaxf(m0, __shfl_xor(m0, 16, 64)); m0 = fmaxf(m0, __shfl_xor(m0, 32, 64));
        m1 = fmaxf(m1, __shfl_xor(m1, 16, 64)); m1 = fmaxf(m1, __shfl_xor(m1, 32, 64));
        if (lg == 0) {
            atomicAdd(&stats2[b * CH + c], s);
            atomicAdd(&stats2[B * CH + b * CH + c], sq);
            ymax[(size_t)gp0 * CH + c] = f2b(m0);
            ymax[(size_t)(gp0 + 1) * CH + c] = f2b(m1);
        }
    }
}

// ---------------- pass C: norm+relu on pooled maxes -> bf16 features ----------------
__global__ void k_passC2(const ushort* __restrict__ ymax, const float* __restrict__ stats,
                         ushort* __restrict__ outp)
{
    int e = blockIdx.x * 256 + threadIdx.x;    // handles 4 cols; total B*N4*32 threads
    int row = e >> 5, cq = (e & 31) * 4;
    int b = row >> 11;
    uint2 v = *(const uint2*)&ymax[(size_t)row * CH + cq];
    float f[4] = { bf2f((ushort)(v.x & 0xffff)), bf2f((ushort)(v.x >> 16)),
                   bf2f((ushort)(v.y & 0xffff)), bf2f((ushort)(v.y >> 16)) };
    uint2 o2;
    ushort o[4];
#pragma unroll
    for (int j = 0; j < 4; ++j) {
        int c = cq + j;
        float mean = stats[b * CH + c] * (1.f / ROWS_PER_B);
        float var = stats[B * CH + b * CH + c] * (1.f / ROWS_PER_B) - mean * mean;
        o[j] = f2b(fmaxf((f[j] - mean) * rsqrtf(var + 1e-5f), 0.f));
    }
    o2.x = (uint)o[0] | ((uint)o[1] << 16);
    o2.y = (uint)o[2] | ((uint)o[3] << 16);
    *(uint2*)&outp[(size_t)row * CH + cq] = o2;
}

// ---------------- FC head: relu(X@W1^T+b1) @ W2^T + b2 -> flow_lr [B,3,N4] in d_out ----------------
__global__ __launch_bounds__(256, 1) void k_fc(
    const ushort* __restrict__ X, const float* __restrict__ W1,
    const float* __restrict__ b1, const float* __restrict__ W2,
    const float* __restrict__ b2, float* __restrict__ out)
{
    __shared__ float hs[64][132];
    __shared__ float ws[128][132];
    int t = threadIdx.x;
    for (int i = t; i < 128 * 132; i += 256) {
        int dd = i / 132, c = i - dd * 132;
        ws[dd][c] = (c < 128) ? W1[dd * 128 + c] : 0.f;
    }
    int r = t >> 2, q = t & 3;
    int g0 = blockIdx.x * 64;
    {
        const uint4* Xrow = (const uint4*)(X + (size_t)(g0 + r) * CH + q * 32);
#pragma unroll
        for (int m = 0; m < 4; ++m) {
            uint4 v = Xrow[m];
            const uint* pv = (const uint*)&v;
            int c0 = q * 32 + m * 8;
#pragma unroll
            for (int e = 0; e < 4; ++e) {
                hs[r][c0 + 2 * e]     = bf2f((ushort)(pv[e] & 0xffff));
                hs[r][c0 + 2 * e + 1] = bf2f((ushort)(pv[e] >> 16));
            }
        }
        if (q == 0) *(float4*)&hs[r][128] = make_float4(0.f, 0.f, 0.f, 0.f);
    }
    __syncthreads();
    int tx = t & 15, ty = t >> 4;
    float acc[4][8];
#pragma unroll
    for (int i = 0; i < 4; ++i)
#pragma unroll
        for (int jj = 0; jj < 8; ++jj) acc[i][jj] = 0.f;
    for (int kb = 0; kb < 33; ++kb) {
        float4 a[4]; float4 w[8];
#pragma unroll
        for (int i = 0; i < 4; ++i) a[i] = *(float4*)&hs[ty * 4 + i][kb * 4];
#pragma unroll
        for (int jj = 0; jj < 8; ++jj) w[jj] = *(float4*)&ws[tx + 16 * jj][kb * 4];
#pragma unroll
        for (int i = 0; i < 4; ++i)
#pragma unroll
            for (int jj = 0; jj < 8; ++jj)
                acc[i][jj] += a[i].x * w[jj].x + a[i].y * w[jj].y
                            + a[i].z * w[jj].z + a[i].w * w[jj].w;
    }
    __syncthreads();                     // done reading hs
#pragma unroll
    for (int jj = 0; jj < 8; ++jj) {
        int c = tx + 16 * jj;
        float bias = b1[c];
#pragma unroll
        for (int i = 0; i < 4; ++i)
            hs[ty * 4 + i][c] = fmaxf(acc[i][jj] + bias, 0.f);
    }
    __syncthreads();
    if (t < 192) {
        int rr = t / 3, o = t - rr * 3;
        float sum = b2[o];
        for (int c = 0; c < 128; ++c) sum += hs[rr][c] * W2[o * 128 + c];
        int g = g0 + rr;
        int b = g >> 11, n = g & (N4 - 1);
        out[FLOWLR_OFF + ((size_t)b * 3 + o) * N4 + n] = sum;
    }
}

// ---------------- feature propagation: 3-NN inverse-sqdist interp onto xyz1 ----------------
// GRID: B * (N1/64) = 1024 blocks (64 queries per block, 4 threads each).
__global__ __launch_bounds__(256) void k_fp(
    const float* __restrict__ xyz_s1, const float* __restrict__ xyz4,
    float* __restrict__ out)
{
    __shared__ float xs[4 * 528], ys[4 * 528], zs[4 * 528];
    int b = blockIdx.x >> 7;             // 128 blocks per batch
    int q0 = (blockIdx.x & 127) * 64;
    int t = threadIdx.x;
    for (int i = t; i < N4; i += 256) {
        int p = (i >> 9) * 528 + (i & 511);
        const float* s = xyz4 + (size_t)b * N4 * 3 + (size_t)i * 3;
        xs[p] = s[0]; ys[p] = s[1]; zs[p] = s[2];
    }
    __syncthreads();
    int q = q0 + (t >> 2), c = t & 3;
    float qx = xyz_s1[((size_t)b * 3 + 0) * N1 + q];
    float qy = xyz_s1[((size_t)b * 3 + 1) * N1 + q];
    float qz = xyz_s1[((size_t)b * 3 + 2) * N1 + q];
    float d0 = 3.4e38f, d1 = 3.4e38f, d2 = 3.4e38f;
    int i0 = 0, i1 = 0, i2 = 0;
    int base = c * 528, nb = c * 512;
    for (int ii = 0; ii < 512; ii += 4) {
        float4 x4 = *(float4*)&xs[base + ii];
        float4 y4 = *(float4*)&ys[base + ii];
        float4 z4 = *(float4*)&zs[base + ii];
#pragma unroll
        for (int j = 0; j < 4; ++j) {
            float dx = ((const float*)&x4)[j] - qx;
            float dy = ((const float*)&y4)[j] - qy;
            float dz = ((const float*)&z4)[j] - qz;
            float dd = dx * dx + dy * dy + dz * dz;
            if (dd < d2) {
                int n = nb + ii + j;
                if (dd < d0)      { d2 = d1; i2 = i1; d1 = d0; i1 = i0; d0 = dd; i0 = n; }
                else if (dd < d1) { d2 = d1; i2 = i1; d1 = dd; i1 = n; }
                else              { d2 = dd; i2 = n; }
            }
        }
    }
#pragma unroll
    for (int m = 1; m <= 2; m <<= 1) {
        float e0 = __shfl_xor(d0, m, 64), e1 = __shfl_xor(d1, m, 64), e2 = __shfl_xor(d2, m, 64);
        int   j0 = __shfl_xor(i0, m, 64), j1 = __shfl_xor(i1, m, 64), j2 = __shfl_xor(i2, m, 64);
        float ed[3] = { e0, e1, e2 }; int ej[3] = { j0, j1, j2 };
#pragma unroll
        for (int s = 0; s < 3; ++s) {
            float dd = ed[s]; int jn = ej[s];
            bool lt2 = dd < d2 || (dd == d2 && jn < i2);
            if (lt2) {
                bool lt0 = dd < d0 || (dd == d0 && jn < i0);
                bool lt1 = dd < d1 || (dd == d1 && jn < i1);
                if (lt0)      { d2 = d1; i2 = i1; d1 = d0; i1 = i0; d0 = dd; i0 = jn; }
                else if (lt1) { d2 = d1; i2 = i1; d1 = dd; i1 = jn; }
                else          { d2 = dd; i2 = jn; }
            }
        }
    }
    float w0 = 1.f / (d0 + 1e-8f), w1 = 1.f / (d1 + 1e-8f), w2 = 1.f / (d2 + 1e-8f);
    float inv = 1.f / (w0 + w1 + w2);
    const float* flr = out + FLOWLR_OFF + (size_t)b * 3 * N4;
    if (c < 3) {
        float v = (w0 * flr[c * N4 + i0] + w1 * flr[c * N4 + i1] + w2 * flr[c * N4 + i2]) * inv;
        out[((size_t)b * 3 + c) * N1 + q] = v;
    }
}

extern "C" void kernel_launch(void* const* d_in, const int* in_sizes, int n_in,
                              void* d_out, int out_size, void* d_ws, size_t ws_size,
                              hipStream_t stream) {
    const float* xyz_s1 = (const float*)d_in[0];
    const float* xyz_s4 = (const float*)d_in[1];
    const float* feats  = (const float*)d_in[2];
    const float* sa1_W1 = (const float*)d_in[3];
    const float* sa1_W2 = (const float*)d_in[5];
    const float* sa2_W1 = (const float*)d_in[7];
    const float* sa2_W2 = (const float*)d_in[9];
    const float* fc_W1  = (const float*)d_in[11];
    const float* fc_b1  = (const float*)d_in[12];
    const float* fc_W2  = (const float*)d_in[13];
    const float* fc_b2  = (const float*)d_in[14];
    float* out = (float*)d_out;

    char* wsb = (char*)d_ws;
    float*  xyz4   = (float*)(wsb + 0);                  // 196608 B
    int*    idx    = (int*)(wsb + 196608);               // 2 MB   -> 2293760
    ushort* featTb = (ushort*)(wsb + 2293760);           // 4 MB   -> 6488064
    ushort* featB  = (ushort*)(wsb + 6488064);           // 4 MB   -> 10682368
    ushort* featC  = (ushort*)(wsb + 10682368);          // 4 MB   -> 14876672
    ushort* W1b1   = (ushort*)(wsb + 14876672);          // 64 KB  -> 14942208
    ushort* W1b2   = (ushort*)(wsb + 14942208);          // 64 KB  -> 15007744
    ushort* W2b1   = (ushort*)(wsb + 15007744);          // 64 KB  -> 15073280
    ushort* W2b2   = (ushort*)(wsb + 15073280);          // 64 KB  -> 15138816
    float*  statsA = (float*)(wsb + 15138816);           // 8 KB each x4 (contiguous)
    float*  statsB = (float*)(wsb + 15147008);
    float*  statsC = (float*)(wsb + 15155200);
    float*  statsD = (float*)(wsb + 15163392);
    ushort* ymax   = (ushort*)(wsb + 15171584);          // 4 MB  -> 19365888 (no alias: fused reads z/u)
    float*  zbuf   = (float*)(wsb + 19365888);           // 8 MB  -> 27754496 (dense z, fp32, reused per layer)
    float*  ubuf   = (float*)(wsb + 27754496);           // 8 MB  -> 36143104

    // ---- setup ----
    k_prep<<<400, 256, 0, stream>>>(xyz_s4, xyz4, sa1_W1, sa2_W1, sa1_W2, sa2_W2,
                                    W1b1, W1b2, W2b1, W2b2, statsA);
    k_knn<<<B * (N4 / 4), 256, 0, stream>>>(xyz4, idx);
    dim3 gt(B, N4 / 32, CH / 32), bt(32, 8);
    k_feat_t<<<gt, bt, 0, stream>>>(feats, featTb);

    // ---- SA1 ----
    k_dense<<<NPTS / 64, 256, 0, stream>>>(featTb, xyz4, W1b1, zbuf);
    k_u<<<NPTS * 32 / 256, 256, 0, stream>>>(xyz4, W1b1, ubuf);
    k_gstats<<<NPTS / 32, 256, 0, stream>>>(zbuf, ubuf, idx, statsA);
    k_fused2<<<ROWS_TOTAL / 64, 256, 0, stream>>>(zbuf, ubuf, idx, W2b1, statsA, statsB, ymax);
    k_passC2<<<(B * N4 * 32) / 256, 256, 0, stream>>>(ymax, statsB, featB);

    // ---- SA2 ----
    k_dense<<<NPTS / 64, 256, 0, stream>>>(featB, xyz4, W1b2, zbuf);
    k_u<<<NPTS * 32 / 256, 256, 0, stream>>>(xyz4, W1b2, ubuf);
    k_gstats<<<NPTS / 32, 256, 0, stream>>>(zbuf, ubuf, idx, statsC);
    k_fused2<<<ROWS_TOTAL / 64, 256, 0, stream>>>(zbuf, ubuf, idx, W2b2, statsC, statsD, ymax);
    k_passC2<<<(B * N4 * 32) / 256, 256, 0, stream>>>(ymax, statsD, featC);

    // ---- FC head + flow_lr ----
    k_fc<<<(B * N4) / 64, 256, 0, stream>>>(featC, fc_W1, fc_b1, fc_W2, fc_b2, out);
    // ---- feature propagation -> flow ----
    k_fp<<<B * (N1 / 64), 256, 0, stream>>>(xyz_s1, xyz4, out);
}

// Round 10
// 435.765 us; speedup vs baseline: 8.1061x; 1.2399x over previous
//
#include <hip/hip_runtime.h>
#include <hip/hip_bf16.h>

#define B 8
#define N1 8192
#define N4 2048
#define CH 128
#define KNN 32
#define ROWS_PER_B (N4 * KNN)          // 65536 rows per batch in the [B,N,K] flattening
#define ROWS_TOTAL (B * ROWS_PER_B)    // 524288
#define NPTS (B * N4)                  // 16384 total points
#define FLOWLR_OFF (B * 3 * N1)        // flow_lr starts after flow in d_out

typedef unsigned int uint;
typedef unsigned short ushort;
typedef __attribute__((ext_vector_type(8))) short short8;
typedef __attribute__((ext_vector_type(4))) float f32x4;

union U16 { uint4 u; short8 s; };

__device__ __forceinline__ float bf2f(ushort u) {
    union { uint i; float f; } v; v.i = ((uint)u) << 16; return v.f;
}
__device__ __forceinline__ ushort f2b(float f) {
    __hip_bfloat16 h = __float2bfloat16(f);
    return *(ushort*)&h;
}

// ---------------- prep: fused W converters (bf16, permuted/padded) + xyz transpose + stats zero ----------------
__global__ void k_prep(const float* __restrict__ xyz_s4, float* __restrict__ xyz4,
                       const float* __restrict__ sa1_W1, const float* __restrict__ sa2_W1,
                       const float* __restrict__ sa1_W2, const float* __restrict__ sa2_W2,
                       ushort* __restrict__ W1b1, ushort* __restrict__ W1b2,
                       ushort* __restrict__ W2b1, ushort* __restrict__ W2b2,
                       float* __restrict__ stats)
{
    int i = blockIdx.x * 256 + threadIdx.x;
    if (i < 43008) {
        const float* W = (i < 21504) ? sa1_W1 : sa2_W1;
        ushort* o = (i < 21504) ? W1b1 : W1b2;
        int j = (i < 21504) ? i : i - 21504;
        int d = j / 168, c = j - d * 168;
        float v = 0.f;
        if (c < 128)      v = W[d * 131 + 3 + c];
        else if (c < 131) v = W[d * 131 + (c - 128)];
        o[j] = f2b(v);
    } else if (i < 77824) {
        const float* W = (i < 60416) ? sa1_W2 : sa2_W2;
        ushort* o = (i < 60416) ? W2b1 : W2b2;
        int j = (i < 60416) ? i - 43008 : i - 60416;
        int d = j / 136, c = j - d * 136;
        o[j] = (c < 128) ? f2b(W[d * 128 + c]) : (ushort)0;
    } else if (i < 94208) {
        int g = i - 77824;
        int b = g >> 11, n = g & (N4 - 1);
        xyz4[g * 3 + 0] = xyz_s4[(b * 3 + 0) * N4 + n];
        xyz4[g * 3 + 1] = xyz_s4[(b * 3 + 1) * N4 + n];
        xyz4[g * 3 + 2] = xyz_s4[(b * 3 + 2) * N4 + n];
    } else if (i < 102400) {
        stats[i - 94208] = 0.f;        // zeros statsA..statsD (contiguous 8192 floats)
    }
}

// ---------------- transpose feats [B,C,N4] fp32 -> featTb [B,N4,C] bf16 ----------------
__global__ void k_feat_t(const float* __restrict__ feats, ushort* __restrict__ featTb) {
    __shared__ float tile[32][33];
    int b = blockIdx.x, nb = blockIdx.y, cb = blockIdx.z;
    int tx = threadIdx.x, ty = threadIdx.y; // 32 x 8
    int n0 = nb * 32, c0 = cb * 32;
#pragma unroll
    for (int i = 0; i < 4; ++i) {
        int c = c0 + ty + 8 * i;
        tile[ty + 8 * i][tx] = feats[((size_t)b * CH + c) * N4 + n0 + tx];
    }
    __syncthreads();
#pragma unroll
    for (int i = 0; i < 4; ++i) {
        int n = n0 + ty + 8 * i;
        featTb[((size_t)b * N4 + n) * CH + c0 + tx] = f2b(tile[tx][ty + 8 * i]);
    }
}

// ---------------- KNN via exact threshold-select (bisection on fp32 bit pattern) ----------------
__global__ __launch_bounds__(256) void k_knn(const float* __restrict__ xyz4, int* __restrict__ idxout) {
    __shared__ float pts[N4 * 3];
    int b = blockIdx.x >> 9;            // 512 blocks per batch
    int qbase = (blockIdx.x & 511) * 4;
    for (int i = threadIdx.x; i < N4 * 3; i += 256) pts[i] = xyz4[(size_t)b * N4 * 3 + i];
    __syncthreads();
    int wave = threadIdx.x >> 6, lane = threadIdx.x & 63;
    int qn = qbase + wave;
    float qx = pts[qn * 3 + 0], qy = pts[qn * 3 + 1], qz = pts[qn * 3 + 2];
    float d[32];
#pragma unroll
    for (int t = 0; t < 32; ++t) {
        int c = t * 64 + lane;
        float dx = pts[c * 3 + 0] - qx;
        float dy = pts[c * 3 + 1] - qy;
        float dz = pts[c * 3 + 2] - qz;
        d[t] = dx * dx + dy * dy + dz * dz;
    }
    uint lo = 0u, hi = 0x7F800000u;
    int cLT = 0;
    while (hi - lo > 1u) {
        uint mid = (lo + hi) >> 1;
        float fmid = __uint_as_float(mid);
        int c = 0;
#pragma unroll
        for (int t = 0; t < 32; ++t) c += __popcll(__ballot(d[t] < fmid));
        if (c < KNN) { lo = mid; cLT = c; } else hi = mid;
    }
    float T = __uint_as_float(lo);      // T = exact 32nd smallest value; cLT = count(d < T)
    int outb = (b * N4 + qn) * KNN;
    unsigned long long lmlt = (1ull << lane) - 1ull;
    int baseLT = 0, baseEQ = cLT;
#pragma unroll
    for (int t = 0; t < 32; ++t) {
        bool lt = d[t] < T;
        unsigned long long m = __ballot(lt);
        if (lt) idxout[outb + baseLT + __popcll(m & lmlt)] = t * 64 + lane;
        baseLT += __popcll(m);
        bool eq = (d[t] == T);
        unsigned long long me = __ballot(eq);
        if (eq) {
            int rk = baseEQ + __popcll(me & lmlt);
            if (rk < KNN) idxout[outb + rk] = t * 64 + lane;
        }
        baseEQ += __popcll(me);
    }
}

// ---------------- dense z GEMM: z[p] = [feat_p | xyz_p] @ W1^T (fp32 out) ----------------
__global__ __launch_bounds__(256) void k_dense(
    const ushort* __restrict__ Fb, const float* __restrict__ xyz4,
    const ushort* __restrict__ W1b, float* __restrict__ z)
{
    __shared__ __align__(16) ushort hs[64][168];
    int t = threadIdx.x;
    int r = t >> 2, q = t & 3;
    int l = t & 63, w = t >> 6, lr = l & 15, lg = l >> 4;
    int g0 = blockIdx.x * 64;
    {
        int p = g0 + r;
        const uint4* src = (const uint4*)(Fb + (size_t)p * CH) + q * 4;
        uint4* dst = (uint4*)&hs[r][q * 32];
#pragma unroll
        for (int m = 0; m < 4; ++m) dst[m] = src[m];
        uint4 zz = make_uint4(0, 0, 0, 0);
        *(uint4*)&hs[r][128 + q * 8] = zz;
        if (q == 0) {
            *(uint4*)&hs[r][160] = zz;
            hs[r][128] = f2b(xyz4[p * 3 + 0]);
            hs[r][129] = f2b(xyz4[p * 3 + 1]);
            hs[r][130] = f2b(xyz4[p * 3 + 2]);
        }
    }
    U16 bf[5][2];
#pragma unroll
    for (int kc = 0; kc < 5; ++kc)
#pragma unroll
        for (int jj = 0; jj < 2; ++jj)
            bf[kc][jj].u = *(const uint4*)&W1b[(size_t)(w * 32 + jj * 16 + lr) * 168 + kc * 32 + lg * 8];
    __syncthreads();
    f32x4 acc[4][2];
    f32x4 z4 = {0.f, 0.f, 0.f, 0.f};
#pragma unroll
    for (int i = 0; i < 4; ++i) { acc[i][0] = z4; acc[i][1] = z4; }
#pragma unroll
    for (int kc = 0; kc < 5; ++kc) {
        U16 a[4];
#pragma unroll
        for (int i = 0; i < 4; ++i) a[i].u = *(const uint4*)&hs[16 * i + lr][kc * 32 + lg * 8];
#pragma unroll
        for (int i = 0; i < 4; ++i)
#pragma unroll
            for (int jj = 0; jj < 2; ++jj)
                acc[i][jj] = __builtin_amdgcn_mfma_f32_16x16x32_bf16(a[i].s, bf[kc][jj].s, acc[i][jj], 0, 0, 0);
    }
#pragma unroll
    for (int jj = 0; jj < 2; ++jj)
#pragma unroll
        for (int i = 0; i < 4; ++i)
#pragma unroll
            for (int rg = 0; rg < 4; ++rg)
                z[(size_t)(g0 + 16 * i + lg * 4 + rg) * CH + w * 32 + jj * 16 + lr] = acc[i][jj][rg];
}

// ---------------- u[p] = bf16(xyz_p) @ bf16(W1x)^T (fp32, matches z's rounding) ----------------
__global__ void k_u(const float* __restrict__ xyz4, const ushort* __restrict__ W1b,
                    float* __restrict__ u)
{
    int e = blockIdx.x * 256 + threadIdx.x;   // NPTS*32 threads; 4 cols each
    int p = e >> 5, i = e & 31;
    float x = bf2f(f2b(xyz4[p * 3 + 0]));
    float y = bf2f(f2b(xyz4[p * 3 + 1]));
    float zc = bf2f(f2b(xyz4[p * 3 + 2]));
    float4 o;
#pragma unroll
    for (int jj = 0; jj < 4; ++jj) {
        int c = i * 4 + jj;
        ((float*)&o)[jj] = x * bf2f(W1b[c * 168 + 128])
                         + y * bf2f(W1b[c * 168 + 129])
                         + zc * bf2f(W1b[c * 168 + 130]);
    }
    *(float4*)&u[(size_t)p * CH + i * 4] = o;
}

// ---------------- gather-stats: per-(b,c) sum/sumsq of y1 = z[j]-u[n], NO MFMA ----------------
__global__ __launch_bounds__(256) void k_gstats(
    const float* __restrict__ z, const float* __restrict__ u,
    const int* __restrict__ idx, float* __restrict__ stats)
{
    __shared__ int idxs[32 * KNN];
    __shared__ float sacc[128], sqacc[128];
    int t = threadIdx.x;
    int gpb = blockIdx.x * 32;
    int b = gpb >> 11;
    for (int ii = t; ii < 32 * KNN; ii += 256) idxs[ii] = idx[(size_t)gpb * KNN + ii];
    if (t < 128) { sacc[t] = 0.f; sqacc[t] = 0.f; }
    __syncthreads();
    int li = t >> 3, cq = (t & 7) * 16;
    int gp = gpb + li;
    float s[16], qa[16];
#pragma unroll
    for (int m = 0; m < 16; ++m) { s[m] = 0.f; qa[m] = 0.f; }
    int zb = b * N4;
#pragma unroll 4
    for (int k = 0; k < KNN; ++k) {
        int j = idxs[li * KNN + k];
        const float4* zr = (const float4*)(z + (size_t)(zb + j) * CH + cq);
#pragma unroll
        for (int m = 0; m < 4; ++m) {
            float4 v = zr[m];
#pragma unroll
            for (int e = 0; e < 4; ++e) {
                float vv = ((const float*)&v)[e];
                s[m * 4 + e] += vv; qa[m * 4 + e] += vv * vv;
            }
        }
    }
    const float4* ur = (const float4*)(u + (size_t)gp * CH + cq);
#pragma unroll
    for (int m = 0; m < 4; ++m) {
        float4 uv = ur[m];
#pragma unroll
        for (int e = 0; e < 4; ++e) {
            float uu = ((const float*)&uv)[e];
            float ss = s[m * 4 + e], qq = qa[m * 4 + e];
            atomicAdd(&sacc[cq + m * 4 + e], ss - 32.f * uu);
            atomicAdd(&sqacc[cq + m * 4 + e], qq - 2.f * uu * ss + 32.f * uu * uu);
        }
    }
    __syncthreads();
    if (t < 128) {
        atomicAdd(&stats[b * CH + t], sacc[t]);
        atomicAdd(&stats[B * CH + b * CH + t], sqacc[t]);
    }
}

// ---------------- fused pass v2: 256 rows/block, double-buffered LDS, 1 barrier per sub-tile ----------------
// gather z, y1=z-u, norm+relu -> bf16 LDS, MFMA2, stats2 (block-accumulated) + k-max (per sub-tile).
__global__ __launch_bounds__(256) void k_fused2(
    const float* __restrict__ z, const float* __restrict__ u,
    const int* __restrict__ idx, const ushort* __restrict__ W2b,
    const float* __restrict__ stats1, float* __restrict__ stats2,
    ushort* __restrict__ ymax)
{
    __shared__ __align__(16) ushort hs[2][64][136];
    __shared__ float smean[128], sinv[128];
    __shared__ float us[8][128];
    int t = threadIdx.x;
    int g0 = blockIdx.x * 256;          // 256 rows = 8 points
    int b = g0 >> 16;
    int gp0 = g0 >> 5;
    int l = t & 63, w = t >> 6, lr = l & 15, lg = l >> 4;
    U16 b2f[4][2];
#pragma unroll
    for (int kc = 0; kc < 4; ++kc)
#pragma unroll
        for (int jj = 0; jj < 2; ++jj)
            b2f[kc][jj].u = *(const uint4*)&W2b[(size_t)(w * 32 + jj * 16 + lr) * 136 + kc * 32 + lg * 8];
    if (t < 128) {
        float s = stats1[b * CH + t], q2 = stats1[B * CH + b * CH + t];
        float mean = s * (1.f / ROWS_PER_B);
        float var = q2 * (1.f / ROWS_PER_B) - mean * mean;
        smean[t] = mean; sinv[t] = rsqrtf(var + 1e-5f);
    }
    {   // us: 8 points x 128 cols; 256 threads x float4
        int p = t >> 5, i = t & 31;
        *(float4*)&us[p][i * 4] = *(const float4*)&u[(size_t)(gp0 + p) * CH + i * 4];
    }
    int r = t >> 2, q = t & 3;
    // prologue: z loads for sub-tile 0
    float4 zv[8];
    {
        int j = idx[g0 + r];
        const float4* zr = (const float4*)(z + (size_t)(b * N4 + j) * CH + q * 32);
#pragma unroll
        for (int m = 0; m < 8; ++m) zv[m] = zr[m];
    }
    float sA[2] = {0.f, 0.f}, qA[2] = {0.f, 0.f};
    f32x4 z4 = {0.f, 0.f, 0.f, 0.f};
    __syncthreads();   // smean/sinv/us ready (zv loads overlap this)
    for (int st = 0; st < 4; ++st) {
        ushort (*buf)[136] = hs[st & 1];
        // norm+relu+pack current sub-tile into buf
        {
            int urow = (st * 64 + r) >> 5;
#pragma unroll
            for (int mm = 0; mm < 4; ++mm) {
                ushort o[8];
#pragma unroll
                for (int h = 0; h < 2; ++h) {
                    float4 v = zv[mm * 2 + h];
#pragma unroll
                    for (int e = 0; e < 4; ++e) {
                        int c = q * 32 + mm * 8 + h * 4 + e;
                        float val = (((const float*)&v)[e] - us[urow][c] - smean[c]) * sinv[c];
                        o[h * 4 + e] = f2b(fmaxf(val, 0.f));
                    }
                }
                *(uint4*)&buf[r][q * 32 + mm * 8] = *(uint4*)o;
            }
            if (q == 0) { uint4 zz = make_uint4(0, 0, 0, 0); *(uint4*)&buf[r][128] = zz; }
        }
        __syncthreads();   // buf visible; also guards reuse of hs[st&1] (MFMA of st-2 done)
        // issue next sub-tile's z loads (overlap with MFMA below)
        if (st < 3) {
            int j = idx[g0 + (st + 1) * 64 + r];
            const float4* zr = (const float4*)(z + (size_t)(b * N4 + j) * CH + q * 32);
#pragma unroll
            for (int m = 0; m < 8; ++m) zv[m] = zr[m];
        }
        // MFMA2 on buf
        f32x4 acc[4][2];
#pragma unroll
        for (int i = 0; i < 4; ++i) { acc[i][0] = z4; acc[i][1] = z4; }
#pragma unroll
        for (int kc = 0; kc < 4; ++kc) {
            U16 a[4];
#pragma unroll
            for (int i = 0; i < 4; ++i) a[i].u = *(const uint4*)&buf[16 * i + lr][kc * 32 + lg * 8];
#pragma unroll
            for (int i = 0; i < 4; ++i)
#pragma unroll
                for (int jj = 0; jj < 2; ++jj)
                    acc[i][jj] = __builtin_amdgcn_mfma_f32_16x16x32_bf16(a[i].s, b2f[kc][jj].s, acc[i][jj], 0, 0, 0);
        }
        // per-sub-tile epilogue: accumulate stats in regs; k-max + ymax write for the 2 points
        int gpA = gp0 + st * 2;
#pragma unroll
        for (int jj = 0; jj < 2; ++jj) {
            int c = w * 32 + jj * 16 + lr;
            float m0 = -3.4e38f, m1 = -3.4e38f;
#pragma unroll
            for (int i = 0; i < 4; ++i)
#pragma unroll
                for (int rg = 0; rg < 4; ++rg) {
                    float v = acc[i][jj][rg];
                    sA[jj] += v; qA[jj] += v * v;
                    if (i < 2) m0 = fmaxf(m0, v); else m1 = fmaxf(m1, v);
                }
            m0 = fmaxf(m0, __shfl_xor(m0, 16, 64)); m0 = fmaxf(m0, __shfl_xor(m0, 32, 64));
            m1 = fmaxf(m1, __shfl_xor(m1, 16, 64)); m1 = fmaxf(m1, __shfl_xor(m1, 32, 64));
            if (lg == 0) {
                ymax[(size_t)gpA * CH + c] = f2b(m0);
                ymax[(size_t)(gpA + 1) * CH + c] = f2b(m1);
            }
        }
    }
    // block-level stats atomics (once instead of per sub-tile)
#pragma unroll
    for (int jj = 0; jj < 2; ++jj) {
        int c = w * 32 + jj * 16 + lr;
        float ss = sA[jj], qq = qA[jj];
        ss += __shfl_xor(ss, 16, 64); ss += __shfl_xor(ss, 32, 64);
        qq += __shfl_xor(qq, 16, 64); qq += __shfl_xor(qq, 32, 64);
        if (lg == 0) {
            atomicAdd(&stats2[b * CH + c], ss);
            atomicAdd(&stats2[B * CH + b * CH + c], qq);
        }
    }
}

// ---------------- pass C: norm+relu on pooled maxes -> bf16 features ----------------
__global__ void k_passC2(const ushort* __restrict__ ymax, const float* __restrict__ stats,
                         ushort* __restrict__ outp)
{
    int e = blockIdx.x * 256 + threadIdx.x;    // handles 4 cols; total B*N4*32 threads
    int row = e >> 5, cq = (e & 31) * 4;
    int b = row >> 11;
    uint2 v = *(const uint2*)&ymax[(size_t)row * CH + cq];
    float f[4] = { bf2f((ushort)(v.x & 0xffff)), bf2f((ushort)(v.x >> 16)),
                   bf2f((ushort)(v.y & 0xffff)), bf2f((ushort)(v.y >> 16)) };
    uint2 o2;
    ushort o[4];
#pragma unroll
    for (int j = 0; j < 4; ++j) {
        int c = cq + j;
        float mean = stats[b * CH + c] * (1.f / ROWS_PER_B);
        float var = stats[B * CH + b * CH + c] * (1.f / ROWS_PER_B) - mean * mean;
        o[j] = f2b(fmaxf((f[j] - mean) * rsqrtf(var + 1e-5f), 0.f));
    }
    o2.x = (uint)o[0] | ((uint)o[1] << 16);
    o2.y = (uint)o[2] | ((uint)o[3] << 16);
    *(uint2*)&outp[(size_t)row * CH + cq] = o2;
}

// ---------------- FC head: relu(X@W1^T+b1) @ W2^T + b2 -> flow_lr [B,3,N4] in d_out ----------------
__global__ __launch_bounds__(256, 1) void k_fc(
    const ushort* __restrict__ X, const float* __restrict__ W1,
    const float* __restrict__ b1, const float* __restrict__ W2,
    const float* __restrict__ b2, float* __restrict__ out)
{
    __shared__ float hs[64][132];
    __shared__ float ws[128][132];
    int t = threadIdx.x;
    for (int i = t; i < 128 * 132; i += 256) {
        int dd = i / 132, c = i - dd * 132;
        ws[dd][c] = (c < 128) ? W1[dd * 128 + c] : 0.f;
    }
    int r = t >> 2, q = t & 3;
    int g0 = blockIdx.x * 64;
    {
        const uint4* Xrow = (const uint4*)(X + (size_t)(g0 + r) * CH + q * 32);
#pragma unroll
        for (int m = 0; m < 4; ++m) {
            uint4 v = Xrow[m];
            const uint* pv = (const uint*)&v;
            int c0 = q * 32 + m * 8;
#pragma unroll
            for (int e = 0; e < 4; ++e) {
                hs[r][c0 + 2 * e]     = bf2f((ushort)(pv[e] & 0xffff));
                hs[r][c0 + 2 * e + 1] = bf2f((ushort)(pv[e] >> 16));
            }
        }
        if (q == 0) *(float4*)&hs[r][128] = make_float4(0.f, 0.f, 0.f, 0.f);
    }
    __syncthreads();
    int tx = t & 15, ty = t >> 4;
    float acc[4][8];
#pragma unroll
    for (int i = 0; i < 4; ++i)
#pragma unroll
        for (int jj = 0; jj < 8; ++jj) acc[i][jj] = 0.f;
    for (int kb = 0; kb < 33; ++kb) {
        float4 a[4]; float4 w[8];
#pragma unroll
        for (int i = 0; i < 4; ++i) a[i] = *(float4*)&hs[ty * 4 + i][kb * 4];
#pragma unroll
        for (int jj = 0; jj < 8; ++jj) w[jj] = *(float4*)&ws[tx + 16 * jj][kb * 4];
#pragma unroll
        for (int i = 0; i < 4; ++i)
#pragma unroll
            for (int jj = 0; jj < 8; ++jj)
                acc[i][jj] += a[i].x * w[jj].x + a[i].y * w[jj].y
                            + a[i].z * w[jj].z + a[i].w * w[jj].w;
    }
    __syncthreads();                     // done reading hs
#pragma unroll
    for (int jj = 0; jj < 8; ++jj) {
        int c = tx + 16 * jj;
        float bias = b1[c];
#pragma unroll
        for (int i = 0; i < 4; ++i)
            hs[ty * 4 + i][c] = fmaxf(acc[i][jj] + bias, 0.f);
    }
    __syncthreads();
    if (t < 192) {
        int rr = t / 3, o = t - rr * 3;
        float sum = b2[o];
        for (int c = 0; c < 128; ++c) sum += hs[rr][c] * W2[o * 128 + c];
        int g = g0 + rr;
        int b = g >> 11, n = g & (N4 - 1);
        out[FLOWLR_OFF + ((size_t)b * 3 + o) * N4 + n] = sum;
    }
}

// ---------------- feature propagation: 3-NN inverse-sqdist interp onto xyz1 ----------------
// GRID: B * (N1/64) = 1024 blocks (64 queries per block, 4 threads each).
__global__ __launch_bounds__(256) void k_fp(
    const float* __restrict__ xyz_s1, const float* __restrict__ xyz4,
    float* __restrict__ out)
{
    __shared__ float xs[4 * 528], ys[4 * 528], zs[4 * 528];
    int b = blockIdx.x >> 7;             // 128 blocks per batch
    int q0 = (blockIdx.x & 127) * 64;
    int t = threadIdx.x;
    for (int i = t; i < N4; i += 256) {
        int p = (i >> 9) * 528 + (i & 511);
        const float* s = xyz4 + (size_t)b * N4 * 3 + (size_t)i * 3;
        xs[p] = s[0]; ys[p] = s[1]; zs[p] = s[2];
    }
    __syncthreads();
    int q = q0 + (t >> 2), c = t & 3;
    float qx = xyz_s1[((size_t)b * 3 + 0) * N1 + q];
    float qy = xyz_s1[((size_t)b * 3 + 1) * N1 + q];
    float qz = xyz_s1[((size_t)b * 3 + 2) * N1 + q];
    float d0 = 3.4e38f, d1 = 3.4e38f, d2 = 3.4e38f;
    int i0 = 0, i1 = 0, i2 = 0;
    int base = c * 528, nb = c * 512;
    for (int ii = 0; ii < 512; ii += 4) {
        float4 x4 = *(float4*)&xs[base + ii];
        float4 y4 = *(float4*)&ys[base + ii];
        float4 z4 = *(float4*)&zs[base + ii];
#pragma unroll
        for (int j = 0; j < 4; ++j) {
            float dx = ((const float*)&x4)[j] - qx;
            float dy = ((const float*)&y4)[j] - qy;
            float dz = ((const float*)&z4)[j] - qz;
            float dd = dx * dx + dy * dy + dz * dz;
            if (dd < d2) {
                int n = nb + ii + j;
                if (dd < d0)      { d2 = d1; i2 = i1; d1 = d0; i1 = i0; d0 = dd; i0 = n; }
                else if (dd < d1) { d2 = d1; i2 = i1; d1 = dd; i1 = n; }
                else              { d2 = dd; i2 = n; }
            }
        }
    }
#pragma unroll
    for (int m = 1; m <= 2; m <<= 1) {
        float e0 = __shfl_xor(d0, m, 64), e1 = __shfl_xor(d1, m, 64), e2 = __shfl_xor(d2, m, 64);
        int   j0 = __shfl_xor(i0, m, 64), j1 = __shfl_xor(i1, m, 64), j2 = __shfl_xor(i2, m, 64);
        float ed[3] = { e0, e1, e2 }; int ej[3] = { j0, j1, j2 };
#pragma unroll
        for (int s = 0; s < 3; ++s) {
            float dd = ed[s]; int jn = ej[s];
            bool lt2 = dd < d2 || (dd == d2 && jn < i2);
            if (lt2) {
                bool lt0 = dd < d0 || (dd == d0 && jn < i0);
                bool lt1 = dd < d1 || (dd == d1 && jn < i1);
                if (lt0)      { d2 = d1; i2 = i1; d1 = d0; i1 = i0; d0 = dd; i0 = jn; }
                else if (lt1) { d2 = d1; i2 = i1; d1 = dd; i1 = jn; }
                else          { d2 = dd; i2 = jn; }
            }
        }
    }
    float w0 = 1.f / (d0 + 1e-8f), w1 = 1.f / (d1 + 1e-8f), w2 = 1.f / (d2 + 1e-8f);
    float inv = 1.f / (w0 + w1 + w2);
    const float* flr = out + FLOWLR_OFF + (size_t)b * 3 * N4;
    if (c < 3) {
        float v = (w0 * flr[c * N4 + i0] + w1 * flr[c * N4 + i1] + w2 * flr[c * N4 + i2]) * inv;
        out[((size_t)b * 3 + c) * N1 + q] = v;
    }
}

extern "C" void kernel_launch(void* const* d_in, const int* in_sizes, int n_in,
                              void* d_out, int out_size, void* d_ws, size_t ws_size,
                              hipStream_t stream) {
    const float* xyz_s1 = (const float*)d_in[0];
    const float* xyz_s4 = (const float*)d_in[1];
    const float* feats  = (const float*)d_in[2];
    const float* sa1_W1 = (const float*)d_in[3];
    const float* sa1_W2 = (const float*)d_in[5];
    const float* sa2_W1 = (const float*)d_in[7];
    const float* sa2_W2 = (const float*)d_in[9];
    const float* fc_W1  = (const float*)d_in[11];
    const float* fc_b1  = (const float*)d_in[12];
    const float* fc_W2  = (const float*)d_in[13];
    const float* fc_b2  = (const float*)d_in[14];
    float* out = (float*)d_out;

    char* wsb = (char*)d_ws;
    float*  xyz4   = (float*)(wsb + 0);                  // 196608 B
    int*    idx    = (int*)(wsb + 196608);               // 2 MB   -> 2293760
    ushort* featTb = (ushort*)(wsb + 2293760);           // 4 MB   -> 6488064
    ushort* featB  = (ushort*)(wsb + 6488064);           // 4 MB   -> 10682368
    ushort* featC  = (ushort*)(wsb + 10682368);          // 4 MB   -> 14876672
    ushort* W1b1   = (ushort*)(wsb + 14876672);          // 64 KB  -> 14942208
    ushort* W1b2   = (ushort*)(wsb + 14942208);          // 64 KB  -> 15007744
    ushort* W2b1   = (ushort*)(wsb + 15007744);          // 64 KB  -> 15073280
    ushort* W2b2   = (ushort*)(wsb + 15073280);          // 64 KB  -> 15138816
    float*  statsA = (float*)(wsb + 15138816);           // 8 KB each x4 (contiguous)
    float*  statsB = (float*)(wsb + 15147008);
    float*  statsC = (float*)(wsb + 15155200);
    float*  statsD = (float*)(wsb + 15163392);
    ushort* ymax   = (ushort*)(wsb + 15171584);          // 4 MB  -> 19365888 (no alias: fused reads z/u)
    float*  zbuf   = (float*)(wsb + 19365888);           // 8 MB  -> 27754496
    float*  ubuf   = (float*)(wsb + 27754496);           // 8 MB  -> 36143104

    // ---- setup ----
    k_prep<<<400, 256, 0, stream>>>(xyz_s4, xyz4, sa1_W1, sa2_W1, sa1_W2, sa2_W2,
                                    W1b1, W1b2, W2b1, W2b2, statsA);
    k_knn<<<B * (N4 / 4), 256, 0, stream>>>(xyz4, idx);
    dim3 gt(B, N4 / 32, CH / 32), bt(32, 8);
    k_feat_t<<<gt, bt, 0, stream>>>(feats, featTb);

    // ---- SA1 ----
    k_dense<<<NPTS / 64, 256, 0, stream>>>(featTb, xyz4, W1b1, zbuf);
    k_u<<<NPTS * 32 / 256, 256, 0, stream>>>(xyz4, W1b1, ubuf);
    k_gstats<<<NPTS / 32, 256, 0, stream>>>(zbuf, ubuf, idx, statsA);
    k_fused2<<<ROWS_TOTAL / 256, 256, 0, stream>>>(zbuf, ubuf, idx, W2b1, statsA, statsB, ymax);
    k_passC2<<<(B * N4 * 32) / 256, 256, 0, stream>>>(ymax, statsB, featB);

    // ---- SA2 ----
    k_dense<<<NPTS / 64, 256, 0, stream>>>(featB, xyz4, W1b2, zbuf);
    k_u<<<NPTS * 32 / 256, 256, 0, stream>>>(xyz4, W1b2, ubuf);
    k_gstats<<<NPTS / 32, 256, 0, stream>>>(zbuf, ubuf, idx, statsC);
    k_fused2<<<ROWS_TOTAL / 256, 256, 0, stream>>>(zbuf, ubuf, idx, W2b2, statsC, statsD, ymax);
    k_passC2<<<(B * N4 * 32) / 256, 256, 0, stream>>>(ymax, statsD, featC);

    // ---- FC head + flow_lr ----
    k_fc<<<(B * N4) / 64, 256, 0, stream>>>(featC, fc_W1, fc_b1, fc_W2, fc_b2, out);
    // ---- feature propagation -> flow ----
    k_fp<<<B * (N1 / 64), 256, 0, stream>>>(xyz_s1, xyz4, out);
}

// Round 11
// 409.613 us; speedup vs baseline: 8.6236x; 1.0638x over previous
//
#include <hip/hip_runtime.h>
#include <hip/hip_bf16.h>

#define B 8
#define N1 8192
#define N4 2048
#define CH 128
#define KNN 32
#define ROWS_PER_B (N4 * KNN)          // 65536 rows per batch in the [B,N,K] flattening
#define ROWS_TOTAL (B * ROWS_PER_B)    // 524288
#define NPTS (B * N4)                  // 16384 total points
#define FLOWLR_OFF (B * 3 * N1)        // flow_lr starts after flow in d_out

typedef unsigned int uint;
typedef unsigned short ushort;
typedef __attribute__((ext_vector_type(8))) short short8;
typedef __attribute__((ext_vector_type(4))) float f32x4;

union U16 { uint4 u; short8 s; };

__device__ __forceinline__ float bf2f(ushort u) {
    union { uint i; float f; } v; v.i = ((uint)u) << 16; return v.f;
}
__device__ __forceinline__ ushort f2b(float f) {
    __hip_bfloat16 h = __float2bfloat16(f);
    return *(ushort*)&h;
}

// ---------------- prep: fused W converters (bf16, permuted/padded) + xyz transpose + stats zero ----------------
__global__ void k_prep(const float* __restrict__ xyz_s4, float* __restrict__ xyz4,
                       const float* __restrict__ sa1_W1, const float* __restrict__ sa2_W1,
                       const float* __restrict__ sa1_W2, const float* __restrict__ sa2_W2,
                       ushort* __restrict__ W1b1, ushort* __restrict__ W1b2,
                       ushort* __restrict__ W2b1, ushort* __restrict__ W2b2,
                       float* __restrict__ stats)
{
    int i = blockIdx.x * 256 + threadIdx.x;
    if (i < 43008) {
        const float* W = (i < 21504) ? sa1_W1 : sa2_W1;
        ushort* o = (i < 21504) ? W1b1 : W1b2;
        int j = (i < 21504) ? i : i - 21504;
        int d = j / 168, c = j - d * 168;
        float v = 0.f;
        if (c < 128)      v = W[d * 131 + 3 + c];
        else if (c < 131) v = W[d * 131 + (c - 128)];
        o[j] = f2b(v);
    } else if (i < 77824) {
        const float* W = (i < 60416) ? sa1_W2 : sa2_W2;
        ushort* o = (i < 60416) ? W2b1 : W2b2;
        int j = (i < 60416) ? i - 43008 : i - 60416;
        int d = j / 136, c = j - d * 136;
        o[j] = (c < 128) ? f2b(W[d * 128 + c]) : (ushort)0;
    } else if (i < 94208) {
        int g = i - 77824;
        int b = g >> 11, n = g & (N4 - 1);
        xyz4[g * 3 + 0] = xyz_s4[(b * 3 + 0) * N4 + n];
        xyz4[g * 3 + 1] = xyz_s4[(b * 3 + 1) * N4 + n];
        xyz4[g * 3 + 2] = xyz_s4[(b * 3 + 2) * N4 + n];
    } else if (i < 102400) {
        stats[i - 94208] = 0.f;        // zeros statsA..statsD (contiguous 8192 floats)
    }
}

// ---------------- transpose feats [B,C,N4] fp32 -> featTb [B,N4,C] bf16 ----------------
__global__ void k_feat_t(const float* __restrict__ feats, ushort* __restrict__ featTb) {
    __shared__ float tile[32][33];
    int b = blockIdx.x, nb = blockIdx.y, cb = blockIdx.z;
    int tx = threadIdx.x, ty = threadIdx.y; // 32 x 8
    int n0 = nb * 32, c0 = cb * 32;
#pragma unroll
    for (int i = 0; i < 4; ++i) {
        int c = c0 + ty + 8 * i;
        tile[ty + 8 * i][tx] = feats[((size_t)b * CH + c) * N4 + n0 + tx];
    }
    __syncthreads();
#pragma unroll
    for (int i = 0; i < 4; ++i) {
        int n = n0 + ty + 8 * i;
        featTb[((size_t)b * N4 + n) * CH + c0 + tx] = f2b(tile[tx][ty + 8 * i]);
    }
}

// ---------------- KNN via exact threshold-select (bisection on fp32 bit pattern) ----------------
// 512-thread blocks: 8 queries/block -> 100% occupancy (thread-capped, not LDS-capped).
__global__ __launch_bounds__(512) void k_knn(const float* __restrict__ xyz4, int* __restrict__ idxout) {
    __shared__ float pts[N4 * 3];
    int b = blockIdx.x >> 8;            // 256 blocks per batch
    int qbase = (blockIdx.x & 255) * 8;
    for (int i = threadIdx.x; i < N4 * 3; i += 512) pts[i] = xyz4[(size_t)b * N4 * 3 + i];
    __syncthreads();
    int wave = threadIdx.x >> 6, lane = threadIdx.x & 63;
    int qn = qbase + wave;
    float qx = pts[qn * 3 + 0], qy = pts[qn * 3 + 1], qz = pts[qn * 3 + 2];
    float d[32];
#pragma unroll
    for (int t = 0; t < 32; ++t) {
        int c = t * 64 + lane;
        float dx = pts[c * 3 + 0] - qx;
        float dy = pts[c * 3 + 1] - qy;
        float dz = pts[c * 3 + 2] - qz;
        d[t] = dx * dx + dy * dy + dz * dz;
    }
    uint lo = 0u, hi = 0x7F800000u;
    int cLT = 0;
    while (hi - lo > 1u) {
        uint mid = (lo + hi) >> 1;
        float fmid = __uint_as_float(mid);
        int c = 0;
#pragma unroll
        for (int t = 0; t < 32; ++t) c += __popcll(__ballot(d[t] < fmid));
        if (c < KNN) { lo = mid; cLT = c; } else hi = mid;
    }
    float T = __uint_as_float(lo);      // T = exact 32nd smallest value; cLT = count(d < T)
    int outb = (b * N4 + qn) * KNN;
    unsigned long long lmlt = (1ull << lane) - 1ull;
    int baseLT = 0, baseEQ = cLT;
#pragma unroll
    for (int t = 0; t < 32; ++t) {
        bool lt = d[t] < T;
        unsigned long long m = __ballot(lt);
        if (lt) idxout[outb + baseLT + __popcll(m & lmlt)] = t * 64 + lane;
        baseLT += __popcll(m);
        bool eq = (d[t] == T);
        unsigned long long me = __ballot(eq);
        if (eq) {
            int rk = baseEQ + __popcll(me & lmlt);
            if (rk < KNN) idxout[outb + rk] = t * 64 + lane;
        }
        baseEQ += __popcll(me);
    }
}

// ---------------- dense z GEMM: z[p] = [in_p | xyz_p] @ W1^T (fp32 out) ----------------
// stats == nullptr: in_p = Fb row (plain bf16). stats != nullptr: in_p = normrelu(Fb row, stats)
// (folds the former passC2 into the SA2 staging).
__global__ __launch_bounds__(256) void k_dense(
    const ushort* __restrict__ Fb, const float* __restrict__ xyz4,
    const ushort* __restrict__ W1b, float* __restrict__ z,
    const float* __restrict__ stats)
{
    __shared__ __align__(16) ushort hs[64][168];
    __shared__ float smean[128], sinv[128];
    int t = threadIdx.x;
    int r = t >> 2, q = t & 3;
    int l = t & 63, w = t >> 6, lr = l & 15, lg = l >> 4;
    int g0 = blockIdx.x * 64;
    int b = g0 >> 11;                    // 2048 points per batch
    if (stats) {
        if (t < 128) {
            float s = stats[b * CH + t], q2 = stats[B * CH + b * CH + t];
            float mean = s * (1.f / ROWS_PER_B);
            float var = q2 * (1.f / ROWS_PER_B) - mean * mean;
            smean[t] = mean; sinv[t] = rsqrtf(var + 1e-5f);
        }
        __syncthreads();
    }
    {
        int p = g0 + r;
        const uint4* src = (const uint4*)(Fb + (size_t)p * CH) + q * 4;
        uint4* dst = (uint4*)&hs[r][q * 32];
        if (stats) {
#pragma unroll
            for (int m = 0; m < 4; ++m) {
                uint4 v = src[m];
                const uint* pv = (const uint*)&v;
                ushort o[8];
#pragma unroll
                for (int e = 0; e < 4; ++e) {
                    int c = q * 32 + m * 8 + e * 2;
                    o[e * 2]     = f2b(fmaxf((bf2f((ushort)(pv[e] & 0xffff)) - smean[c])     * sinv[c],     0.f));
                    o[e * 2 + 1] = f2b(fmaxf((bf2f((ushort)(pv[e] >> 16))    - smean[c + 1]) * sinv[c + 1], 0.f));
                }
                dst[m] = *(uint4*)o;
            }
        } else {
#pragma unroll
            for (int m = 0; m < 4; ++m) dst[m] = src[m];
        }
        uint4 zz = make_uint4(0, 0, 0, 0);
        *(uint4*)&hs[r][128 + q * 8] = zz;
        if (q == 0) {
            *(uint4*)&hs[r][160] = zz;
            hs[r][128] = f2b(xyz4[p * 3 + 0]);
            hs[r][129] = f2b(xyz4[p * 3 + 1]);
            hs[r][130] = f2b(xyz4[p * 3 + 2]);
        }
    }
    U16 bf[5][2];
#pragma unroll
    for (int kc = 0; kc < 5; ++kc)
#pragma unroll
        for (int jj = 0; jj < 2; ++jj)
            bf[kc][jj].u = *(const uint4*)&W1b[(size_t)(w * 32 + jj * 16 + lr) * 168 + kc * 32 + lg * 8];
    __syncthreads();
    f32x4 acc[4][2];
    f32x4 z4 = {0.f, 0.f, 0.f, 0.f};
#pragma unroll
    for (int i = 0; i < 4; ++i) { acc[i][0] = z4; acc[i][1] = z4; }
#pragma unroll
    for (int kc = 0; kc < 5; ++kc) {
        U16 a[4];
#pragma unroll
        for (int i = 0; i < 4; ++i) a[i].u = *(const uint4*)&hs[16 * i + lr][kc * 32 + lg * 8];
#pragma unroll
        for (int i = 0; i < 4; ++i)
#pragma unroll
            for (int jj = 0; jj < 2; ++jj)
                acc[i][jj] = __builtin_amdgcn_mfma_f32_16x16x32_bf16(a[i].s, bf[kc][jj].s, acc[i][jj], 0, 0, 0);
    }
#pragma unroll
    for (int jj = 0; jj < 2; ++jj)
#pragma unroll
        for (int i = 0; i < 4; ++i)
#pragma unroll
            for (int rg = 0; rg < 4; ++rg)
                z[(size_t)(g0 + 16 * i + lg * 4 + rg) * CH + w * 32 + jj * 16 + lr] = acc[i][jj][rg];
}

// ---------------- gather-stats: per-(b,c) sum/sumsq of y1 = z[j]-u[n]; u computed on the fly ----------------
__global__ __launch_bounds__(256) void k_gstats(
    const float* __restrict__ z, const int* __restrict__ idx,
    const float* __restrict__ xyz4, const ushort* __restrict__ W1b,
    float* __restrict__ stats)
{
    __shared__ int idxs[32 * KNN];
    __shared__ float sacc[128], sqacc[128];
    __shared__ ushort w1x[384];          // [c][a], c*3+a
    int t = threadIdx.x;
    int gpb = blockIdx.x * 32;
    int b = gpb >> 11;
    for (int ii = t; ii < 32 * KNN; ii += 256) idxs[ii] = idx[(size_t)gpb * KNN + ii];
    if (t < 128) {
        sacc[t] = 0.f; sqacc[t] = 0.f;
        w1x[t * 3 + 0] = W1b[t * 168 + 128];
        w1x[t * 3 + 1] = W1b[t * 168 + 129];
        w1x[t * 3 + 2] = W1b[t * 168 + 130];
    }
    __syncthreads();
    int li = t >> 3, cq = (t & 7) * 16;
    int gp = gpb + li;
    float s[16], qa[16];
#pragma unroll
    for (int m = 0; m < 16; ++m) { s[m] = 0.f; qa[m] = 0.f; }
    int zb = b * N4;
#pragma unroll 4
    for (int k = 0; k < KNN; ++k) {
        int j = idxs[li * KNN + k];
        const float4* zr = (const float4*)(z + (size_t)(zb + j) * CH + cq);
#pragma unroll
        for (int m = 0; m < 4; ++m) {
            float4 v = zr[m];
#pragma unroll
            for (int e = 0; e < 4; ++e) {
                float vv = ((const float*)&v)[e];
                s[m * 4 + e] += vv; qa[m * 4 + e] += vv * vv;
            }
        }
    }
    // u[gp][cq..cq+15] on the fly (bf16-rounded xyz, bf16 W1x -> fp32)
    float x = bf2f(f2b(xyz4[gp * 3 + 0]));
    float y = bf2f(f2b(xyz4[gp * 3 + 1]));
    float zc = bf2f(f2b(xyz4[gp * 3 + 2]));
#pragma unroll
    for (int m = 0; m < 4; ++m) {
#pragma unroll
        for (int e = 0; e < 4; ++e) {
            int c = cq + m * 4 + e;
            float uu = x * bf2f(w1x[c * 3]) + y * bf2f(w1x[c * 3 + 1]) + zc * bf2f(w1x[c * 3 + 2]);
            float ss = s[m * 4 + e], qq = qa[m * 4 + e];
            atomicAdd(&sacc[c], ss - 32.f * uu);
            atomicAdd(&sqacc[c], qq - 2.f * uu * ss + 32.f * uu * uu);
        }
    }
    __syncthreads();
    if (t < 128) {
        atomicAdd(&stats[b * CH + t], sacc[t]);
        atomicAdd(&stats[B * CH + b * CH + t], sqacc[t]);
    }
}

// ---------------- fused pass: 256 rows/block, dbuf LDS; u computed on the fly ----------------
__global__ __launch_bounds__(256) void k_fused2(
    const float* __restrict__ z, const int* __restrict__ idx,
    const float* __restrict__ xyz4, const ushort* __restrict__ W1b,
    const ushort* __restrict__ W2b, const float* __restrict__ stats1,
    float* __restrict__ stats2, ushort* __restrict__ ymax)
{
    __shared__ __align__(16) ushort hs[2][64][136];
    __shared__ float smean[128], sinv[128];
    __shared__ float us[8][128];
    __shared__ ushort w1x[384];
    int t = threadIdx.x;
    int g0 = blockIdx.x * 256;          // 256 rows = 8 points
    int b = g0 >> 16;
    int gp0 = g0 >> 5;
    int l = t & 63, w = t >> 6, lr = l & 15, lg = l >> 4;
    U16 b2f[4][2];
#pragma unroll
    for (int kc = 0; kc < 4; ++kc)
#pragma unroll
        for (int jj = 0; jj < 2; ++jj)
            b2f[kc][jj].u = *(const uint4*)&W2b[(size_t)(w * 32 + jj * 16 + lr) * 136 + kc * 32 + lg * 8];
    if (t < 128) {
        float s = stats1[b * CH + t], q2 = stats1[B * CH + b * CH + t];
        float mean = s * (1.f / ROWS_PER_B);
        float var = q2 * (1.f / ROWS_PER_B) - mean * mean;
        smean[t] = mean; sinv[t] = rsqrtf(var + 1e-5f);
        w1x[t * 3 + 0] = W1b[t * 168 + 128];
        w1x[t * 3 + 1] = W1b[t * 168 + 129];
        w1x[t * 3 + 2] = W1b[t * 168 + 130];
    }
    __syncthreads();
    {   // us: 8 points x 128 cols, 4 cols/thread, same formula as k_gstats
        int p = t >> 5, i = t & 31;
        float x = bf2f(f2b(xyz4[(gp0 + p) * 3 + 0]));
        float y = bf2f(f2b(xyz4[(gp0 + p) * 3 + 1]));
        float zc = bf2f(f2b(xyz4[(gp0 + p) * 3 + 2]));
#pragma unroll
        for (int jj = 0; jj < 4; ++jj) {
            int c = i * 4 + jj;
            us[p][c] = x * bf2f(w1x[c * 3]) + y * bf2f(w1x[c * 3 + 1]) + zc * bf2f(w1x[c * 3 + 2]);
        }
    }
    int r = t >> 2, q = t & 3;
    // prologue: z loads for sub-tile 0
    float4 zv[8];
    {
        int j = idx[g0 + r];
        const float4* zr = (const float4*)(z + (size_t)(b * N4 + j) * CH + q * 32);
#pragma unroll
        for (int m = 0; m < 8; ++m) zv[m] = zr[m];
    }
    float sA[2] = {0.f, 0.f}, qA[2] = {0.f, 0.f};
    f32x4 z4 = {0.f, 0.f, 0.f, 0.f};
    __syncthreads();   // smean/sinv/us ready
    for (int st = 0; st < 4; ++st) {
        ushort (*buf)[136] = hs[st & 1];
        {
            int urow = (st * 64 + r) >> 5;
#pragma unroll
            for (int mm = 0; mm < 4; ++mm) {
                ushort o[8];
#pragma unroll
                for (int h = 0; h < 2; ++h) {
                    float4 v = zv[mm * 2 + h];
#pragma unroll
                    for (int e = 0; e < 4; ++e) {
                        int c = q * 32 + mm * 8 + h * 4 + e;
                        float val = (((const float*)&v)[e] - us[urow][c] - smean[c]) * sinv[c];
                        o[h * 4 + e] = f2b(fmaxf(val, 0.f));
                    }
                }
                *(uint4*)&buf[r][q * 32 + mm * 8] = *(uint4*)o;
            }
            if (q == 0) { uint4 zz = make_uint4(0, 0, 0, 0); *(uint4*)&buf[r][128] = zz; }
        }
        __syncthreads();
        if (st < 3) {
            int j = idx[g0 + (st + 1) * 64 + r];
            const float4* zr = (const float4*)(z + (size_t)(b * N4 + j) * CH + q * 32);
#pragma unroll
            for (int m = 0; m < 8; ++m) zv[m] = zr[m];
        }
        f32x4 acc[4][2];
#pragma unroll
        for (int i = 0; i < 4; ++i) { acc[i][0] = z4; acc[i][1] = z4; }
#pragma unroll
        for (int kc = 0; kc < 4; ++kc) {
            U16 a[4];
#pragma unroll
            for (int i = 0; i < 4; ++i) a[i].u = *(const uint4*)&buf[16 * i + lr][kc * 32 + lg * 8];
#pragma unroll
            for (int i = 0; i < 4; ++i)
#pragma unroll
                for (int jj = 0; jj < 2; ++jj)
                    acc[i][jj] = __builtin_amdgcn_mfma_f32_16x16x32_bf16(a[i].s, b2f[kc][jj].s, acc[i][jj], 0, 0, 0);
        }
        int gpA = gp0 + st * 2;
#pragma unroll
        for (int jj = 0; jj < 2; ++jj) {
            int c = w * 32 + jj * 16 + lr;
            float m0 = -3.4e38f, m1 = -3.4e38f;
#pragma unroll
            for (int i = 0; i < 4; ++i)
#pragma unroll
                for (int rg = 0; rg < 4; ++rg) {
                    float v = acc[i][jj][rg];
                    sA[jj] += v; qA[jj] += v * v;
                    if (i < 2) m0 = fmaxf(m0, v); else m1 = fmaxf(m1, v);
                }
            m0 = fmaxf(m0, __shfl_xor(m0, 16, 64)); m0 = fmaxf(m0, __shfl_xor(m0, 32, 64));
            m1 = fmaxf(m1, __shfl_xor(m1, 16, 64)); m1 = fmaxf(m1, __shfl_xor(m1, 32, 64));
            if (lg == 0) {
                ymax[(size_t)gpA * CH + c] = f2b(m0);
                ymax[(size_t)(gpA + 1) * CH + c] = f2b(m1);
            }
        }
    }
#pragma unroll
    for (int jj = 0; jj < 2; ++jj) {
        int c = w * 32 + jj * 16 + lr;
        float ss = sA[jj], qq = qA[jj];
        ss += __shfl_xor(ss, 16, 64); ss += __shfl_xor(ss, 32, 64);
        qq += __shfl_xor(qq, 16, 64); qq += __shfl_xor(qq, 32, 64);
        if (lg == 0) {
            atomicAdd(&stats2[b * CH + c], ss);
            atomicAdd(&stats2[B * CH + b * CH + c], qq);
        }
    }
}

// ---------------- FC head: relu(normrelu(ymax)@W1^T+b1) @ W2^T + b2 -> flow_lr [B,3,N4] ----------------
// (folds the former passC2-SA2 into the load stage)
__global__ __launch_bounds__(256, 1) void k_fc(
    const ushort* __restrict__ Ymax, const float* __restrict__ stats,
    const float* __restrict__ W1, const float* __restrict__ b1,
    const float* __restrict__ W2, const float* __restrict__ b2,
    float* __restrict__ out)
{
    __shared__ float hs[64][132];
    __shared__ float ws[128][132];
    __shared__ float smean[128], sinv[128];
    int t = threadIdx.x;
    int g0 = blockIdx.x * 64;
    int b = g0 >> 11;
    if (t < 128) {
        float s = stats[b * CH + t], q2 = stats[B * CH + b * CH + t];
        float mean = s * (1.f / ROWS_PER_B);
        float var = q2 * (1.f / ROWS_PER_B) - mean * mean;
        smean[t] = mean; sinv[t] = rsqrtf(var + 1e-5f);
    }
    for (int i = t; i < 128 * 132; i += 256) {
        int dd = i / 132, c = i - dd * 132;
        ws[dd][c] = (c < 128) ? W1[dd * 128 + c] : 0.f;
    }
    __syncthreads();   // smean/sinv ready
    int r = t >> 2, q = t & 3;
    {
        const uint4* Xrow = (const uint4*)(Ymax + (size_t)(g0 + r) * CH + q * 32);
#pragma unroll
        for (int m = 0; m < 4; ++m) {
            uint4 v = Xrow[m];
            const uint* pv = (const uint*)&v;
            int c0 = q * 32 + m * 8;
#pragma unroll
            for (int e = 0; e < 4; ++e) {
                int c = c0 + 2 * e;
                hs[r][c]     = fmaxf((bf2f((ushort)(pv[e] & 0xffff)) - smean[c])     * sinv[c],     0.f);
                hs[r][c + 1] = fmaxf((bf2f((ushort)(pv[e] >> 16))    - smean[c + 1]) * sinv[c + 1], 0.f);
            }
        }
        if (q == 0) *(float4*)&hs[r][128] = make_float4(0.f, 0.f, 0.f, 0.f);
    }
    __syncthreads();
    int tx = t & 15, ty = t >> 4;
    float acc[4][8];
#pragma unroll
    for (int i = 0; i < 4; ++i)
#pragma unroll
        for (int jj = 0; jj < 8; ++jj) acc[i][jj] = 0.f;
    for (int kb = 0; kb < 33; ++kb) {
        float4 a[4]; float4 w[8];
#pragma unroll
        for (int i = 0; i < 4; ++i) a[i] = *(float4*)&hs[ty * 4 + i][kb * 4];
#pragma unroll
        for (int jj = 0; jj < 8; ++jj) w[jj] = *(float4*)&ws[tx + 16 * jj][kb * 4];
#pragma unroll
        for (int i = 0; i < 4; ++i)
#pragma unroll
            for (int jj = 0; jj < 8; ++jj)
                acc[i][jj] += a[i].x * w[jj].x + a[i].y * w[jj].y
                            + a[i].z * w[jj].z + a[i].w * w[jj].w;
    }
    __syncthreads();                     // done reading hs
#pragma unroll
    for (int jj = 0; jj < 8; ++jj) {
        int c = tx + 16 * jj;
        float bias = b1[c];
#pragma unroll
        for (int i = 0; i < 4; ++i)
            hs[ty * 4 + i][c] = fmaxf(acc[i][jj] + bias, 0.f);
    }
    __syncthreads();
    if (t < 192) {
        int rr = t / 3, o = t - rr * 3;
        float sum = b2[o];
        for (int c = 0; c < 128; ++c) sum += hs[rr][c] * W2[o * 128 + c];
        int g = g0 + rr;
        int bb = g >> 11, n = g & (N4 - 1);
        out[FLOWLR_OFF + ((size_t)bb * 3 + o) * N4 + n] = sum;
    }
}

// ---------------- feature propagation: 3-NN inverse-sqdist interp onto xyz1 ----------------
// GRID: B * (N1/64) = 1024 blocks (64 queries per block, 4 threads each).
__global__ __launch_bounds__(256) void k_fp(
    const float* __restrict__ xyz_s1, const float* __restrict__ xyz4,
    float* __restrict__ out)
{
    __shared__ float xs[4 * 528], ys[4 * 528], zs[4 * 528];
    int b = blockIdx.x >> 7;             // 128 blocks per batch
    int q0 = (blockIdx.x & 127) * 64;
    int t = threadIdx.x;
    for (int i = t; i < N4; i += 256) {
        int p = (i >> 9) * 528 + (i & 511);
        const float* s = xyz4 + (size_t)b * N4 * 3 + (size_t)i * 3;
        xs[p] = s[0]; ys[p] = s[1]; zs[p] = s[2];
    }
    __syncthreads();
    int q = q0 + (t >> 2), c = t & 3;
    float qx = xyz_s1[((size_t)b * 3 + 0) * N1 + q];
    float qy = xyz_s1[((size_t)b * 3 + 1) * N1 + q];
    float qz = xyz_s1[((size_t)b * 3 + 2) * N1 + q];
    float d0 = 3.4e38f, d1 = 3.4e38f, d2 = 3.4e38f;
    int i0 = 0, i1 = 0, i2 = 0;
    int base = c * 528, nb = c * 512;
    for (int ii = 0; ii < 512; ii += 4) {
        float4 x4 = *(float4*)&xs[base + ii];
        float4 y4 = *(float4*)&ys[base + ii];
        float4 z4 = *(float4*)&zs[base + ii];
#pragma unroll
        for (int j = 0; j < 4; ++j) {
            float dx = ((const float*)&x4)[j] - qx;
            float dy = ((const float*)&y4)[j] - qy;
            float dz = ((const float*)&z4)[j] - qz;
            float dd = dx * dx + dy * dy + dz * dz;
            if (dd < d2) {
                int n = nb + ii + j;
                if (dd < d0)      { d2 = d1; i2 = i1; d1 = d0; i1 = i0; d0 = dd; i0 = n; }
                else if (dd < d1) { d2 = d1; i2 = i1; d1 = dd; i1 = n; }
                else              { d2 = dd; i2 = n; }
            }
        }
    }
#pragma unroll
    for (int m = 1; m <= 2; m <<= 1) {
        float e0 = __shfl_xor(d0, m, 64), e1 = __shfl_xor(d1, m, 64), e2 = __shfl_xor(d2, m, 64);
        int   j0 = __shfl_xor(i0, m, 64), j1 = __shfl_xor(i1, m, 64), j2 = __shfl_xor(i2, m, 64);
        float ed[3] = { e0, e1, e2 }; int ej[3] = { j0, j1, j2 };
#pragma unroll
        for (int s = 0; s < 3; ++s) {
            float dd = ed[s]; int jn = ej[s];
            bool lt2 = dd < d2 || (dd == d2 && jn < i2);
            if (lt2) {
                bool lt0 = dd < d0 || (dd == d0 && jn < i0);
                bool lt1 = dd < d1 || (dd == d1 && jn < i1);
                if (lt0)      { d2 = d1; i2 = i1; d1 = d0; i1 = i0; d0 = dd; i0 = jn; }
                else if (lt1) { d2 = d1; i2 = i1; d1 = dd; i1 = jn; }
                else          { d2 = dd; i2 = jn; }
            }
        }
    }
    float w0 = 1.f / (d0 + 1e-8f), w1 = 1.f / (d1 + 1e-8f), w2 = 1.f / (d2 + 1e-8f);
    float inv = 1.f / (w0 + w1 + w2);
    const float* flr = out + FLOWLR_OFF + (size_t)b * 3 * N4;
    if (c < 3) {
        float v = (w0 * flr[c * N4 + i0] + w1 * flr[c * N4 + i1] + w2 * flr[c * N4 + i2]) * inv;
        out[((size_t)b * 3 + c) * N1 + q] = v;
    }
}

extern "C" void kernel_launch(void* const* d_in, const int* in_sizes, int n_in,
                              void* d_out, int out_size, void* d_ws, size_t ws_size,
                              hipStream_t stream) {
    const float* xyz_s1 = (const float*)d_in[0];
    const float* xyz_s4 = (const float*)d_in[1];
    const float* feats  = (const float*)d_in[2];
    const float* sa1_W1 = (const float*)d_in[3];
    const float* sa1_W2 = (const float*)d_in[5];
    const float* sa2_W1 = (const float*)d_in[7];
    const float* sa2_W2 = (const float*)d_in[9];
    const float* fc_W1  = (const float*)d_in[11];
    const float* fc_b1  = (const float*)d_in[12];
    const float* fc_W2  = (const float*)d_in[13];
    const float* fc_b2  = (const float*)d_in[14];
    float* out = (float*)d_out;

    char* wsb = (char*)d_ws;
    float*  xyz4   = (float*)(wsb + 0);                  // 196608 B
    int*    idx    = (int*)(wsb + 196608);               // 2 MB   -> 2293760
    ushort* featTb = (ushort*)(wsb + 2293760);           // 4 MB   -> 6488064
    ushort* W1b1   = (ushort*)(wsb + 6488064);           // 64 KB  -> 6553600
    ushort* W1b2   = (ushort*)(wsb + 6553600);           // 64 KB  -> 6619136
    ushort* W2b1   = (ushort*)(wsb + 6619136);           // 64 KB  -> 6684672
    ushort* W2b2   = (ushort*)(wsb + 6684672);           // 64 KB  -> 6750208
    float*  statsA = (float*)(wsb + 6750208);            // 8 KB each x4 (contiguous)
    float*  statsB = (float*)(wsb + 6758400);
    float*  statsC = (float*)(wsb + 6766592);
    float*  statsD = (float*)(wsb + 6774784);
    ushort* ymax   = (ushort*)(wsb + 6782976);           // 4 MB  -> 10977280
    float*  zbuf   = (float*)(wsb + 10977280);           // 8 MB  -> 19365888

    // ---- setup ----
    k_prep<<<400, 256, 0, stream>>>(xyz_s4, xyz4, sa1_W1, sa2_W1, sa1_W2, sa2_W2,
                                    W1b1, W1b2, W2b1, W2b2, statsA);
    k_knn<<<B * (N4 / 8), 512, 0, stream>>>(xyz4, idx);
    dim3 gt(B, N4 / 32, CH / 32), bt(32, 8);
    k_feat_t<<<gt, bt, 0, stream>>>(feats, featTb);

    // ---- SA1 ----
    k_dense<<<NPTS / 64, 256, 0, stream>>>(featTb, xyz4, W1b1, zbuf, nullptr);
    k_gstats<<<NPTS / 32, 256, 0, stream>>>(zbuf, idx, xyz4, W1b1, statsA);
    k_fused2<<<ROWS_TOTAL / 256, 256, 0, stream>>>(zbuf, idx, xyz4, W1b1, W2b1,
                                                   statsA, statsB, ymax);
    // ---- SA2 (dense folds the SA1 norm+relu of ymax via statsB) ----
    k_dense<<<NPTS / 64, 256, 0, stream>>>(ymax, xyz4, W1b2, zbuf, statsB);
    k_gstats<<<NPTS / 32, 256, 0, stream>>>(zbuf, idx, xyz4, W1b2, statsC);
    k_fused2<<<ROWS_TOTAL / 256, 256, 0, stream>>>(zbuf, idx, xyz4, W1b2, W2b2,
                                                   statsC, statsD, ymax);

    // ---- FC head (folds SA2 norm+relu via statsD) + flow_lr ----
    k_fc<<<(B * N4) / 64, 256, 0, stream>>>(ymax, statsD, fc_W1, fc_b1, fc_W2, fc_b2, out);
    // ---- feature propagation -> flow ----
    k_fp<<<B * (N1 / 64), 256, 0, stream>>>(xyz_s1, xyz4, out);
}

// Round 12
// 395.727 us; speedup vs baseline: 8.9262x; 1.0351x over previous
//
#include <hip/hip_runtime.h>
#include <hip/hip_bf16.h>

#define B 8
#define N1 8192
#define N4 2048
#define CH 128
#define KNN 32
#define ROWS_PER_B (N4 * KNN)          // 65536 rows per batch in the [B,N,K] flattening
#define ROWS_TOTAL (B * ROWS_PER_B)    // 524288
#define NPTS (B * N4)                  // 16384 total points
#define FLOWLR_OFF (B * 3 * N1)        // flow_lr starts after flow in d_out

typedef unsigned int uint;
typedef unsigned short ushort;
typedef __attribute__((ext_vector_type(8))) short short8;
typedef __attribute__((ext_vector_type(4))) float f32x4;

union U16 { uint4 u; short8 s; };

__device__ __forceinline__ float bf2f(ushort u) {
    union { uint i; float f; } v; v.i = ((uint)u) << 16; return v.f;
}
__device__ __forceinline__ ushort f2b(float f) {
    __hip_bfloat16 h = __float2bfloat16(f);
    return *(ushort*)&h;
}

// ---------------- prep: fused W converters (bf16, permuted/padded) + xyz transpose + stats zero ----------------
__global__ void k_prep(const float* __restrict__ xyz_s4, float* __restrict__ xyz4,
                       const float* __restrict__ sa1_W1, const float* __restrict__ sa2_W1,
                       const float* __restrict__ sa1_W2, const float* __restrict__ sa2_W2,
                       ushort* __restrict__ W1b1, ushort* __restrict__ W1b2,
                       ushort* __restrict__ W2b1, ushort* __restrict__ W2b2,
                       float* __restrict__ stats)
{
    int i = blockIdx.x * 256 + threadIdx.x;
    if (i < 43008) {
        const float* W = (i < 21504) ? sa1_W1 : sa2_W1;
        ushort* o = (i < 21504) ? W1b1 : W1b2;
        int j = (i < 21504) ? i : i - 21504;
        int d = j / 168, c = j - d * 168;
        float v = 0.f;
        if (c < 128)      v = W[d * 131 + 3 + c];
        else if (c < 131) v = W[d * 131 + (c - 128)];
        o[j] = f2b(v);
    } else if (i < 77824) {
        const float* W = (i < 60416) ? sa1_W2 : sa2_W2;
        ushort* o = (i < 60416) ? W2b1 : W2b2;
        int j = (i < 60416) ? i - 43008 : i - 60416;
        int d = j / 136, c = j - d * 136;
        o[j] = (c < 128) ? f2b(W[d * 128 + c]) : (ushort)0;
    } else if (i < 94208) {
        int g = i - 77824;
        int b = g >> 11, n = g & (N4 - 1);
        xyz4[g * 3 + 0] = xyz_s4[(b * 3 + 0) * N4 + n];
        xyz4[g * 3 + 1] = xyz_s4[(b * 3 + 1) * N4 + n];
        xyz4[g * 3 + 2] = xyz_s4[(b * 3 + 2) * N4 + n];
    } else if (i < 102400) {
        stats[i - 94208] = 0.f;        // zeros statsA..statsD (contiguous 8192 floats)
    }
}

// ---------------- transpose feats [B,C,N4] fp32 -> featTb [B,N4,C] bf16 ----------------
__global__ void k_feat_t(const float* __restrict__ feats, ushort* __restrict__ featTb) {
    __shared__ float tile[32][33];
    int b = blockIdx.x, nb = blockIdx.y, cb = blockIdx.z;
    int tx = threadIdx.x, ty = threadIdx.y; // 32 x 8
    int n0 = nb * 32, c0 = cb * 32;
#pragma unroll
    for (int i = 0; i < 4; ++i) {
        int c = c0 + ty + 8 * i;
        tile[ty + 8 * i][tx] = feats[((size_t)b * CH + c) * N4 + n0 + tx];
    }
    __syncthreads();
#pragma unroll
    for (int i = 0; i < 4; ++i) {
        int n = n0 + ty + 8 * i;
        featTb[((size_t)b * N4 + n) * CH + c0 + tx] = f2b(tile[tx][ty + 8 * i]);
    }
}

// ---------------- KNN via exact threshold-select (safeguarded interpolation search) ----------------
// SALU-bound before: 31 bit-bisection iters x ~66 SALU (1 scalar unit/CU). Interpolation in
// value space (counts are a smooth CDF) + alternating bit-bisection safeguard cuts iterations
// to ~7-10. Early exit: when the bracket holds exactly ONE element (cHI-cLT==1), that element
// IS T (rank 32, since cLT==31) -> extract via masked wave-min. T and the emitted index set
// are bit-identical to full bisection (== exact lax.top_k set).
__global__ __launch_bounds__(512) void k_knn(const float* __restrict__ xyz4, int* __restrict__ idxout) {
    __shared__ float pts[N4 * 3];
    int b = blockIdx.x >> 8;            // 256 blocks per batch
    int qbase = (blockIdx.x & 255) * 8;
    for (int i = threadIdx.x; i < N4 * 3; i += 512) pts[i] = xyz4[(size_t)b * N4 * 3 + i];
    __syncthreads();
    int wave = threadIdx.x >> 6, lane = threadIdx.x & 63;
    int qn = qbase + wave;
    float qx = pts[qn * 3 + 0], qy = pts[qn * 3 + 1], qz = pts[qn * 3 + 2];
    float d[32];
#pragma unroll
    for (int t = 0; t < 32; ++t) {
        int c = t * 64 + lane;
        float dx = pts[c * 3 + 0] - qx;
        float dy = pts[c * 3 + 1] - qy;
        float dz = pts[c * 3 + 2] - qz;
        d[t] = dx * dx + dy * dy + dz * dz;
    }
    // invariant: count(d < f(lo)) = cLT < 32 <= cHI = count(d < f(hi)); d>=0 so uint order == float order
    uint lo = 0u, hi = 0x7F800000u;
    int cLT = 0, cHI = N4;
    float T;
    int it = 1;                          // start with a bisection step (f(hi)=inf initially)
    for (;;) {
        if (hi - lo <= 1u) { T = __uint_as_float(lo); break; }
        if (cHI - cLT == 1) {
            // exactly one element in [f(lo), f(hi)) and cLT==31 -> that element is T
            float flo = __uint_as_float(lo), fhi = __uint_as_float(hi);
            float m = 3.4e38f;
#pragma unroll
            for (int t = 0; t < 32; ++t) {
                float dv = d[t];
                if (dv >= flo && dv < fhi) m = fminf(m, dv);
            }
#pragma unroll
            for (int s = 1; s < 64; s <<= 1) m = fminf(m, __shfl_xor(m, s, 64));
            T = m;
            break;
        }
        uint mid;
        if (it & 1) {
            mid = (lo + hi) >> 1;        // safeguard: bit-space bisection
        } else {
            float flo = __uint_as_float(lo), fhi = __uint_as_float(hi);
            float fm = flo + (fhi - flo) * ((float)(KNN - cLT) / (float)(cHI - cLT));
            mid = __float_as_uint(fm);
            if (mid <= lo) mid = lo + 1u;
            if (mid >= hi) mid = hi - 1u;
        }
        float fmid = __uint_as_float(mid);
        int c = 0;
#pragma unroll
        for (int t = 0; t < 32; ++t) c += __popcll(__ballot(d[t] < fmid));
        if (c < KNN) { lo = mid; cLT = c; } else { hi = mid; cHI = c; }
        ++it;
    }
    // compaction: d<T at ranks [0,cLT); ties d==T fill [cLT,32) in ascending (t,lane) = ascending index
    int outb = (b * N4 + qn) * KNN;
    unsigned long long lmlt = (1ull << lane) - 1ull;
    int baseLT = 0, baseEQ = cLT;
#pragma unroll
    for (int t = 0; t < 32; ++t) {
        bool lt = d[t] < T;
        unsigned long long m = __ballot(lt);
        if (lt) idxout[outb + baseLT + __popcll(m & lmlt)] = t * 64 + lane;
        baseLT += __popcll(m);
        bool eq = (d[t] == T);
        unsigned long long me = __ballot(eq);
        if (eq) {
            int rk = baseEQ + __popcll(me & lmlt);
            if (rk < KNN) idxout[outb + rk] = t * 64 + lane;
        }
        baseEQ += __popcll(me);
    }
}

// ---------------- dense z GEMM: z[p] = [in_p | xyz_p] @ W1^T (fp32 out) ----------------
// stats == nullptr: in_p = Fb row (plain bf16). stats != nullptr: in_p = normrelu(Fb row, stats)
__global__ __launch_bounds__(256) void k_dense(
    const ushort* __restrict__ Fb, const float* __restrict__ xyz4,
    const ushort* __restrict__ W1b, float* __restrict__ z,
    const float* __restrict__ stats)
{
    __shared__ __align__(16) ushort hs[64][168];
    __shared__ float smean[128], sinv[128];
    int t = threadIdx.x;
    int r = t >> 2, q = t & 3;
    int l = t & 63, w = t >> 6, lr = l & 15, lg = l >> 4;
    int g0 = blockIdx.x * 64;
    int b = g0 >> 11;                    // 2048 points per batch
    if (stats) {
        if (t < 128) {
            float s = stats[b * CH + t], q2 = stats[B * CH + b * CH + t];
            float mean = s * (1.f / ROWS_PER_B);
            float var = q2 * (1.f / ROWS_PER_B) - mean * mean;
            smean[t] = mean; sinv[t] = rsqrtf(var + 1e-5f);
        }
        __syncthreads();
    }
    {
        int p = g0 + r;
        const uint4* src = (const uint4*)(Fb + (size_t)p * CH) + q * 4;
        uint4* dst = (uint4*)&hs[r][q * 32];
        if (stats) {
#pragma unroll
            for (int m = 0; m < 4; ++m) {
                uint4 v = src[m];
                const uint* pv = (const uint*)&v;
                ushort o[8];
#pragma unroll
                for (int e = 0; e < 4; ++e) {
                    int c = q * 32 + m * 8 + e * 2;
                    o[e * 2]     = f2b(fmaxf((bf2f((ushort)(pv[e] & 0xffff)) - smean[c])     * sinv[c],     0.f));
                    o[e * 2 + 1] = f2b(fmaxf((bf2f((ushort)(pv[e] >> 16))    - smean[c + 1]) * sinv[c + 1], 0.f));
                }
                dst[m] = *(uint4*)o;
            }
        } else {
#pragma unroll
            for (int m = 0; m < 4; ++m) dst[m] = src[m];
        }
        uint4 zz = make_uint4(0, 0, 0, 0);
        *(uint4*)&hs[r][128 + q * 8] = zz;
        if (q == 0) {
            *(uint4*)&hs[r][160] = zz;
            hs[r][128] = f2b(xyz4[p * 3 + 0]);
            hs[r][129] = f2b(xyz4[p * 3 + 1]);
            hs[r][130] = f2b(xyz4[p * 3 + 2]);
        }
    }
    U16 bf[5][2];
#pragma unroll
    for (int kc = 0; kc < 5; ++kc)
#pragma unroll
        for (int jj = 0; jj < 2; ++jj)
            bf[kc][jj].u = *(const uint4*)&W1b[(size_t)(w * 32 + jj * 16 + lr) * 168 + kc * 32 + lg * 8];
    __syncthreads();
    f32x4 acc[4][2];
    f32x4 z4 = {0.f, 0.f, 0.f, 0.f};
#pragma unroll
    for (int i = 0; i < 4; ++i) { acc[i][0] = z4; acc[i][1] = z4; }
#pragma unroll
    for (int kc = 0; kc < 5; ++kc) {
        U16 a[4];
#pragma unroll
        for (int i = 0; i < 4; ++i) a[i].u = *(const uint4*)&hs[16 * i + lr][kc * 32 + lg * 8];
#pragma unroll
        for (int i = 0; i < 4; ++i)
#pragma unroll
            for (int jj = 0; jj < 2; ++jj)
                acc[i][jj] = __builtin_amdgcn_mfma_f32_16x16x32_bf16(a[i].s, bf[kc][jj].s, acc[i][jj], 0, 0, 0);
    }
#pragma unroll
    for (int jj = 0; jj < 2; ++jj)
#pragma unroll
        for (int i = 0; i < 4; ++i)
#pragma unroll
            for (int rg = 0; rg < 4; ++rg)
                z[(size_t)(g0 + 16 * i + lg * 4 + rg) * CH + w * 32 + jj * 16 + lr] = acc[i][jj][rg];
}

// ---------------- gather-stats: per-(b,c) sum/sumsq of y1 = z[j]-u[n]; u computed on the fly ----------------
__global__ __launch_bounds__(256) void k_gstats(
    const float* __restrict__ z, const int* __restrict__ idx,
    const float* __restrict__ xyz4, const ushort* __restrict__ W1b,
    float* __restrict__ stats)
{
    __shared__ int idxs[32 * KNN];
    __shared__ float sacc[128], sqacc[128];
    __shared__ ushort w1x[384];          // [c][a], c*3+a
    int t = threadIdx.x;
    int gpb = blockIdx.x * 32;
    int b = gpb >> 11;
    for (int ii = t; ii < 32 * KNN; ii += 256) idxs[ii] = idx[(size_t)gpb * KNN + ii];
    if (t < 128) {
        sacc[t] = 0.f; sqacc[t] = 0.f;
        w1x[t * 3 + 0] = W1b[t * 168 + 128];
        w1x[t * 3 + 1] = W1b[t * 168 + 129];
        w1x[t * 3 + 2] = W1b[t * 168 + 130];
    }
    __syncthreads();
    int li = t >> 3, cq = (t & 7) * 16;
    int gp = gpb + li;
    float s[16], qa[16];
#pragma unroll
    for (int m = 0; m < 16; ++m) { s[m] = 0.f; qa[m] = 0.f; }
    int zb = b * N4;
#pragma unroll 4
    for (int k = 0; k < KNN; ++k) {
        int j = idxs[li * KNN + k];
        const float4* zr = (const float4*)(z + (size_t)(zb + j) * CH + cq);
#pragma unroll
        for (int m = 0; m < 4; ++m) {
            float4 v = zr[m];
#pragma unroll
            for (int e = 0; e < 4; ++e) {
                float vv = ((const float*)&v)[e];
                s[m * 4 + e] += vv; qa[m * 4 + e] += vv * vv;
            }
        }
    }
    // u[gp][cq..cq+15] on the fly (bf16-rounded xyz, bf16 W1x -> fp32)
    float x = bf2f(f2b(xyz4[gp * 3 + 0]));
    float y = bf2f(f2b(xyz4[gp * 3 + 1]));
    float zc = bf2f(f2b(xyz4[gp * 3 + 2]));
#pragma unroll
    for (int m = 0; m < 4; ++m) {
#pragma unroll
        for (int e = 0; e < 4; ++e) {
            int c = cq + m * 4 + e;
            float uu = x * bf2f(w1x[c * 3]) + y * bf2f(w1x[c * 3 + 1]) + zc * bf2f(w1x[c * 3 + 2]);
            float ss = s[m * 4 + e], qq = qa[m * 4 + e];
            atomicAdd(&sacc[c], ss - 32.f * uu);
            atomicAdd(&sqacc[c], qq - 2.f * uu * ss + 32.f * uu * uu);
        }
    }
    __syncthreads();
    if (t < 128) {
        atomicAdd(&stats[b * CH + t], sacc[t]);
        atomicAdd(&stats[B * CH + b * CH + t], sqacc[t]);
    }
}

// ---------------- fused pass: 256 rows/block, dbuf LDS; u computed on the fly ----------------
__global__ __launch_bounds__(256) void k_fused2(
    const float* __restrict__ z, const int* __restrict__ idx,
    const float* __restrict__ xyz4, const ushort* __restrict__ W1b,
    const ushort* __restrict__ W2b, const float* __restrict__ stats1,
    float* __restrict__ stats2, ushort* __restrict__ ymax)
{
    __shared__ __align__(16) ushort hs[2][64][136];
    __shared__ float smean[128], sinv[128];
    __shared__ float us[8][128];
    __shared__ ushort w1x[384];
    int t = threadIdx.x;
    int g0 = blockIdx.x * 256;          // 256 rows = 8 points
    int b = g0 >> 16;
    int gp0 = g0 >> 5;
    int l = t & 63, w = t >> 6, lr = l & 15, lg = l >> 4;
    U16 b2f[4][2];
#pragma unroll
    for (int kc = 0; kc < 4; ++kc)
#pragma unroll
        for (int jj = 0; jj < 2; ++jj)
            b2f[kc][jj].u = *(const uint4*)&W2b[(size_t)(w * 32 + jj * 16 + lr) * 136 + kc * 32 + lg * 8];
    if (t < 128) {
        float s = stats1[b * CH + t], q2 = stats1[B * CH + b * CH + t];
        float mean = s * (1.f / ROWS_PER_B);
        float var = q2 * (1.f / ROWS_PER_B) - mean * mean;
        smean[t] = mean; sinv[t] = rsqrtf(var + 1e-5f);
        w1x[t * 3 + 0] = W1b[t * 168 + 128];
        w1x[t * 3 + 1] = W1b[t * 168 + 129];
        w1x[t * 3 + 2] = W1b[t * 168 + 130];
    }
    __syncthreads();
    {   // us: 8 points x 128 cols, 4 cols/thread, same formula as k_gstats
        int p = t >> 5, i = t & 31;
        float x = bf2f(f2b(xyz4[(gp0 + p) * 3 + 0]));
        float y = bf2f(f2b(xyz4[(gp0 + p) * 3 + 1]));
        float zc = bf2f(f2b(xyz4[(gp0 + p) * 3 + 2]));
#pragma unroll
        for (int jj = 0; jj < 4; ++jj) {
            int c = i * 4 + jj;
            us[p][c] = x * bf2f(w1x[c * 3]) + y * bf2f(w1x[c * 3 + 1]) + zc * bf2f(w1x[c * 3 + 2]);
        }
    }
    int r = t >> 2, q = t & 3;
    // prologue: z loads for sub-tile 0
    float4 zv[8];
    {
        int j = idx[g0 + r];
        const float4* zr = (const float4*)(z + (size_t)(b * N4 + j) * CH + q * 32);
#pragma unroll
        for (int m = 0; m < 8; ++m) zv[m] = zr[m];
    }
    float sA[2] = {0.f, 0.f}, qA[2] = {0.f, 0.f};
    f32x4 z4 = {0.f, 0.f, 0.f, 0.f};
    __syncthreads();   // smean/sinv/us ready
    for (int st = 0; st < 4; ++st) {
        ushort (*buf)[136] = hs[st & 1];
        {
            int urow = (st * 64 + r) >> 5;
#pragma unroll
            for (int mm = 0; mm < 4; ++mm) {
                ushort o[8];
#pragma unroll
                for (int h = 0; h < 2; ++h) {
                    float4 v = zv[mm * 2 + h];
#pragma unroll
                    for (int e = 0; e < 4; ++e) {
                        int c = q * 32 + mm * 8 + h * 4 + e;
                        float val = (((const float*)&v)[e] - us[urow][c] - smean[c]) * sinv[c];
                        o[h * 4 + e] = f2b(fmaxf(val, 0.f));
                    }
                }
                *(uint4*)&buf[r][q * 32 + mm * 8] = *(uint4*)o;
            }
            if (q == 0) { uint4 zz = make_uint4(0, 0, 0, 0); *(uint4*)&buf[r][128] = zz; }
        }
        __syncthreads();
        if (st < 3) {
            int j = idx[g0 + (st + 1) * 64 + r];
            const float4* zr = (const float4*)(z + (size_t)(b * N4 + j) * CH + q * 32);
#pragma unroll
            for (int m = 0; m < 8; ++m) zv[m] = zr[m];
        }
        f32x4 acc[4][2];
#pragma unroll
        for (int i = 0; i < 4; ++i) { acc[i][0] = z4; acc[i][1] = z4; }
#pragma unroll
        for (int kc = 0; kc < 4; ++kc) {
            U16 a[4];
#pragma unroll
            for (int i = 0; i < 4; ++i) a[i].u = *(const uint4*)&buf[16 * i + lr][kc * 32 + lg * 8];
#pragma unroll
            for (int i = 0; i < 4; ++i)
#pragma unroll
                for (int jj = 0; jj < 2; ++jj)
                    acc[i][jj] = __builtin_amdgcn_mfma_f32_16x16x32_bf16(a[i].s, b2f[kc][jj].s, acc[i][jj], 0, 0, 0);
        }
        int gpA = gp0 + st * 2;
#pragma unroll
        for (int jj = 0; jj < 2; ++jj) {
            int c = w * 32 + jj * 16 + lr;
            float m0 = -3.4e38f, m1 = -3.4e38f;
#pragma unroll
            for (int i = 0; i < 4; ++i)
#pragma unroll
                for (int rg = 0; rg < 4; ++rg) {
                    float v = acc[i][jj][rg];
                    sA[jj] += v; qA[jj] += v * v;
                    if (i < 2) m0 = fmaxf(m0, v); else m1 = fmaxf(m1, v);
                }
            m0 = fmaxf(m0, __shfl_xor(m0, 16, 64)); m0 = fmaxf(m0, __shfl_xor(m0, 32, 64));
            m1 = fmaxf(m1, __shfl_xor(m1, 16, 64)); m1 = fmaxf(m1, __shfl_xor(m1, 32, 64));
            if (lg == 0) {
                ymax[(size_t)gpA * CH + c] = f2b(m0);
                ymax[(size_t)(gpA + 1) * CH + c] = f2b(m1);
            }
        }
    }
#pragma unroll
    for (int jj = 0; jj < 2; ++jj) {
        int c = w * 32 + jj * 16 + lr;
        float ss = sA[jj], qq = qA[jj];
        ss += __shfl_xor(ss, 16, 64); ss += __shfl_xor(ss, 32, 64);
        qq += __shfl_xor(qq, 16, 64); qq += __shfl_xor(qq, 32, 64);
        if (lg == 0) {
            atomicAdd(&stats2[b * CH + c], ss);
            atomicAdd(&stats2[B * CH + b * CH + c], qq);
        }
    }
}

// ---------------- FC head: relu(normrelu(ymax)@W1^T+b1) @ W2^T + b2 -> flow_lr [B,3,N4] ----------------
__global__ __launch_bounds__(256, 1) void k_fc(
    const ushort* __restrict__ Ymax, const float* __restrict__ stats,
    const float* __restrict__ W1, const float* __restrict__ b1,
    const float* __restrict__ W2, const float* __restrict__ b2,
    float* __restrict__ out)
{
    __shared__ float hs[64][132];
    __shared__ float ws[128][132];
    __shared__ float smean[128], sinv[128];
    int t = threadIdx.x;
    int g0 = blockIdx.x * 64;
    int b = g0 >> 11;
    if (t < 128) {
        float s = stats[b * CH + t], q2 = stats[B * CH + b * CH + t];
        float mean = s * (1.f / ROWS_PER_B);
        float var = q2 * (1.f / ROWS_PER_B) - mean * mean;
        smean[t] = mean; sinv[t] = rsqrtf(var + 1e-5f);
    }
    for (int i = t; i < 128 * 132; i += 256) {
        int dd = i / 132, c = i - dd * 132;
        ws[dd][c] = (c < 128) ? W1[dd * 128 + c] : 0.f;
    }
    __syncthreads();   // smean/sinv ready
    int r = t >> 2, q = t & 3;
    {
        const uint4* Xrow = (const uint4*)(Ymax + (size_t)(g0 + r) * CH + q * 32);
#pragma unroll
        for (int m = 0; m < 4; ++m) {
            uint4 v = Xrow[m];
            const uint* pv = (const uint*)&v;
            int c0 = q * 32 + m * 8;
#pragma unroll
            for (int e = 0; e < 4; ++e) {
                int c = c0 + 2 * e;
                hs[r][c]     = fmaxf((bf2f((ushort)(pv[e] & 0xffff)) - smean[c])     * sinv[c],     0.f);
                hs[r][c + 1] = fmaxf((bf2f((ushort)(pv[e] >> 16))    - smean[c + 1]) * sinv[c + 1], 0.f);
            }
        }
        if (q == 0) *(float4*)&hs[r][128] = make_float4(0.f, 0.f, 0.f, 0.f);
    }
    __syncthreads();
    int tx = t & 15, ty = t >> 4;
    float acc[4][8];
#pragma unroll
    for (int i = 0; i < 4; ++i)
#pragma unroll
        for (int jj = 0; jj < 8; ++jj) acc[i][jj] = 0.f;
    for (int kb = 0; kb < 33; ++kb) {
        float4 a[4]; float4 w[8];
#pragma unroll
        for (int i = 0; i < 4; ++i) a[i] = *(float4*)&hs[ty * 4 + i][kb * 4];
#pragma unroll
        for (int jj = 0; jj < 8; ++jj) w[jj] = *(float4*)&ws[tx + 16 * jj][kb * 4];
#pragma unroll
        for (int i = 0; i < 4; ++i)
#pragma unroll
            for (int jj = 0; jj < 8; ++jj)
                acc[i][jj] += a[i].x * w[jj].x + a[i].y * w[jj].y
                            + a[i].z * w[jj].z + a[i].w * w[jj].w;
    }
    __syncthreads();                     // done reading hs
#pragma unroll
    for (int jj = 0; jj < 8; ++jj) {
        int c = tx + 16 * jj;
        float bias = b1[c];
#pragma unroll
        for (int i = 0; i < 4; ++i)
            hs[ty * 4 + i][c] = fmaxf(acc[i][jj] + bias, 0.f);
    }
    __syncthreads();
    if (t < 192) {
        int rr = t / 3, o = t - rr * 3;
        float sum = b2[o];
        for (int c = 0; c < 128; ++c) sum += hs[rr][c] * W2[o * 128 + c];
        int g = g0 + rr;
        int bb = g >> 11, n = g & (N4 - 1);
        out[FLOWLR_OFF + ((size_t)bb * 3 + o) * N4 + n] = sum;
    }
}

// ---------------- feature propagation: 3-NN inverse-sqdist interp onto xyz1 ----------------
// GRID: B * (N1/64) = 1024 blocks (64 queries per block, 4 threads each).
__global__ __launch_bounds__(256) void k_fp(
    const float* __restrict__ xyz_s1, const float* __restrict__ xyz4,
    float* __restrict__ out)
{
    __shared__ float xs[4 * 528], ys[4 * 528], zs[4 * 528];
    int b = blockIdx.x >> 7;             // 128 blocks per batch
    int q0 = (blockIdx.x & 127) * 64;
    int t = threadIdx.x;
    for (int i = t; i < N4; i += 256) {
        int p = (i >> 9) * 528 + (i & 511);
        const float* s = xyz4 + (size_t)b * N4 * 3 + (size_t)i * 3;
        xs[p] = s[0]; ys[p] = s[1]; zs[p] = s[2];
    }
    __syncthreads();
    int q = q0 + (t >> 2), c = t & 3;
    float qx = xyz_s1[((size_t)b * 3 + 0) * N1 + q];
    float qy = xyz_s1[((size_t)b * 3 + 1) * N1 + q];
    float qz = xyz_s1[((size_t)b * 3 + 2) * N1 + q];
    float d0 = 3.4e38f, d1 = 3.4e38f, d2 = 3.4e38f;
    int i0 = 0, i1 = 0, i2 = 0;
    int base = c * 528, nb = c * 512;
    for (int ii = 0; ii < 512; ii += 4) {
        float4 x4 = *(float4*)&xs[base + ii];
        float4 y4 = *(float4*)&ys[base + ii];
        float4 z4 = *(float4*)&zs[base + ii];
#pragma unroll
        for (int j = 0; j < 4; ++j) {
            float dx = ((const float*)&x4)[j] - qx;
            float dy = ((const float*)&y4)[j] - qy;
            float dz = ((const float*)&z4)[j] - qz;
            float dd = dx * dx + dy * dy + dz * dz;
            if (dd < d2) {
                int n = nb + ii + j;
                if (dd < d0)      { d2 = d1; i2 = i1; d1 = d0; i1 = i0; d0 = dd; i0 = n; }
                else if (dd < d1) { d2 = d1; i2 = i1; d1 = dd; i1 = n; }
                else              { d2 = dd; i2 = n; }
            }
        }
    }
#pragma unroll
    for (int m = 1; m <= 2; m <<= 1) {
        float e0 = __shfl_xor(d0, m, 64), e1 = __shfl_xor(d1, m, 64), e2 = __shfl_xor(d2, m, 64);
        int   j0 = __shfl_xor(i0, m, 64), j1 = __shfl_xor(i1, m, 64), j2 = __shfl_xor(i2, m, 64);
        float ed[3] = { e0, e1, e2 }; int ej[3] = { j0, j1, j2 };
#pragma unroll
        for (int s = 0; s < 3; ++s) {
            float dd = ed[s]; int jn = ej[s];
            bool lt2 = dd < d2 || (dd == d2 && jn < i2);
            if (lt2) {
                bool lt0 = dd < d0 || (dd == d0 && jn < i0);
                bool lt1 = dd < d1 || (dd == d1 && jn < i1);
                if (lt0)      { d2 = d1; i2 = i1; d1 = d0; i1 = i0; d0 = dd; i0 = jn; }
                else if (lt1) { d2 = d1; i2 = i1; d1 = dd; i1 = jn; }
                else          { d2 = dd; i2 = jn; }
            }
        }
    }
    float w0 = 1.f / (d0 + 1e-8f), w1 = 1.f / (d1 + 1e-8f), w2 = 1.f / (d2 + 1e-8f);
    float inv = 1.f / (w0 + w1 + w2);
    const float* flr = out + FLOWLR_OFF + (size_t)b * 3 * N4;
    if (c < 3) {
        float v = (w0 * flr[c * N4 + i0] + w1 * flr[c * N4 + i1] + w2 * flr[c * N4 + i2]) * inv;
        out[((size_t)b * 3 + c) * N1 + q] = v;
    }
}

extern "C" void kernel_launch(void* const* d_in, const int* in_sizes, int n_in,
                              void* d_out, int out_size, void* d_ws, size_t ws_size,
                              hipStream_t stream) {
    const float* xyz_s1 = (const float*)d_in[0];
    const float* xyz_s4 = (const float*)d_in[1];
    const float* feats  = (const float*)d_in[2];
    const float* sa1_W1 = (const float*)d_in[3];
    const float* sa1_W2 = (const float*)d_in[5];
    const float* sa2_W1 = (const float*)d_in[7];
    const float* sa2_W2 = (const float*)d_in[9];
    const float* fc_W1  = (const float*)d_in[11];
    const float* fc_b1  = (const float*)d_in[12];
    const float* fc_W2  = (const float*)d_in[13];
    const float* fc_b2  = (const float*)d_in[14];
    float* out = (float*)d_out;

    char* wsb = (char*)d_ws;
    float*  xyz4   = (float*)(wsb + 0);                  // 196608 B
    int*    idx    = (int*)(wsb + 196608);               // 2 MB   -> 2293760
    ushort* featTb = (ushort*)(wsb + 2293760);           // 4 MB   -> 6488064
    ushort* W1b1   = (ushort*)(wsb + 6488064);           // 64 KB  -> 6553600
    ushort* W1b2   = (ushort*)(wsb + 6553600);           // 64 KB  -> 6619136
    ushort* W2b1   = (ushort*)(wsb + 6619136);           // 64 KB  -> 6684672
    ushort* W2b2   = (ushort*)(wsb + 6684672);           // 64 KB  -> 6750208
    float*  statsA = (float*)(wsb + 6750208);            // 8 KB each x4 (contiguous)
    float*  statsB = (float*)(wsb + 6758400);
    float*  statsC = (float*)(wsb + 6766592);
    float*  statsD = (float*)(wsb + 6774784);
    ushort* ymax   = (ushort*)(wsb + 6782976);           // 4 MB  -> 10977280
    float*  zbuf   = (float*)(wsb + 10977280);           // 8 MB  -> 19365888

    // ---- setup ----
    k_prep<<<400, 256, 0, stream>>>(xyz_s4, xyz4, sa1_W1, sa2_W1, sa1_W2, sa2_W2,
                                    W1b1, W1b2, W2b1, W2b2, statsA);
    k_knn<<<B * (N4 / 8), 512, 0, stream>>>(xyz4, idx);
    dim3 gt(B, N4 / 32, CH / 32), bt(32, 8);
    k_feat_t<<<gt, bt, 0, stream>>>(feats, featTb);

    // ---- SA1 ----
    k_dense<<<NPTS / 64, 256, 0, stream>>>(featTb, xyz4, W1b1, zbuf, nullptr);
    k_gstats<<<NPTS / 32, 256, 0, stream>>>(zbuf, idx, xyz4, W1b1, statsA);
    k_fused2<<<ROWS_TOTAL / 256, 256, 0, stream>>>(zbuf, idx, xyz4, W1b1, W2b1,
                                                   statsA, statsB, ymax);
    // ---- SA2 (dense folds the SA1 norm+relu of ymax via statsB) ----
    k_dense<<<NPTS / 64, 256, 0, stream>>>(ymax, xyz4, W1b2, zbuf, statsB);
    k_gstats<<<NPTS / 32, 256, 0, stream>>>(zbuf, idx, xyz4, W1b2, statsC);
    k_fused2<<<ROWS_TOTAL / 256, 256, 0, stream>>>(zbuf, idx, xyz4, W1b2, W2b2,
                                                   statsC, statsD, ymax);

    // ---- FC head (folds SA2 norm+relu via statsD) + flow_lr ----
    k_fc<<<(B * N4) / 64, 256, 0, stream>>>(ymax, statsD, fc_W1, fc_b1, fc_W2, fc_b2, out);
    // ---- feature propagation -> flow ----
    k_fp<<<B * (N1 / 64), 256, 0, stream>>>(xyz_s1, xyz4, out);
}

// Round 13
// 379.938 us; speedup vs baseline: 9.2971x; 1.0416x over previous
//
#include <hip/hip_runtime.h>
#include <hip/hip_bf16.h>

#define B 8
#define N1 8192
#define N4 2048
#define CH 128
#define KNN 32
#define ROWS_PER_B (N4 * KNN)          // 65536 rows per batch in the [B,N,K] flattening
#define ROWS_TOTAL (B * ROWS_PER_B)    // 524288
#define NPTS (B * N4)                  // 16384 total points
#define FLOWLR_OFF (B * 3 * N1)        // flow_lr starts after flow in d_out

typedef unsigned int uint;
typedef unsigned short ushort;
typedef __attribute__((ext_vector_type(8))) short short8;
typedef __attribute__((ext_vector_type(4))) float f32x4;

union U16 { uint4 u; short8 s; };

__device__ __forceinline__ float bf2f(ushort u) {
    union { uint i; float f; } v; v.i = ((uint)u) << 16; return v.f;
}
__device__ __forceinline__ ushort f2b(float f) {
    __hip_bfloat16 h = __float2bfloat16(f);
    return *(ushort*)&h;
}

// ---------------- prep: fused W converters (bf16, permuted/padded) + xyz transpose + stats zero ----------------
__global__ void k_prep(const float* __restrict__ xyz_s4, float* __restrict__ xyz4,
                       const float* __restrict__ sa1_W1, const float* __restrict__ sa2_W1,
                       const float* __restrict__ sa1_W2, const float* __restrict__ sa2_W2,
                       ushort* __restrict__ W1b1, ushort* __restrict__ W1b2,
                       ushort* __restrict__ W2b1, ushort* __restrict__ W2b2,
                       float* __restrict__ stats)
{
    int i = blockIdx.x * 256 + threadIdx.x;
    if (i < 43008) {
        const float* W = (i < 21504) ? sa1_W1 : sa2_W1;
        ushort* o = (i < 21504) ? W1b1 : W1b2;
        int j = (i < 21504) ? i : i - 21504;
        int d = j / 168, c = j - d * 168;
        float v = 0.f;
        if (c < 128)      v = W[d * 131 + 3 + c];
        else if (c < 131) v = W[d * 131 + (c - 128)];
        o[j] = f2b(v);
    } else if (i < 77824) {
        const float* W = (i < 60416) ? sa1_W2 : sa2_W2;
        ushort* o = (i < 60416) ? W2b1 : W2b2;
        int j = (i < 60416) ? i - 43008 : i - 60416;
        int d = j / 136, c = j - d * 136;
        o[j] = (c < 128) ? f2b(W[d * 128 + c]) : (ushort)0;
    } else if (i < 94208) {
        int g = i - 77824;
        int b = g >> 11, n = g & (N4 - 1);
        xyz4[g * 3 + 0] = xyz_s4[(b * 3 + 0) * N4 + n];
        xyz4[g * 3 + 1] = xyz_s4[(b * 3 + 1) * N4 + n];
        xyz4[g * 3 + 2] = xyz_s4[(b * 3 + 2) * N4 + n];
    } else if (i < 102400) {
        stats[i - 94208] = 0.f;        // zeros statsA..statsD (contiguous 8192 floats)
    }
}

// ---------------- transpose feats [B,C,N4] fp32 -> featTb [B,N4,C] bf16 ----------------
__global__ void k_feat_t(const float* __restrict__ feats, ushort* __restrict__ featTb) {
    __shared__ float tile[32][33];
    int b = blockIdx.x, nb = blockIdx.y, cb = blockIdx.z;
    int tx = threadIdx.x, ty = threadIdx.y; // 32 x 8
    int n0 = nb * 32, c0 = cb * 32;
#pragma unroll
    for (int i = 0; i < 4; ++i) {
        int c = c0 + ty + 8 * i;
        tile[ty + 8 * i][tx] = feats[((size_t)b * CH + c) * N4 + n0 + tx];
    }
    __syncthreads();
#pragma unroll
    for (int i = 0; i < 4; ++i) {
        int n = n0 + ty + 8 * i;
        featTb[((size_t)b * N4 + n) * CH + c0 + tx] = f2b(tile[tx][ty + 8 * i]);
    }
}

// ---------------- KNN via exact threshold-select (safeguarded interpolation search) ----------------
__global__ __launch_bounds__(512) void k_knn(const float* __restrict__ xyz4, int* __restrict__ idxout) {
    __shared__ float pts[N4 * 3];
    int b = blockIdx.x >> 8;            // 256 blocks per batch
    int qbase = (blockIdx.x & 255) * 8;
    for (int i = threadIdx.x; i < N4 * 3; i += 512) pts[i] = xyz4[(size_t)b * N4 * 3 + i];
    __syncthreads();
    int wave = threadIdx.x >> 6, lane = threadIdx.x & 63;
    int qn = qbase + wave;
    float qx = pts[qn * 3 + 0], qy = pts[qn * 3 + 1], qz = pts[qn * 3 + 2];
    float d[32];
#pragma unroll
    for (int t = 0; t < 32; ++t) {
        int c = t * 64 + lane;
        float dx = pts[c * 3 + 0] - qx;
        float dy = pts[c * 3 + 1] - qy;
        float dz = pts[c * 3 + 2] - qz;
        d[t] = dx * dx + dy * dy + dz * dz;
    }
    // invariant: count(d < f(lo)) = cLT < 32 <= cHI = count(d < f(hi)); d>=0 so uint order == float order
    uint lo = 0u, hi = 0x7F800000u;
    int cLT = 0, cHI = N4;
    float T;
    int it = 1;                          // start with a bisection step (f(hi)=inf initially)
    for (;;) {
        if (hi - lo <= 1u) { T = __uint_as_float(lo); break; }
        if (cHI - cLT == 1) {
            // exactly one element in [f(lo), f(hi)) and cLT==31 -> that element is T
            float flo = __uint_as_float(lo), fhi = __uint_as_float(hi);
            float m = 3.4e38f;
#pragma unroll
            for (int t = 0; t < 32; ++t) {
                float dv = d[t];
                if (dv >= flo && dv < fhi) m = fminf(m, dv);
            }
#pragma unroll
            for (int s = 1; s < 64; s <<= 1) m = fminf(m, __shfl_xor(m, s, 64));
            T = m;
            break;
        }
        uint mid;
        if (it & 1) {
            mid = (lo + hi) >> 1;        // safeguard: bit-space bisection
        } else {
            float flo = __uint_as_float(lo), fhi = __uint_as_float(hi);
            float fm = flo + (fhi - flo) * ((float)(KNN - cLT) / (float)(cHI - cLT));
            mid = __float_as_uint(fm);
            if (mid <= lo) mid = lo + 1u;
            if (mid >= hi) mid = hi - 1u;
        }
        float fmid = __uint_as_float(mid);
        int c = 0;
#pragma unroll
        for (int t = 0; t < 32; ++t) c += __popcll(__ballot(d[t] < fmid));
        if (c < KNN) { lo = mid; cLT = c; } else { hi = mid; cHI = c; }
        ++it;
    }
    // compaction: d<T at ranks [0,cLT); ties d==T fill [cLT,32) in ascending (t,lane) = ascending index
    int outb = (b * N4 + qn) * KNN;
    unsigned long long lmlt = (1ull << lane) - 1ull;
    int baseLT = 0, baseEQ = cLT;
#pragma unroll
    for (int t = 0; t < 32; ++t) {
        bool lt = d[t] < T;
        unsigned long long m = __ballot(lt);
        if (lt) idxout[outb + baseLT + __popcll(m & lmlt)] = t * 64 + lane;
        baseLT += __popcll(m);
        bool eq = (d[t] == T);
        unsigned long long me = __ballot(eq);
        if (eq) {
            int rk = baseEQ + __popcll(me & lmlt);
            if (rk < KNN) idxout[outb + rk] = t * 64 + lane;
        }
        baseEQ += __popcll(me);
    }
}

// ---------------- dense z GEMM: z[p] = [in_p | xyz_p] @ W1^T (fp32 out) ----------------
// stats == nullptr: in_p = Fb row (plain bf16). stats != nullptr: in_p = normrelu(Fb row, stats)
__global__ __launch_bounds__(256) void k_dense(
    const ushort* __restrict__ Fb, const float* __restrict__ xyz4,
    const ushort* __restrict__ W1b, float* __restrict__ z,
    const float* __restrict__ stats)
{
    __shared__ __align__(16) ushort hs[64][168];
    __shared__ float smean[128], sinv[128];
    int t = threadIdx.x;
    int r = t >> 2, q = t & 3;
    int l = t & 63, w = t >> 6, lr = l & 15, lg = l >> 4;
    int g0 = blockIdx.x * 64;
    int b = g0 >> 11;                    // 2048 points per batch
    if (stats) {
        if (t < 128) {
            float s = stats[b * CH + t], q2 = stats[B * CH + b * CH + t];
            float mean = s * (1.f / ROWS_PER_B);
            float var = q2 * (1.f / ROWS_PER_B) - mean * mean;
            smean[t] = mean; sinv[t] = rsqrtf(var + 1e-5f);
        }
        __syncthreads();
    }
    {
        int p = g0 + r;
        const uint4* src = (const uint4*)(Fb + (size_t)p * CH) + q * 4;
        uint4* dst = (uint4*)&hs[r][q * 32];
        if (stats) {
#pragma unroll
            for (int m = 0; m < 4; ++m) {
                uint4 v = src[m];
                const uint* pv = (const uint*)&v;
                ushort o[8];
#pragma unroll
                for (int e = 0; e < 4; ++e) {
                    int c = q * 32 + m * 8 + e * 2;
                    o[e * 2]     = f2b(fmaxf((bf2f((ushort)(pv[e] & 0xffff)) - smean[c])     * sinv[c],     0.f));
                    o[e * 2 + 1] = f2b(fmaxf((bf2f((ushort)(pv[e] >> 16))    - smean[c + 1]) * sinv[c + 1], 0.f));
                }
                dst[m] = *(uint4*)o;
            }
        } else {
#pragma unroll
            for (int m = 0; m < 4; ++m) dst[m] = src[m];
        }
        uint4 zz = make_uint4(0, 0, 0, 0);
        *(uint4*)&hs[r][128 + q * 8] = zz;
        if (q == 0) {
            *(uint4*)&hs[r][160] = zz;
            hs[r][128] = f2b(xyz4[p * 3 + 0]);
            hs[r][129] = f2b(xyz4[p * 3 + 1]);
            hs[r][130] = f2b(xyz4[p * 3 + 2]);
        }
    }
    U16 bf[5][2];
#pragma unroll
    for (int kc = 0; kc < 5; ++kc)
#pragma unroll
        for (int jj = 0; jj < 2; ++jj)
            bf[kc][jj].u = *(const uint4*)&W1b[(size_t)(w * 32 + jj * 16 + lr) * 168 + kc * 32 + lg * 8];
    __syncthreads();
    f32x4 acc[4][2];
    f32x4 z4 = {0.f, 0.f, 0.f, 0.f};
#pragma unroll
    for (int i = 0; i < 4; ++i) { acc[i][0] = z4; acc[i][1] = z4; }
#pragma unroll
    for (int kc = 0; kc < 5; ++kc) {
        U16 a[4];
#pragma unroll
        for (int i = 0; i < 4; ++i) a[i].u = *(const uint4*)&hs[16 * i + lr][kc * 32 + lg * 8];
#pragma unroll
        for (int i = 0; i < 4; ++i)
#pragma unroll
            for (int jj = 0; jj < 2; ++jj)
                acc[i][jj] = __builtin_amdgcn_mfma_f32_16x16x32_bf16(a[i].s, bf[kc][jj].s, acc[i][jj], 0, 0, 0);
    }
#pragma unroll
    for (int jj = 0; jj < 2; ++jj)
#pragma unroll
        for (int i = 0; i < 4; ++i)
#pragma unroll
            for (int rg = 0; rg < 4; ++rg)
                z[(size_t)(g0 + 16 * i + lg * 4 + rg) * CH + w * 32 + jj * 16 + lr] = acc[i][jj][rg];
}

// ---------------- gather-stats: per-(b,c) sum/sumsq of y1 = z[j]-u[n]; u computed on the fly ----------------
__global__ __launch_bounds__(256) void k_gstats(
    const float* __restrict__ z, const int* __restrict__ idx,
    const float* __restrict__ xyz4, const ushort* __restrict__ W1b,
    float* __restrict__ stats)
{
    __shared__ int idxs[32 * KNN];
    __shared__ float sacc[128], sqacc[128];
    __shared__ ushort w1x[384];          // [c][a], c*3+a
    int t = threadIdx.x;
    int gpb = blockIdx.x * 32;
    int b = gpb >> 11;
    for (int ii = t; ii < 32 * KNN; ii += 256) idxs[ii] = idx[(size_t)gpb * KNN + ii];
    if (t < 128) {
        sacc[t] = 0.f; sqacc[t] = 0.f;
        w1x[t * 3 + 0] = W1b[t * 168 + 128];
        w1x[t * 3 + 1] = W1b[t * 168 + 129];
        w1x[t * 3 + 2] = W1b[t * 168 + 130];
    }
    __syncthreads();
    int li = t >> 3, cq = (t & 7) * 16;
    int gp = gpb + li;
    float s[16], qa[16];
#pragma unroll
    for (int m = 0; m < 16; ++m) { s[m] = 0.f; qa[m] = 0.f; }
    int zb = b * N4;
#pragma unroll 4
    for (int k = 0; k < KNN; ++k) {
        int j = idxs[li * KNN + k];
        const float4* zr = (const float4*)(z + (size_t)(zb + j) * CH + cq);
#pragma unroll
        for (int m = 0; m < 4; ++m) {
            float4 v = zr[m];
#pragma unroll
            for (int e = 0; e < 4; ++e) {
                float vv = ((const float*)&v)[e];
                s[m * 4 + e] += vv; qa[m * 4 + e] += vv * vv;
            }
        }
    }
    // u[gp][cq..cq+15] on the fly (bf16-rounded xyz, bf16 W1x -> fp32)
    float x = bf2f(f2b(xyz4[gp * 3 + 0]));
    float y = bf2f(f2b(xyz4[gp * 3 + 1]));
    float zc = bf2f(f2b(xyz4[gp * 3 + 2]));
#pragma unroll
    for (int m = 0; m < 4; ++m) {
#pragma unroll
        for (int e = 0; e < 4; ++e) {
            int c = cq + m * 4 + e;
            float uu = x * bf2f(w1x[c * 3]) + y * bf2f(w1x[c * 3 + 1]) + zc * bf2f(w1x[c * 3 + 2]);
            float ss = s[m * 4 + e], qq = qa[m * 4 + e];
            atomicAdd(&sacc[c], ss - 32.f * uu);
            atomicAdd(&sqacc[c], qq - 2.f * uu * ss + 32.f * uu * uu);
        }
    }
    __syncthreads();
    if (t < 128) {
        atomicAdd(&stats[b * CH + t], sacc[t]);
        atomicAdd(&stats[B * CH + b * CH + t], sqacc[t]);
    }
}

// ---------------- fused pass: 256 rows/block, dbuf LDS; u computed on the fly ----------------
__global__ __launch_bounds__(256) void k_fused2(
    const float* __restrict__ z, const int* __restrict__ idx,
    const float* __restrict__ xyz4, const ushort* __restrict__ W1b,
    const ushort* __restrict__ W2b, const float* __restrict__ stats1,
    float* __restrict__ stats2, ushort* __restrict__ ymax)
{
    __shared__ __align__(16) ushort hs[2][64][136];
    __shared__ float smean[128], sinv[128];
    __shared__ float us[8][128];
    __shared__ ushort w1x[384];
    int t = threadIdx.x;
    int g0 = blockIdx.x * 256;          // 256 rows = 8 points
    int b = g0 >> 16;
    int gp0 = g0 >> 5;
    int l = t & 63, w = t >> 6, lr = l & 15, lg = l >> 4;
    U16 b2f[4][2];
#pragma unroll
    for (int kc = 0; kc < 4; ++kc)
#pragma unroll
        for (int jj = 0; jj < 2; ++jj)
            b2f[kc][jj].u = *(const uint4*)&W2b[(size_t)(w * 32 + jj * 16 + lr) * 136 + kc * 32 + lg * 8];
    if (t < 128) {
        float s = stats1[b * CH + t], q2 = stats1[B * CH + b * CH + t];
        float mean = s * (1.f / ROWS_PER_B);
        float var = q2 * (1.f / ROWS_PER_B) - mean * mean;
        smean[t] = mean; sinv[t] = rsqrtf(var + 1e-5f);
        w1x[t * 3 + 0] = W1b[t * 168 + 128];
        w1x[t * 3 + 1] = W1b[t * 168 + 129];
        w1x[t * 3 + 2] = W1b[t * 168 + 130];
    }
    __syncthreads();
    {   // us: 8 points x 128 cols, 4 cols/thread, same formula as k_gstats
        int p = t >> 5, i = t & 31;
        float x = bf2f(f2b(xyz4[(gp0 + p) * 3 + 0]));
        float y = bf2f(f2b(xyz4[(gp0 + p) * 3 + 1]));
        float zc = bf2f(f2b(xyz4[(gp0 + p) * 3 + 2]));
#pragma unroll
        for (int jj = 0; jj < 4; ++jj) {
            int c = i * 4 + jj;
            us[p][c] = x * bf2f(w1x[c * 3]) + y * bf2f(w1x[c * 3 + 1]) + zc * bf2f(w1x[c * 3 + 2]);
        }
    }
    int r = t >> 2, q = t & 3;
    // prologue: z loads for sub-tile 0
    float4 zv[8];
    {
        int j = idx[g0 + r];
        const float4* zr = (const float4*)(z + (size_t)(b * N4 + j) * CH + q * 32);
#pragma unroll
        for (int m = 0; m < 8; ++m) zv[m] = zr[m];
    }
    float sA[2] = {0.f, 0.f}, qA[2] = {0.f, 0.f};
    f32x4 z4 = {0.f, 0.f, 0.f, 0.f};
    __syncthreads();   // smean/sinv/us ready
    for (int st = 0; st < 4; ++st) {
        ushort (*buf)[136] = hs[st & 1];
        {
            int urow = (st * 64 + r) >> 5;
#pragma unroll
            for (int mm = 0; mm < 4; ++mm) {
                ushort o[8];
#pragma unroll
                for (int h = 0; h < 2; ++h) {
                    float4 v = zv[mm * 2 + h];
#pragma unroll
                    for (int e = 0; e < 4; ++e) {
                        int c = q * 32 + mm * 8 + h * 4 + e;
                        float val = (((const float*)&v)[e] - us[urow][c] - smean[c]) * sinv[c];
                        o[h * 4 + e] = f2b(fmaxf(val, 0.f));
                    }
                }
                *(uint4*)&buf[r][q * 32 + mm * 8] = *(uint4*)o;
            }
            if (q == 0) { uint4 zz = make_uint4(0, 0, 0, 0); *(uint4*)&buf[r][128] = zz; }
        }
        __syncthreads();
        if (st < 3) {
            int j = idx[g0 + (st + 1) * 64 + r];
            const float4* zr = (const float4*)(z + (size_t)(b * N4 + j) * CH + q * 32);
#pragma unroll
            for (int m = 0; m < 8; ++m) zv[m] = zr[m];
        }
        f32x4 acc[4][2];
#pragma unroll
        for (int i = 0; i < 4; ++i) { acc[i][0] = z4; acc[i][1] = z4; }
#pragma unroll
        for (int kc = 0; kc < 4; ++kc) {
            U16 a[4];
#pragma unroll
            for (int i = 0; i < 4; ++i) a[i].u = *(const uint4*)&buf[16 * i + lr][kc * 32 + lg * 8];
#pragma unroll
            for (int i = 0; i < 4; ++i)
#pragma unroll
                for (int jj = 0; jj < 2; ++jj)
                    acc[i][jj] = __builtin_amdgcn_mfma_f32_16x16x32_bf16(a[i].s, b2f[kc][jj].s, acc[i][jj], 0, 0, 0);
        }
        int gpA = gp0 + st * 2;
#pragma unroll
        for (int jj = 0; jj < 2; ++jj) {
            int c = w * 32 + jj * 16 + lr;
            float m0 = -3.4e38f, m1 = -3.4e38f;
#pragma unroll
            for (int i = 0; i < 4; ++i)
#pragma unroll
                for (int rg = 0; rg < 4; ++rg) {
                    float v = acc[i][jj][rg];
                    sA[jj] += v; qA[jj] += v * v;
                    if (i < 2) m0 = fmaxf(m0, v); else m1 = fmaxf(m1, v);
                }
            m0 = fmaxf(m0, __shfl_xor(m0, 16, 64)); m0 = fmaxf(m0, __shfl_xor(m0, 32, 64));
            m1 = fmaxf(m1, __shfl_xor(m1, 16, 64)); m1 = fmaxf(m1, __shfl_xor(m1, 32, 64));
            if (lg == 0) {
                ymax[(size_t)gpA * CH + c] = f2b(m0);
                ymax[(size_t)(gpA + 1) * CH + c] = f2b(m1);
            }
        }
    }
#pragma unroll
    for (int jj = 0; jj < 2; ++jj) {
        int c = w * 32 + jj * 16 + lr;
        float ss = sA[jj], qq = qA[jj];
        ss += __shfl_xor(ss, 16, 64); ss += __shfl_xor(ss, 32, 64);
        qq += __shfl_xor(qq, 16, 64); qq += __shfl_xor(qq, 32, 64);
        if (lg == 0) {
            atomicAdd(&stats2[b * CH + c], ss);
            atomicAdd(&stats2[B * CH + b * CH + c], qq);
        }
    }
}

// ---------------- FC head: relu(normrelu(ymax)@W1^T+b1) @ W2^T + b2 -> flow_lr [B,3,N4] ----------------
__global__ __launch_bounds__(256, 1) void k_fc(
    const ushort* __restrict__ Ymax, const float* __restrict__ stats,
    const float* __restrict__ W1, const float* __restrict__ b1,
    const float* __restrict__ W2, const float* __restrict__ b2,
    float* __restrict__ out)
{
    __shared__ float hs[64][132];
    __shared__ float ws[128][132];
    __shared__ float smean[128], sinv[128];
    int t = threadIdx.x;
    int g0 = blockIdx.x * 64;
    int b = g0 >> 11;
    if (t < 128) {
        float s = stats[b * CH + t], q2 = stats[B * CH + b * CH + t];
        float mean = s * (1.f / ROWS_PER_B);
        float var = q2 * (1.f / ROWS_PER_B) - mean * mean;
        smean[t] = mean; sinv[t] = rsqrtf(var + 1e-5f);
    }
    for (int i = t; i < 128 * 132; i += 256) {
        int dd = i / 132, c = i - dd * 132;
        ws[dd][c] = (c < 128) ? W1[dd * 128 + c] : 0.f;
    }
    __syncthreads();   // smean/sinv ready
    int r = t >> 2, q = t & 3;
    {
        const uint4* Xrow = (const uint4*)(Ymax + (size_t)(g0 + r) * CH + q * 32);
#pragma unroll
        for (int m = 0; m < 4; ++m) {
            uint4 v = Xrow[m];
            const uint* pv = (const uint*)&v;
            int c0 = q * 32 + m * 8;
#pragma unroll
            for (int e = 0; e < 4; ++e) {
                int c = c0 + 2 * e;
                hs[r][c]     = fmaxf((bf2f((ushort)(pv[e] & 0xffff)) - smean[c])     * sinv[c],     0.f);
                hs[r][c + 1] = fmaxf((bf2f((ushort)(pv[e] >> 16))    - smean[c + 1]) * sinv[c + 1], 0.f);
            }
        }
        if (q == 0) *(float4*)&hs[r][128] = make_float4(0.f, 0.f, 0.f, 0.f);
    }
    __syncthreads();
    int tx = t & 15, ty = t >> 4;
    float acc[4][8];
#pragma unroll
    for (int i = 0; i < 4; ++i)
#pragma unroll
        for (int jj = 0; jj < 8; ++jj) acc[i][jj] = 0.f;
    for (int kb = 0; kb < 33; ++kb) {
        float4 a[4]; float4 w[8];
#pragma unroll
        for (int i = 0; i < 4; ++i) a[i] = *(float4*)&hs[ty * 4 + i][kb * 4];
#pragma unroll
        for (int jj = 0; jj < 8; ++jj) w[jj] = *(float4*)&ws[tx + 16 * jj][kb * 4];
#pragma unroll
        for (int i = 0; i < 4; ++i)
#pragma unroll
            for (int jj = 0; jj < 8; ++jj)
                acc[i][jj] += a[i].x * w[jj].x + a[i].y * w[jj].y
                            + a[i].z * w[jj].z + a[i].w * w[jj].w;
    }
    __syncthreads();                     // done reading hs
#pragma unroll
    for (int jj = 0; jj < 8; ++jj) {
        int c = tx + 16 * jj;
        float bias = b1[c];
#pragma unroll
        for (int i = 0; i < 4; ++i)
            hs[ty * 4 + i][c] = fmaxf(acc[i][jj] + bias, 0.f);
    }
    __syncthreads();
    if (t < 192) {
        int rr = t / 3, o = t - rr * 3;
        float sum = b2[o];
        for (int c = 0; c < 128; ++c) sum += hs[rr][c] * W2[o * 128 + c];
        int g = g0 + rr;
        int bb = g >> 11, n = g & (N4 - 1);
        out[FLOWLR_OFF + ((size_t)bb * 3 + o) * N4 + n] = sum;
    }
}

// ---------------- feature propagation: 3-NN inverse-sqdist interp onto xyz1 ----------------
// Expanded-distance key: key = |p|^2 - 2 p.q  (3 FMA/candidate vs 6 ops); |q|^2 is a
// query-constant shift so ordering is preserved. Weights use d = max(key + |q|^2, 0)
// (clamp guards fp32 cancellation for ultra-close pairs; nearest then dominates, matching ref).
// GRID: B * (N1/64) = 1024 blocks (64 queries per block, 4 threads each).
__global__ __launch_bounds__(256) void k_fp(
    const float* __restrict__ xyz_s1, const float* __restrict__ xyz4,
    float* __restrict__ out)
{
    __shared__ float xs[4 * 528], ys[4 * 528], zs[4 * 528], ss[4 * 528];
    int b = blockIdx.x >> 7;             // 128 blocks per batch
    int q0 = (blockIdx.x & 127) * 64;
    int t = threadIdx.x;
    for (int i = t; i < N4; i += 256) {
        int p = (i >> 9) * 528 + (i & 511);
        const float* s = xyz4 + (size_t)b * N4 * 3 + (size_t)i * 3;
        float x = s[0], y = s[1], z = s[2];
        xs[p] = x; ys[p] = y; zs[p] = z;
        ss[p] = x * x + y * y + z * z;
    }
    __syncthreads();
    int q = q0 + (t >> 2), c = t & 3;
    float qx = xyz_s1[((size_t)b * 3 + 0) * N1 + q];
    float qy = xyz_s1[((size_t)b * 3 + 1) * N1 + q];
    float qz = xyz_s1[((size_t)b * 3 + 2) * N1 + q];
    float nqx = -2.f * qx, nqy = -2.f * qy, nqz = -2.f * qz;
    float sq = qx * qx + qy * qy + qz * qz;
    float d0 = 3.4e38f, d1 = 3.4e38f, d2 = 3.4e38f;   // hold KEYS (= d^2 - |q|^2)
    int i0 = 0, i1 = 0, i2 = 0;
    int base = c * 528, nb = c * 512;
    for (int ii = 0; ii < 512; ii += 4) {
        float4 x4 = *(float4*)&xs[base + ii];
        float4 y4 = *(float4*)&ys[base + ii];
        float4 z4 = *(float4*)&zs[base + ii];
        float4 s4 = *(float4*)&ss[base + ii];
#pragma unroll
        for (int j = 0; j < 4; ++j) {
            float dd = fmaf(((const float*)&x4)[j], nqx,
                       fmaf(((const float*)&y4)[j], nqy,
                       fmaf(((const float*)&z4)[j], nqz, ((const float*)&s4)[j])));
            if (dd < d2) {               // strict < is tie-correct for ascending index scan
                int n = nb + ii + j;
                if (dd < d0)      { d2 = d1; i2 = i1; d1 = d0; i1 = i0; d0 = dd; i0 = n; }
                else if (dd < d1) { d2 = d1; i2 = i1; d1 = dd; i1 = n; }
                else              { d2 = dd; i2 = n; }
            }
        }
    }
    // merge the 4 chunk-local top-3 lists (lexicographic (key, idx) insertion)
#pragma unroll
    for (int m = 1; m <= 2; m <<= 1) {
        float e0 = __shfl_xor(d0, m, 64), e1 = __shfl_xor(d1, m, 64), e2 = __shfl_xor(d2, m, 64);
        int   j0 = __shfl_xor(i0, m, 64), j1 = __shfl_xor(i1, m, 64), j2 = __shfl_xor(i2, m, 64);
        float ed[3] = { e0, e1, e2 }; int ej[3] = { j0, j1, j2 };
#pragma unroll
        for (int s = 0; s < 3; ++s) {
            float dd = ed[s]; int jn = ej[s];
            bool lt2 = dd < d2 || (dd == d2 && jn < i2);
            if (lt2) {
                bool lt0 = dd < d0 || (dd == d0 && jn < i0);
                bool lt1 = dd < d1 || (dd == d1 && jn < i1);
                if (lt0)      { d2 = d1; i2 = i1; d1 = d0; i1 = i0; d0 = dd; i0 = jn; }
                else if (lt1) { d2 = d1; i2 = i1; d1 = dd; i1 = jn; }
                else          { d2 = dd; i2 = jn; }
            }
        }
    }
    float dd0 = fmaxf(d0 + sq, 0.f), dd1 = fmaxf(d1 + sq, 0.f), dd2 = fmaxf(d2 + sq, 0.f);
    float w0 = 1.f / (dd0 + 1e-8f), w1 = 1.f / (dd1 + 1e-8f), w2 = 1.f / (dd2 + 1e-8f);
    float inv = 1.f / (w0 + w1 + w2);
    const float* flr = out + FLOWLR_OFF + (size_t)b * 3 * N4;
    if (c < 3) {
        float v = (w0 * flr[c * N4 + i0] + w1 * flr[c * N4 + i1] + w2 * flr[c * N4 + i2]) * inv;
        out[((size_t)b * 3 + c) * N1 + q] = v;
    }
}

extern "C" void kernel_launch(void* const* d_in, const int* in_sizes, int n_in,
                              void* d_out, int out_size, void* d_ws, size_t ws_size,
                              hipStream_t stream) {
    const float* xyz_s1 = (const float*)d_in[0];
    const float* xyz_s4 = (const float*)d_in[1];
    const float* feats  = (const float*)d_in[2];
    const float* sa1_W1 = (const float*)d_in[3];
    const float* sa1_W2 = (const float*)d_in[5];
    const float* sa2_W1 = (const float*)d_in[7];
    const float* sa2_W2 = (const float*)d_in[9];
    const float* fc_W1  = (const float*)d_in[11];
    const float* fc_b1  = (const float*)d_in[12];
    const float* fc_W2  = (const float*)d_in[13];
    const float* fc_b2  = (const float*)d_in[14];
    float* out = (float*)d_out;

    char* wsb = (char*)d_ws;
    float*  xyz4   = (float*)(wsb + 0);                  // 196608 B
    int*    idx    = (int*)(wsb + 196608);               // 2 MB   -> 2293760
    ushort* featTb = (ushort*)(wsb + 2293760);           // 4 MB   -> 6488064
    ushort* W1b1   = (ushort*)(wsb + 6488064);           // 64 KB  -> 6553600
    ushort* W1b2   = (ushort*)(wsb + 6553600);           // 64 KB  -> 6619136
    ushort* W2b1   = (ushort*)(wsb + 6619136);           // 64 KB  -> 6684672
    ushort* W2b2   = (ushort*)(wsb + 6684672);           // 64 KB  -> 6750208
    float*  statsA = (float*)(wsb + 6750208);            // 8 KB each x4 (contiguous)
    float*  statsB = (float*)(wsb + 6758400);
    float*  statsC = (float*)(wsb + 6766592);
    float*  statsD = (float*)(wsb + 6774784);
    ushort* ymax   = (ushort*)(wsb + 6782976);           // 4 MB  -> 10977280
    float*  zbuf   = (float*)(wsb + 10977280);           // 8 MB  -> 19365888

    // ---- setup ----
    k_prep<<<400, 256, 0, stream>>>(xyz_s4, xyz4, sa1_W1, sa2_W1, sa1_W2, sa2_W2,
                                    W1b1, W1b2, W2b1, W2b2, statsA);
    k_knn<<<B * (N4 / 8), 512, 0, stream>>>(xyz4, idx);
    dim3 gt(B, N4 / 32, CH / 32), bt(32, 8);
    k_feat_t<<<gt, bt, 0, stream>>>(feats, featTb);

    // ---- SA1 ----
    k_dense<<<NPTS / 64, 256, 0, stream>>>(featTb, xyz4, W1b1, zbuf, nullptr);
    k_gstats<<<NPTS / 32, 256, 0, stream>>>(zbuf, idx, xyz4, W1b1, statsA);
    k_fused2<<<ROWS_TOTAL / 256, 256, 0, stream>>>(zbuf, idx, xyz4, W1b1, W2b1,
                                                   statsA, statsB, ymax);
    // ---- SA2 (dense folds the SA1 norm+relu of ymax via statsB) ----
    k_dense<<<NPTS / 64, 256, 0, stream>>>(ymax, xyz4, W1b2, zbuf, statsB);
    k_gstats<<<NPTS / 32, 256, 0, stream>>>(zbuf, idx, xyz4, W1b2, statsC);
    k_fused2<<<ROWS_TOTAL / 256, 256, 0, stream>>>(zbuf, idx, xyz4, W1b2, W2b2,
                                                   statsC, statsD, ymax);

    // ---- FC head (folds SA2 norm+relu via statsD) + flow_lr ----
    k_fc<<<(B * N4) / 64, 256, 0, stream>>>(ymax, statsD, fc_W1, fc_b1, fc_W2, fc_b2, out);
    // ---- feature propagation -> flow ----
    k_fp<<<B * (N1 / 64), 256, 0, stream>>>(xyz_s1, xyz4, out);
}

// Round 14
// 363.675 us; speedup vs baseline: 9.7129x; 1.0447x over previous
//
#include <hip/hip_runtime.h>
#include <hip/hip_bf16.h>

#define B 8
#define N1 8192
#define N4 2048
#define CH 128
#define KNN 32
#define ROWS_PER_B (N4 * KNN)          // 65536 rows per batch in the [B,N,K] flattening
#define ROWS_TOTAL (B * ROWS_PER_B)    // 524288
#define NPTS (B * N4)                  // 16384 total points
#define FLOWLR_OFF (B * 3 * N1)        // flow_lr starts after flow in d_out

typedef unsigned int uint;
typedef unsigned short ushort;
typedef __attribute__((ext_vector_type(8))) short short8;
typedef __attribute__((ext_vector_type(4))) float f32x4;

union U16 { uint4 u; short8 s; };

__device__ __forceinline__ float bf2f(ushort u) {
    union { uint i; float f; } v; v.i = ((uint)u) << 16; return v.f;
}
__device__ __forceinline__ ushort f2b(float f) {
    __hip_bfloat16 h = __float2bfloat16(f);
    return *(ushort*)&h;
}

// ---------------- prep: fused W converters (bf16, permuted/padded) + xyz transpose + stats zero ----------------
__global__ void k_prep(const float* __restrict__ xyz_s4, float* __restrict__ xyz4,
                       const float* __restrict__ sa1_W1, const float* __restrict__ sa2_W1,
                       const float* __restrict__ sa1_W2, const float* __restrict__ sa2_W2,
                       ushort* __restrict__ W1b1, ushort* __restrict__ W1b2,
                       ushort* __restrict__ W2b1, ushort* __restrict__ W2b2,
                       float* __restrict__ stats)
{
    int i = blockIdx.x * 256 + threadIdx.x;
    if (i < 43008) {
        const float* W = (i < 21504) ? sa1_W1 : sa2_W1;
        ushort* o = (i < 21504) ? W1b1 : W1b2;
        int j = (i < 21504) ? i : i - 21504;
        int d = j / 168, c = j - d * 168;
        float v = 0.f;
        if (c < 128)      v = W[d * 131 + 3 + c];
        else if (c < 131) v = W[d * 131 + (c - 128)];
        o[j] = f2b(v);
    } else if (i < 77824) {
        const float* W = (i < 60416) ? sa1_W2 : sa2_W2;
        ushort* o = (i < 60416) ? W2b1 : W2b2;
        int j = (i < 60416) ? i - 43008 : i - 60416;
        int d = j / 136, c = j - d * 136;
        o[j] = (c < 128) ? f2b(W[d * 128 + c]) : (ushort)0;
    } else if (i < 94208) {
        int g = i - 77824;
        int b = g >> 11, n = g & (N4 - 1);
        xyz4[g * 3 + 0] = xyz_s4[(b * 3 + 0) * N4 + n];
        xyz4[g * 3 + 1] = xyz_s4[(b * 3 + 1) * N4 + n];
        xyz4[g * 3 + 2] = xyz_s4[(b * 3 + 2) * N4 + n];
    } else if (i < 102400) {
        stats[i - 94208] = 0.f;        // zeros statsA..statsD (contiguous 8192 floats)
    }
}

// ---------------- transpose feats [B,C,N4] fp32 -> featTb [B,N4,C] bf16 ----------------
__global__ void k_feat_t(const float* __restrict__ feats, ushort* __restrict__ featTb) {
    __shared__ float tile[32][33];
    int b = blockIdx.x, nb = blockIdx.y, cb = blockIdx.z;
    int tx = threadIdx.x, ty = threadIdx.y; // 32 x 8
    int n0 = nb * 32, c0 = cb * 32;
#pragma unroll
    for (int i = 0; i < 4; ++i) {
        int c = c0 + ty + 8 * i;
        tile[ty + 8 * i][tx] = feats[((size_t)b * CH + c) * N4 + n0 + tx];
    }
    __syncthreads();
#pragma unroll
    for (int i = 0; i < 4; ++i) {
        int n = n0 + ty + 8 * i;
        featTb[((size_t)b * N4 + n) * CH + c0 + tx] = f2b(tile[tx][ty + 8 * i]);
    }
}

// ---------------- KNN via exact threshold-select (interpolation search + order-statistic gap exit) ----------------
// Only the SET of 32 indices matters downstream. If any probe fmid satisfies
// count(d < fmid) == 32, then {d < fmid} IS the exact top-32 set (probe landed in the
// [d_(32), d_(33)) gap) -> immediate exit, tie-free compaction (halves compaction SALU).
// Otherwise fall through to bracket-collapse exits with full tie handling (== lax.top_k set).
// Interpolation 3-of-4 iters (bisection every 4th as safeguard); clamp guarantees >=1 ulp progress.
__global__ __launch_bounds__(512) void k_knn(const float* __restrict__ xyz4, int* __restrict__ idxout) {
    __shared__ float pts[N4 * 3];
    int b = blockIdx.x >> 8;            // 256 blocks per batch
    int qbase = (blockIdx.x & 255) * 8;
    for (int i = threadIdx.x; i < N4 * 3; i += 512) pts[i] = xyz4[(size_t)b * N4 * 3 + i];
    __syncthreads();
    int wave = threadIdx.x >> 6, lane = threadIdx.x & 63;
    int qn = qbase + wave;
    float qx = pts[qn * 3 + 0], qy = pts[qn * 3 + 1], qz = pts[qn * 3 + 2];
    float d[32];
#pragma unroll
    for (int t = 0; t < 32; ++t) {
        int c = t * 64 + lane;
        float dx = pts[c * 3 + 0] - qx;
        float dy = pts[c * 3 + 1] - qy;
        float dz = pts[c * 3 + 2] - qz;
        d[t] = dx * dx + dy * dy + dz * dz;
    }
    // invariant: count(d < f(lo)) = cLT < 32 <= cHI = count(d < f(hi)); d>=0 so uint order == float order
    uint lo = 0u, hi = 0x7F800000u;
    int cLT = 0, cHI = N4;
    float T;
    bool strict = false;                 // true: set = {d < T} exactly (no ties needed)
    int it = 0;
    for (;;) {
        if (hi - lo <= 1u) { T = __uint_as_float(lo); break; }
        if (cHI - cLT == 1) {
            // exactly one element in [f(lo), f(hi)) and cLT==31 -> that element is T
            float flo = __uint_as_float(lo), fhi = __uint_as_float(hi);
            float m = 3.4e38f;
#pragma unroll
            for (int t = 0; t < 32; ++t) {
                float dv = d[t];
                if (dv >= flo && dv < fhi) m = fminf(m, dv);
            }
#pragma unroll
            for (int s = 1; s < 64; s <<= 1) m = fminf(m, __shfl_xor(m, s, 64));
            T = m;
            break;
        }
        uint mid;
        if ((it & 3) == 0) {
            mid = (lo + hi) >> 1;        // safeguard: bit-space bisection (also the first probe)
        } else {
            float flo = __uint_as_float(lo), fhi = __uint_as_float(hi);
            float fm = flo + (fhi - flo) * ((float)(KNN - cLT) / (float)(cHI - cLT));
            mid = __float_as_uint(fm);
            if (mid <= lo) mid = lo + 1u;
            if (mid >= hi) mid = hi - 1u;
        }
        float fmid = __uint_as_float(mid);
        int c = 0;
#pragma unroll
        for (int t = 0; t < 32; ++t) c += __popcll(__ballot(d[t] < fmid));
        if (c == KNN) { T = fmid; strict = true; break; }   // gap hit: exact set, tie-free
        if (c < KNN) { lo = mid; cLT = c; } else { hi = mid; cHI = c; }
        ++it;
    }
    int outb = (b * N4 + qn) * KNN;
    unsigned long long lmlt = (1ull << lane) - 1ull;
    if (strict) {
        // tie-free compaction: exactly 32 elements satisfy d < T
        int baseLT = 0;
#pragma unroll
        for (int t = 0; t < 32; ++t) {
            bool lt = d[t] < T;
            unsigned long long m = __ballot(lt);
            if (lt) idxout[outb + baseLT + __popcll(m & lmlt)] = t * 64 + lane;
            baseLT += __popcll(m);
        }
    } else {
        // general: d<T at ranks [0,cLT); ties d==T fill [cLT,32) in ascending (t,lane) = ascending index
        int baseLT = 0, baseEQ = cLT;
#pragma unroll
        for (int t = 0; t < 32; ++t) {
            bool lt = d[t] < T;
            unsigned long long m = __ballot(lt);
            if (lt) idxout[outb + baseLT + __popcll(m & lmlt)] = t * 64 + lane;
            baseLT += __popcll(m);
            bool eq = (d[t] == T);
            unsigned long long me = __ballot(eq);
            if (eq) {
                int rk = baseEQ + __popcll(me & lmlt);
                if (rk < KNN) idxout[outb + rk] = t * 64 + lane;
            }
            baseEQ += __popcll(me);
        }
    }
}

// ---------------- dense z GEMM: z[p] = [in_p | xyz_p] @ W1^T (fp32 out) ----------------
// stats == nullptr: in_p = Fb row (plain bf16). stats != nullptr: in_p = normrelu(Fb row, stats)
__global__ __launch_bounds__(256) void k_dense(
    const ushort* __restrict__ Fb, const float* __restrict__ xyz4,
    const ushort* __restrict__ W1b, float* __restrict__ z,
    const float* __restrict__ stats)
{
    __shared__ __align__(16) ushort hs[64][168];
    __shared__ float smean[128], sinv[128];
    int t = threadIdx.x;
    int r = t >> 2, q = t & 3;
    int l = t & 63, w = t >> 6, lr = l & 15, lg = l >> 4;
    int g0 = blockIdx.x * 64;
    int b = g0 >> 11;                    // 2048 points per batch
    if (stats) {
        if (t < 128) {
            float s = stats[b * CH + t], q2 = stats[B * CH + b * CH + t];
            float mean = s * (1.f / ROWS_PER_B);
            float var = q2 * (1.f / ROWS_PER_B) - mean * mean;
            smean[t] = mean; sinv[t] = rsqrtf(var + 1e-5f);
        }
        __syncthreads();
    }
    {
        int p = g0 + r;
        const uint4* src = (const uint4*)(Fb + (size_t)p * CH) + q * 4;
        uint4* dst = (uint4*)&hs[r][q * 32];
        if (stats) {
#pragma unroll
            for (int m = 0; m < 4; ++m) {
                uint4 v = src[m];
                const uint* pv = (const uint*)&v;
                ushort o[8];
#pragma unroll
                for (int e = 0; e < 4; ++e) {
                    int c = q * 32 + m * 8 + e * 2;
                    o[e * 2]     = f2b(fmaxf((bf2f((ushort)(pv[e] & 0xffff)) - smean[c])     * sinv[c],     0.f));
                    o[e * 2 + 1] = f2b(fmaxf((bf2f((ushort)(pv[e] >> 16))    - smean[c + 1]) * sinv[c + 1], 0.f));
                }
                dst[m] = *(uint4*)o;
            }
        } else {
#pragma unroll
            for (int m = 0; m < 4; ++m) dst[m] = src[m];
        }
        uint4 zz = make_uint4(0, 0, 0, 0);
        *(uint4*)&hs[r][128 + q * 8] = zz;
        if (q == 0) {
            *(uint4*)&hs[r][160] = zz;
            hs[r][128] = f2b(xyz4[p * 3 + 0]);
            hs[r][129] = f2b(xyz4[p * 3 + 1]);
            hs[r][130] = f2b(xyz4[p * 3 + 2]);
        }
    }
    U16 bf[5][2];
#pragma unroll
    for (int kc = 0; kc < 5; ++kc)
#pragma unroll
        for (int jj = 0; jj < 2; ++jj)
            bf[kc][jj].u = *(const uint4*)&W1b[(size_t)(w * 32 + jj * 16 + lr) * 168 + kc * 32 + lg * 8];
    __syncthreads();
    f32x4 acc[4][2];
    f32x4 z4 = {0.f, 0.f, 0.f, 0.f};
#pragma unroll
    for (int i = 0; i < 4; ++i) { acc[i][0] = z4; acc[i][1] = z4; }
#pragma unroll
    for (int kc = 0; kc < 5; ++kc) {
        U16 a[4];
#pragma unroll
        for (int i = 0; i < 4; ++i) a[i].u = *(const uint4*)&hs[16 * i + lr][kc * 32 + lg * 8];
#pragma unroll
        for (int i = 0; i < 4; ++i)
#pragma unroll
            for (int jj = 0; jj < 2; ++jj)
                acc[i][jj] = __builtin_amdgcn_mfma_f32_16x16x32_bf16(a[i].s, bf[kc][jj].s, acc[i][jj], 0, 0, 0);
    }
#pragma unroll
    for (int jj = 0; jj < 2; ++jj)
#pragma unroll
        for (int i = 0; i < 4; ++i)
#pragma unroll
            for (int rg = 0; rg < 4; ++rg)
                z[(size_t)(g0 + 16 * i + lg * 4 + rg) * CH + w * 32 + jj * 16 + lr] = acc[i][jj][rg];
}

// ---------------- gather-stats: per-(b,c) sum/sumsq of y1 = z[j]-u[n]; u computed on the fly ----------------
__global__ __launch_bounds__(256) void k_gstats(
    const float* __restrict__ z, const int* __restrict__ idx,
    const float* __restrict__ xyz4, const ushort* __restrict__ W1b,
    float* __restrict__ stats)
{
    __shared__ int idxs[32 * KNN];
    __shared__ float sacc[128], sqacc[128];
    __shared__ ushort w1x[384];          // [c][a], c*3+a
    int t = threadIdx.x;
    int gpb = blockIdx.x * 32;
    int b = gpb >> 11;
    for (int ii = t; ii < 32 * KNN; ii += 256) idxs[ii] = idx[(size_t)gpb * KNN + ii];
    if (t < 128) {
        sacc[t] = 0.f; sqacc[t] = 0.f;
        w1x[t * 3 + 0] = W1b[t * 168 + 128];
        w1x[t * 3 + 1] = W1b[t * 168 + 129];
        w1x[t * 3 + 2] = W1b[t * 168 + 130];
    }
    __syncthreads();
    int li = t >> 3, cq = (t & 7) * 16;
    int gp = gpb + li;
    float s[16], qa[16];
#pragma unroll
    for (int m = 0; m < 16; ++m) { s[m] = 0.f; qa[m] = 0.f; }
    int zb = b * N4;
#pragma unroll 4
    for (int k = 0; k < KNN; ++k) {
        int j = idxs[li * KNN + k];
        const float4* zr = (const float4*)(z + (size_t)(zb + j) * CH + cq);
#pragma unroll
        for (int m = 0; m < 4; ++m) {
            float4 v = zr[m];
#pragma unroll
            for (int e = 0; e < 4; ++e) {
                float vv = ((const float*)&v)[e];
                s[m * 4 + e] += vv; qa[m * 4 + e] += vv * vv;
            }
        }
    }
    // u[gp][cq..cq+15] on the fly (bf16-rounded xyz, bf16 W1x -> fp32)
    float x = bf2f(f2b(xyz4[gp * 3 + 0]));
    float y = bf2f(f2b(xyz4[gp * 3 + 1]));
    float zc = bf2f(f2b(xyz4[gp * 3 + 2]));
#pragma unroll
    for (int m = 0; m < 4; ++m) {
#pragma unroll
        for (int e = 0; e < 4; ++e) {
            int c = cq + m * 4 + e;
            float uu = x * bf2f(w1x[c * 3]) + y * bf2f(w1x[c * 3 + 1]) + zc * bf2f(w1x[c * 3 + 2]);
            float ss = s[m * 4 + e], qq = qa[m * 4 + e];
            atomicAdd(&sacc[c], ss - 32.f * uu);
            atomicAdd(&sqacc[c], qq - 2.f * uu * ss + 32.f * uu * uu);
        }
    }
    __syncthreads();
    if (t < 128) {
        atomicAdd(&stats[b * CH + t], sacc[t]);
        atomicAdd(&stats[B * CH + b * CH + t], sqacc[t]);
    }
}

// ---------------- fused pass: 256 rows/block, dbuf LDS; u computed on the fly ----------------
__global__ __launch_bounds__(256) void k_fused2(
    const float* __restrict__ z, const int* __restrict__ idx,
    const float* __restrict__ xyz4, const ushort* __restrict__ W1b,
    const ushort* __restrict__ W2b, const float* __restrict__ stats1,
    float* __restrict__ stats2, ushort* __restrict__ ymax)
{
    __shared__ __align__(16) ushort hs[2][64][136];
    __shared__ float smean[128], sinv[128];
    __shared__ float us[8][128];
    __shared__ ushort w1x[384];
    int t = threadIdx.x;
    int g0 = blockIdx.x * 256;          // 256 rows = 8 points
    int b = g0 >> 16;
    int gp0 = g0 >> 5;
    int l = t & 63, w = t >> 6, lr = l & 15, lg = l >> 4;
    U16 b2f[4][2];
#pragma unroll
    for (int kc = 0; kc < 4; ++kc)
#pragma unroll
        for (int jj = 0; jj < 2; ++jj)
            b2f[kc][jj].u = *(const uint4*)&W2b[(size_t)(w * 32 + jj * 16 + lr) * 136 + kc * 32 + lg * 8];
    if (t < 128) {
        float s = stats1[b * CH + t], q2 = stats1[B * CH + b * CH + t];
        float mean = s * (1.f / ROWS_PER_B);
        float var = q2 * (1.f / ROWS_PER_B) - mean * mean;
        smean[t] = mean; sinv[t] = rsqrtf(var + 1e-5f);
        w1x[t * 3 + 0] = W1b[t * 168 + 128];
        w1x[t * 3 + 1] = W1b[t * 168 + 129];
        w1x[t * 3 + 2] = W1b[t * 168 + 130];
    }
    __syncthreads();
    {   // us: 8 points x 128 cols, 4 cols/thread, same formula as k_gstats
        int p = t >> 5, i = t & 31;
        float x = bf2f(f2b(xyz4[(gp0 + p) * 3 + 0]));
        float y = bf2f(f2b(xyz4[(gp0 + p) * 3 + 1]));
        float zc = bf2f(f2b(xyz4[(gp0 + p) * 3 + 2]));
#pragma unroll
        for (int jj = 0; jj < 4; ++jj) {
            int c = i * 4 + jj;
            us[p][c] = x * bf2f(w1x[c * 3]) + y * bf2f(w1x[c * 3 + 1]) + zc * bf2f(w1x[c * 3 + 2]);
        }
    }
    int r = t >> 2, q = t & 3;
    // prologue: z loads for sub-tile 0
    float4 zv[8];
    {
        int j = idx[g0 + r];
        const float4* zr = (const float4*)(z + (size_t)(b * N4 + j) * CH + q * 32);
#pragma unroll
        for (int m = 0; m < 8; ++m) zv[m] = zr[m];
    }
    float sA[2] = {0.f, 0.f}, qA[2] = {0.f, 0.f};
    f32x4 z4 = {0.f, 0.f, 0.f, 0.f};
    __syncthreads();   // smean/sinv/us ready
    for (int st = 0; st < 4; ++st) {
        ushort (*buf)[136] = hs[st & 1];
        {
            int urow = (st * 64 + r) >> 5;
#pragma unroll
            for (int mm = 0; mm < 4; ++mm) {
                ushort o[8];
#pragma unroll
                for (int h = 0; h < 2; ++h) {
                    float4 v = zv[mm * 2 + h];
#pragma unroll
                    for (int e = 0; e < 4; ++e) {
                        int c = q * 32 + mm * 8 + h * 4 + e;
                        float val = (((const float*)&v)[e] - us[urow][c] - smean[c]) * sinv[c];
                        o[h * 4 + e] = f2b(fmaxf(val, 0.f));
                    }
                }
                *(uint4*)&buf[r][q * 32 + mm * 8] = *(uint4*)o;
            }
            if (q == 0) { uint4 zz = make_uint4(0, 0, 0, 0); *(uint4*)&buf[r][128] = zz; }
        }
        __syncthreads();
        if (st < 3) {
            int j = idx[g0 + (st + 1) * 64 + r];
            const float4* zr = (const float4*)(z + (size_t)(b * N4 + j) * CH + q * 32);
#pragma unroll
            for (int m = 0; m < 8; ++m) zv[m] = zr[m];
        }
        f32x4 acc[4][2];
#pragma unroll
        for (int i = 0; i < 4; ++i) { acc[i][0] = z4; acc[i][1] = z4; }
#pragma unroll
        for (int kc = 0; kc < 4; ++kc) {
            U16 a[4];
#pragma unroll
            for (int i = 0; i < 4; ++i) a[i].u = *(const uint4*)&buf[16 * i + lr][kc * 32 + lg * 8];
#pragma unroll
            for (int i = 0; i < 4; ++i)
#pragma unroll
                for (int jj = 0; jj < 2; ++jj)
                    acc[i][jj] = __builtin_amdgcn_mfma_f32_16x16x32_bf16(a[i].s, b2f[kc][jj].s, acc[i][jj], 0, 0, 0);
        }
        int gpA = gp0 + st * 2;
#pragma unroll
        for (int jj = 0; jj < 2; ++jj) {
            int c = w * 32 + jj * 16 + lr;
            float m0 = -3.4e38f, m1 = -3.4e38f;
#pragma unroll
            for (int i = 0; i < 4; ++i)
#pragma unroll
                for (int rg = 0; rg < 4; ++rg) {
                    float v = acc[i][jj][rg];
                    sA[jj] += v; qA[jj] += v * v;
                    if (i < 2) m0 = fmaxf(m0, v); else m1 = fmaxf(m1, v);
                }
            m0 = fmaxf(m0, __shfl_xor(m0, 16, 64)); m0 = fmaxf(m0, __shfl_xor(m0, 32, 64));
            m1 = fmaxf(m1, __shfl_xor(m1, 16, 64)); m1 = fmaxf(m1, __shfl_xor(m1, 32, 64));
            if (lg == 0) {
                ymax[(size_t)gpA * CH + c] = f2b(m0);
                ymax[(size_t)(gpA + 1) * CH + c] = f2b(m1);
            }
        }
    }
#pragma unroll
    for (int jj = 0; jj < 2; ++jj) {
        int c = w * 32 + jj * 16 + lr;
        float ss = sA[jj], qq = qA[jj];
        ss += __shfl_xor(ss, 16, 64); ss += __shfl_xor(ss, 32, 64);
        qq += __shfl_xor(qq, 16, 64); qq += __shfl_xor(qq, 32, 64);
        if (lg == 0) {
            atomicAdd(&stats2[b * CH + c], ss);
            atomicAdd(&stats2[B * CH + b * CH + c], qq);
        }
    }
}

// ---------------- FC head: relu(normrelu(ymax)@W1^T+b1) @ W2^T + b2 -> flow_lr [B,3,N4] ----------------
__global__ __launch_bounds__(256, 1) void k_fc(
    const ushort* __restrict__ Ymax, const float* __restrict__ stats,
    const float* __restrict__ W1, const float* __restrict__ b1,
    const float* __restrict__ W2, const float* __restrict__ b2,
    float* __restrict__ out)
{
    __shared__ float hs[64][132];
    __shared__ float ws[128][132];
    __shared__ float smean[128], sinv[128];
    int t = threadIdx.x;
    int g0 = blockIdx.x * 64;
    int b = g0 >> 11;
    if (t < 128) {
        float s = stats[b * CH + t], q2 = stats[B * CH + b * CH + t];
        float mean = s * (1.f / ROWS_PER_B);
        float var = q2 * (1.f / ROWS_PER_B) - mean * mean;
        smean[t] = mean; sinv[t] = rsqrtf(var + 1e-5f);
    }
    for (int i = t; i < 128 * 132; i += 256) {
        int dd = i / 132, c = i - dd * 132;
        ws[dd][c] = (c < 128) ? W1[dd * 128 + c] : 0.f;
    }
    __syncthreads();   // smean/sinv ready
    int r = t >> 2, q = t & 3;
    {
        const uint4* Xrow = (const uint4*)(Ymax + (size_t)(g0 + r) * CH + q * 32);
#pragma unroll
        for (int m = 0; m < 4; ++m) {
            uint4 v = Xrow[m];
            const uint* pv = (const uint*)&v;
            int c0 = q * 32 + m * 8;
#pragma unroll
            for (int e = 0; e < 4; ++e) {
                int c = c0 + 2 * e;
                hs[r][c]     = fmaxf((bf2f((ushort)(pv[e] & 0xffff)) - smean[c])     * sinv[c],     0.f);
                hs[r][c + 1] = fmaxf((bf2f((ushort)(pv[e] >> 16))    - smean[c + 1]) * sinv[c + 1], 0.f);
            }
        }
        if (q == 0) *(float4*)&hs[r][128] = make_float4(0.f, 0.f, 0.f, 0.f);
    }
    __syncthreads();
    int tx = t & 15, ty = t >> 4;
    float acc[4][8];
#pragma unroll
    for (int i = 0; i < 4; ++i)
#pragma unroll
        for (int jj = 0; jj < 8; ++jj) acc[i][jj] = 0.f;
    for (int kb = 0; kb < 33; ++kb) {
        float4 a[4]; float4 w[8];
#pragma unroll
        for (int i = 0; i < 4; ++i) a[i] = *(float4*)&hs[ty * 4 + i][kb * 4];
#pragma unroll
        for (int jj = 0; jj < 8; ++jj) w[jj] = *(float4*)&ws[tx + 16 * jj][kb * 4];
#pragma unroll
        for (int i = 0; i < 4; ++i)
#pragma unroll
            for (int jj = 0; jj < 8; ++jj)
                acc[i][jj] += a[i].x * w[jj].x + a[i].y * w[jj].y
                            + a[i].z * w[jj].z + a[i].w * w[jj].w;
    }
    __syncthreads();                     // done reading hs
#pragma unroll
    for (int jj = 0; jj < 8; ++jj) {
        int c = tx + 16 * jj;
        float bias = b1[c];
#pragma unroll
        for (int i = 0; i < 4; ++i)
            hs[ty * 4 + i][c] = fmaxf(acc[i][jj] + bias, 0.f);
    }
    __syncthreads();
    if (t < 192) {
        int rr = t / 3, o = t - rr * 3;
        float sum = b2[o];
        for (int c = 0; c < 128; ++c) sum += hs[rr][c] * W2[o * 128 + c];
        int g = g0 + rr;
        int bb = g >> 11, n = g & (N4 - 1);
        out[FLOWLR_OFF + ((size_t)bb * 3 + o) * N4 + n] = sum;
    }
}

// ---------------- feature propagation: 3-NN inverse-sqdist interp onto xyz1 ----------------
// Expanded-distance key: key = |p|^2 - 2 p.q; |q|^2 is a query-constant shift so ordering is
// preserved. Weights use d = max(key + |q|^2, 0).
// GRID: B * (N1/64) = 1024 blocks (64 queries per block, 4 threads each).
__global__ __launch_bounds__(256) void k_fp(
    const float* __restrict__ xyz_s1, const float* __restrict__ xyz4,
    float* __restrict__ out)
{
    __shared__ float xs[4 * 528], ys[4 * 528], zs[4 * 528], ss[4 * 528];
    int b = blockIdx.x >> 7;             // 128 blocks per batch
    int q0 = (blockIdx.x & 127) * 64;
    int t = threadIdx.x;
    for (int i = t; i < N4; i += 256) {
        int p = (i >> 9) * 528 + (i & 511);
        const float* s = xyz4 + (size_t)b * N4 * 3 + (size_t)i * 3;
        float x = s[0], y = s[1], z = s[2];
        xs[p] = x; ys[p] = y; zs[p] = z;
        ss[p] = x * x + y * y + z * z;
    }
    __syncthreads();
    int q = q0 + (t >> 2), c = t & 3;
    float qx = xyz_s1[((size_t)b * 3 + 0) * N1 + q];
    float qy = xyz_s1[((size_t)b * 3 + 1) * N1 + q];
    float qz = xyz_s1[((size_t)b * 3 + 2) * N1 + q];
    float nqx = -2.f * qx, nqy = -2.f * qy, nqz = -2.f * qz;
    float sq = qx * qx + qy * qy + qz * qz;
    float d0 = 3.4e38f, d1 = 3.4e38f, d2 = 3.4e38f;   // hold KEYS (= d^2 - |q|^2)
    int i0 = 0, i1 = 0, i2 = 0;
    int base = c * 528, nb = c * 512;
    for (int ii = 0; ii < 512; ii += 4) {
        float4 x4 = *(float4*)&xs[base + ii];
        float4 y4 = *(float4*)&ys[base + ii];
        float4 z4 = *(float4*)&zs[base + ii];
        float4 s4 = *(float4*)&ss[base + ii];
#pragma unroll
        for (int j = 0; j < 4; ++j) {
            float dd = fmaf(((const float*)&x4)[j], nqx,
                       fmaf(((const float*)&y4)[j], nqy,
                       fmaf(((const float*)&z4)[j], nqz, ((const float*)&s4)[j])));
            if (dd < d2) {               // strict < is tie-correct for ascending index scan
                int n = nb + ii + j;
                if (dd < d0)      { d2 = d1; i2 = i1; d1 = d0; i1 = i0; d0 = dd; i0 = n; }
                else if (dd < d1) { d2 = d1; i2 = i1; d1 = dd; i1 = n; }
                else              { d2 = dd; i2 = n; }
            }
        }
    }
    // merge the 4 chunk-local top-3 lists (lexicographic (key, idx) insertion)
#pragma unroll
    for (int m = 1; m <= 2; m <<= 1) {
        float e0 = __shfl_xor(d0, m, 64), e1 = __shfl_xor(d1, m, 64), e2 = __shfl_xor(d2, m, 64);
        int   j0 = __shfl_xor(i0, m, 64), j1 = __shfl_xor(i1, m, 64), j2 = __shfl_xor(i2, m, 64);
        float ed[3] = { e0, e1, e2 }; int ej[3] = { j0, j1, j2 };
#pragma unroll
        for (int s = 0; s < 3; ++s) {
            float dd = ed[s]; int jn = ej[s];
            bool lt2 = dd < d2 || (dd == d2 && jn < i2);
            if (lt2) {
                bool lt0 = dd < d0 || (dd == d0 && jn < i0);
                bool lt1 = dd < d1 || (dd == d1 && jn < i1);
                if (lt0)      { d2 = d1; i2 = i1; d1 = d0; i1 = i0; d0 = dd; i0 = jn; }
                else if (lt1) { d2 = d1; i2 = i1; d1 = dd; i1 = jn; }
                else          { d2 = dd; i2 = jn; }
            }
        }
    }
    float dd0 = fmaxf(d0 + sq, 0.f), dd1 = fmaxf(d1 + sq, 0.f), dd2 = fmaxf(d2 + sq, 0.f);
    float w0 = 1.f / (dd0 + 1e-8f), w1 = 1.f / (dd1 + 1e-8f), w2 = 1.f / (dd2 + 1e-8f);
    float inv = 1.f / (w0 + w1 + w2);
    const float* flr = out + FLOWLR_OFF + (size_t)b * 3 * N4;
    if (c < 3) {
        float v = (w0 * flr[c * N4 + i0] + w1 * flr[c * N4 + i1] + w2 * flr[c * N4 + i2]) * inv;
        out[((size_t)b * 3 + c) * N1 + q] = v;
    }
}

extern "C" void kernel_launch(void* const* d_in, const int* in_sizes, int n_in,
                              void* d_out, int out_size, void* d_ws, size_t ws_size,
                              hipStream_t stream) {
    const float* xyz_s1 = (const float*)d_in[0];
    const float* xyz_s4 = (const float*)d_in[1];
    const float* feats  = (const float*)d_in[2];
    const float* sa1_W1 = (const float*)d_in[3];
    const float* sa1_W2 = (const float*)d_in[5];
    const float* sa2_W1 = (const float*)d_in[7];
    const float* sa2_W2 = (const float*)d_in[9];
    const float* fc_W1  = (const float*)d_in[11];
    const float* fc_b1  = (const float*)d_in[12];
    const float* fc_W2  = (const float*)d_in[13];
    const float* fc_b2  = (const float*)d_in[14];
    float* out = (float*)d_out;

    char* wsb = (char*)d_ws;
    float*  xyz4   = (float*)(wsb + 0);                  // 196608 B
    int*    idx    = (int*)(wsb + 196608);               // 2 MB   -> 2293760
    ushort* featTb = (ushort*)(wsb + 2293760);           // 4 MB   -> 6488064
    ushort* W1b1   = (ushort*)(wsb + 6488064);           // 64 KB  -> 6553600
    ushort* W1b2   = (ushort*)(wsb + 6553600);           // 64 KB  -> 6619136
    ushort* W2b1   = (ushort*)(wsb + 6619136);           // 64 KB  -> 6684672
    ushort* W2b2   = (ushort*)(wsb + 6684672);           // 64 KB  -> 6750208
    float*  statsA = (float*)(wsb + 6750208);            // 8 KB each x4 (contiguous)
    float*  statsB = (float*)(wsb + 6758400);
    float*  statsC = (float*)(wsb + 6766592);
    float*  statsD = (float*)(wsb + 6774784);
    ushort* ymax   = (ushort*)(wsb + 6782976);           // 4 MB  -> 10977280
    float*  zbuf   = (float*)(wsb + 10977280);           // 8 MB  -> 19365888

    // ---- setup ----
    k_prep<<<400, 256, 0, stream>>>(xyz_s4, xyz4, sa1_W1, sa2_W1, sa1_W2, sa2_W2,
                                    W1b1, W1b2, W2b1, W2b2, statsA);
    k_knn<<<B * (N4 / 8), 512, 0, stream>>>(xyz4, idx);
    dim3 gt(B, N4 / 32, CH / 32), bt(32, 8);
    k_feat_t<<<gt, bt, 0, stream>>>(feats, featTb);

    // ---- SA1 ----
    k_dense<<<NPTS / 64, 256, 0, stream>>>(featTb, xyz4, W1b1, zbuf, nullptr);
    k_gstats<<<NPTS / 32, 256, 0, stream>>>(zbuf, idx, xyz4, W1b1, statsA);
    k_fused2<<<ROWS_TOTAL / 256, 256, 0, stream>>>(zbuf, idx, xyz4, W1b1, W2b1,
                                                   statsA, statsB, ymax);
    // ---- SA2 (dense folds the SA1 norm+relu of ymax via statsB) ----
    k_dense<<<NPTS / 64, 256, 0, stream>>>(ymax, xyz4, W1b2, zbuf, statsB);
    k_gstats<<<NPTS / 32, 256, 0, stream>>>(zbuf, idx, xyz4, W1b2, statsC);
    k_fused2<<<ROWS_TOTAL / 256, 256, 0, stream>>>(zbuf, idx, xyz4, W1b2, W2b2,
                                                   statsC, statsD, ymax);

    // ---- FC head (folds SA2 norm+relu via statsD) + flow_lr ----
    k_fc<<<(B * N4) / 64, 256, 0, stream>>>(ymax, statsD, fc_W1, fc_b1, fc_W2, fc_b2, out);
    // ---- feature propagation -> flow ----
    k_fp<<<B * (N1 / 64), 256, 0, stream>>>(xyz_s1, xyz4, out);
}

// Round 15
// 316.864 us; speedup vs baseline: 11.1478x; 1.1477x over previous
//
#include <hip/hip_runtime.h>
#include <hip/hip_bf16.h>

#define B 8
#define N1 8192
#define N4 2048
#define CH 128
#define KNN 32
#define ROWS_PER_B (N4 * KNN)          // 65536 rows per batch in the [B,N,K] flattening
#define ROWS_TOTAL (B * ROWS_PER_B)    // 524288
#define NPTS (B * N4)                  // 16384 total points
#define FLOWLR_OFF (B * 3 * N1)        // flow_lr starts after flow in d_out

typedef unsigned int uint;
typedef unsigned short ushort;
typedef __attribute__((ext_vector_type(8))) short short8;
typedef __attribute__((ext_vector_type(4))) float f32x4;

union U16 { uint4 u; short8 s; };

__device__ __forceinline__ float bf2f(ushort u) {
    union { uint i; float f; } v; v.i = ((uint)u) << 16; return v.f;
}
__device__ __forceinline__ ushort f2b(float f) {
    __hip_bfloat16 h = __float2bfloat16(f);
    return *(ushort*)&h;
}

// ---------------- prep: fused W converters (bf16, permuted/padded) + xyz transpose + stats zero ----------------
__global__ void k_prep(const float* __restrict__ xyz_s4, float* __restrict__ xyz4,
                       const float* __restrict__ sa1_W1, const float* __restrict__ sa2_W1,
                       const float* __restrict__ sa1_W2, const float* __restrict__ sa2_W2,
                       ushort* __restrict__ W1b1, ushort* __restrict__ W1b2,
                       ushort* __restrict__ W2b1, ushort* __restrict__ W2b2,
                       float* __restrict__ stats)
{
    int i = blockIdx.x * 256 + threadIdx.x;
    if (i < 43008) {
        const float* W = (i < 21504) ? sa1_W1 : sa2_W1;
        ushort* o = (i < 21504) ? W1b1 : W1b2;
        int j = (i < 21504) ? i : i - 21504;
        int d = j / 168, c = j - d * 168;
        float v = 0.f;
        if (c < 128)      v = W[d * 131 + 3 + c];
        else if (c < 131) v = W[d * 131 + (c - 128)];
        o[j] = f2b(v);
    } else if (i < 77824) {
        const float* W = (i < 60416) ? sa1_W2 : sa2_W2;
        ushort* o = (i < 60416) ? W2b1 : W2b2;
        int j = (i < 60416) ? i - 43008 : i - 60416;
        int d = j / 136, c = j - d * 136;
        o[j] = (c < 128) ? f2b(W[d * 128 + c]) : (ushort)0;
    } else if (i < 94208) {
        int g = i - 77824;
        int b = g >> 11, n = g & (N4 - 1);
        xyz4[g * 3 + 0] = xyz_s4[(b * 3 + 0) * N4 + n];
        xyz4[g * 3 + 1] = xyz_s4[(b * 3 + 1) * N4 + n];
        xyz4[g * 3 + 2] = xyz_s4[(b * 3 + 2) * N4 + n];
    } else if (i < 102400) {
        stats[i - 94208] = 0.f;        // zeros statsA..statsD (contiguous 8192 floats)
    }
}

// ---------------- transpose feats [B,C,N4] fp32 -> featTb [B,N4,C] bf16 ----------------
__global__ void k_feat_t(const float* __restrict__ feats, ushort* __restrict__ featTb) {
    __shared__ float tile[32][33];
    int b = blockIdx.x, nb = blockIdx.y, cb = blockIdx.z;
    int tx = threadIdx.x, ty = threadIdx.y; // 32 x 8
    int n0 = nb * 32, c0 = cb * 32;
#pragma unroll
    for (int i = 0; i < 4; ++i) {
        int c = c0 + ty + 8 * i;
        tile[ty + 8 * i][tx] = feats[((size_t)b * CH + c) * N4 + n0 + tx];
    }
    __syncthreads();
#pragma unroll
    for (int i = 0; i < 4; ++i) {
        int n = n0 + ty + 8 * i;
        featTb[((size_t)b * N4 + n) * CH + c0 + tx] = f2b(tile[tx][ty + 8 * i]);
    }
}

// ---------------- KNN via exact threshold-select (interpolation search + order-statistic gap exit) ----------------
__global__ __launch_bounds__(512) void k_knn(const float* __restrict__ xyz4, int* __restrict__ idxout) {
    __shared__ float pts[N4 * 3];
    int b = blockIdx.x >> 8;            // 256 blocks per batch
    int qbase = (blockIdx.x & 255) * 8;
    for (int i = threadIdx.x; i < N4 * 3; i += 512) pts[i] = xyz4[(size_t)b * N4 * 3 + i];
    __syncthreads();
    int wave = threadIdx.x >> 6, lane = threadIdx.x & 63;
    int qn = qbase + wave;
    float qx = pts[qn * 3 + 0], qy = pts[qn * 3 + 1], qz = pts[qn * 3 + 2];
    float d[32];
#pragma unroll
    for (int t = 0; t < 32; ++t) {
        int c = t * 64 + lane;
        float dx = pts[c * 3 + 0] - qx;
        float dy = pts[c * 3 + 1] - qy;
        float dz = pts[c * 3 + 2] - qz;
        d[t] = dx * dx + dy * dy + dz * dz;
    }
    uint lo = 0u, hi = 0x7F800000u;
    int cLT = 0, cHI = N4;
    float T;
    bool strict = false;
    int it = 0;
    for (;;) {
        if (hi - lo <= 1u) { T = __uint_as_float(lo); break; }
        if (cHI - cLT == 1) {
            float flo = __uint_as_float(lo), fhi = __uint_as_float(hi);
            float m = 3.4e38f;
#pragma unroll
            for (int t = 0; t < 32; ++t) {
                float dv = d[t];
                if (dv >= flo && dv < fhi) m = fminf(m, dv);
            }
#pragma unroll
            for (int s = 1; s < 64; s <<= 1) m = fminf(m, __shfl_xor(m, s, 64));
            T = m;
            break;
        }
        uint mid;
        if ((it & 3) == 0) {
            mid = (lo + hi) >> 1;
        } else {
            float flo = __uint_as_float(lo), fhi = __uint_as_float(hi);
            float fm = flo + (fhi - flo) * ((float)(KNN - cLT) / (float)(cHI - cLT));
            mid = __float_as_uint(fm);
            if (mid <= lo) mid = lo + 1u;
            if (mid >= hi) mid = hi - 1u;
        }
        float fmid = __uint_as_float(mid);
        int c = 0;
#pragma unroll
        for (int t = 0; t < 32; ++t) c += __popcll(__ballot(d[t] < fmid));
        if (c == KNN) { T = fmid; strict = true; break; }
        if (c < KNN) { lo = mid; cLT = c; } else { hi = mid; cHI = c; }
        ++it;
    }
    int outb = (b * N4 + qn) * KNN;
    unsigned long long lmlt = (1ull << lane) - 1ull;
    if (strict) {
        int baseLT = 0;
#pragma unroll
        for (int t = 0; t < 32; ++t) {
            bool lt = d[t] < T;
            unsigned long long m = __ballot(lt);
            if (lt) idxout[outb + baseLT + __popcll(m & lmlt)] = t * 64 + lane;
            baseLT += __popcll(m);
        }
    } else {
        int baseLT = 0, baseEQ = cLT;
#pragma unroll
        for (int t = 0; t < 32; ++t) {
            bool lt = d[t] < T;
            unsigned long long m = __ballot(lt);
            if (lt) idxout[outb + baseLT + __popcll(m & lmlt)] = t * 64 + lane;
            baseLT += __popcll(m);
            bool eq = (d[t] == T);
            unsigned long long me = __ballot(eq);
            if (eq) {
                int rk = baseEQ + __popcll(me & lmlt);
                if (rk < KNN) idxout[outb + rk] = t * 64 + lane;
            }
            baseEQ += __popcll(me);
        }
    }
}

// ---------------- dense z GEMM: z[p] = [in_p | xyz_p] @ W1^T -> bf16 out (LDS repack, coalesced) ----------------
// stats == nullptr: in_p = Fb row. stats != nullptr: in_p = normrelu(Fb row, stats) (affine-folded).
__global__ __launch_bounds__(256) void k_dense(
    const ushort* __restrict__ Fb, const float* __restrict__ xyz4,
    const ushort* __restrict__ W1b, ushort* __restrict__ z,
    const float* __restrict__ stats)
{
    __shared__ __align__(16) ushort hs[64][168];
    __shared__ float sinvs[128], sprem[128];   // sinv, mean*sinv
    int t = threadIdx.x;
    int r = t >> 2, q = t & 3;
    int l = t & 63, w = t >> 6, lr = l & 15, lg = l >> 4;
    int g0 = blockIdx.x * 64;
    int b = g0 >> 11;                    // 2048 points per batch
    if (stats) {
        if (t < 128) {
            float s = stats[b * CH + t], q2 = stats[B * CH + b * CH + t];
            float mean = s * (1.f / ROWS_PER_B);
            float var = q2 * (1.f / ROWS_PER_B) - mean * mean;
            float iv = rsqrtf(var + 1e-5f);
            sinvs[t] = iv; sprem[t] = mean * iv;
        }
        __syncthreads();
    }
    {
        int p = g0 + r;
        const uint4* src = (const uint4*)(Fb + (size_t)p * CH) + q * 4;
        uint4* dst = (uint4*)&hs[r][q * 32];
        if (stats) {
#pragma unroll
            for (int m = 0; m < 4; ++m) {
                uint4 v = src[m];
                const uint* pv = (const uint*)&v;
                ushort o[8];
#pragma unroll
                for (int e = 0; e < 4; ++e) {
                    int c = q * 32 + m * 8 + e * 2;
                    o[e * 2]     = f2b(fmaxf(fmaf(bf2f((ushort)(pv[e] & 0xffff)), sinvs[c],     -sprem[c]),     0.f));
                    o[e * 2 + 1] = f2b(fmaxf(fmaf(bf2f((ushort)(pv[e] >> 16)),    sinvs[c + 1], -sprem[c + 1]), 0.f));
                }
                dst[m] = *(uint4*)o;
            }
        } else {
#pragma unroll
            for (int m = 0; m < 4; ++m) dst[m] = src[m];
        }
        uint4 zz = make_uint4(0, 0, 0, 0);
        *(uint4*)&hs[r][128 + q * 8] = zz;
        if (q == 0) {
            *(uint4*)&hs[r][160] = zz;
            hs[r][128] = f2b(xyz4[p * 3 + 0]);
            hs[r][129] = f2b(xyz4[p * 3 + 1]);
            hs[r][130] = f2b(xyz4[p * 3 + 2]);
        }
    }
    U16 bf[5][2];
#pragma unroll
    for (int kc = 0; kc < 5; ++kc)
#pragma unroll
        for (int jj = 0; jj < 2; ++jj)
            bf[kc][jj].u = *(const uint4*)&W1b[(size_t)(w * 32 + jj * 16 + lr) * 168 + kc * 32 + lg * 8];
    __syncthreads();
    f32x4 acc[4][2];
    f32x4 z4 = {0.f, 0.f, 0.f, 0.f};
#pragma unroll
    for (int i = 0; i < 4; ++i) { acc[i][0] = z4; acc[i][1] = z4; }
#pragma unroll
    for (int kc = 0; kc < 5; ++kc) {
        U16 a[4];
#pragma unroll
        for (int i = 0; i < 4; ++i) a[i].u = *(const uint4*)&hs[16 * i + lr][kc * 32 + lg * 8];
#pragma unroll
        for (int i = 0; i < 4; ++i)
#pragma unroll
            for (int jj = 0; jj < 2; ++jj)
                acc[i][jj] = __builtin_amdgcn_mfma_f32_16x16x32_bf16(a[i].s, bf[kc][jj].s, acc[i][jj], 0, 0, 0);
    }
    __syncthreads();   // hs reads done -> reuse as bf16 repack buffer
#pragma unroll
    for (int jj = 0; jj < 2; ++jj)
#pragma unroll
        for (int i = 0; i < 4; ++i)
#pragma unroll
            for (int rg = 0; rg < 4; ++rg)
                hs[16 * i + lg * 4 + rg][w * 32 + jj * 16 + lr] = f2b(acc[i][jj][rg]);
    __syncthreads();
    {
        uint4* dst = (uint4*)(z + (size_t)(g0 + r) * CH + q * 32);
#pragma unroll
        for (int m = 0; m < 4; ++m) dst[m] = *(const uint4*)&hs[r][q * 32 + m * 8];
    }
}

// ---------------- gather-stats: per-(b,c) sum/sumsq of y1 = z[j]-u[n]; z bf16, u on the fly ----------------
__global__ __launch_bounds__(256) void k_gstats(
    const ushort* __restrict__ z, const int* __restrict__ idx,
    const float* __restrict__ xyz4, const ushort* __restrict__ W1b,
    float* __restrict__ stats)
{
    __shared__ int idxs[32 * KNN];
    __shared__ float sacc[128], sqacc[128];
    __shared__ ushort w1x[384];          // [c][a], c*3+a
    int t = threadIdx.x;
    int gpb = blockIdx.x * 32;
    int b = gpb >> 11;
    for (int ii = t; ii < 32 * KNN; ii += 256) idxs[ii] = idx[(size_t)gpb * KNN + ii];
    if (t < 128) {
        sacc[t] = 0.f; sqacc[t] = 0.f;
        w1x[t * 3 + 0] = W1b[t * 168 + 128];
        w1x[t * 3 + 1] = W1b[t * 168 + 129];
        w1x[t * 3 + 2] = W1b[t * 168 + 130];
    }
    __syncthreads();
    int li = t >> 3, cq = (t & 7) * 16;
    int gp = gpb + li;
    float s[16], qa[16];
#pragma unroll
    for (int m = 0; m < 16; ++m) { s[m] = 0.f; qa[m] = 0.f; }
    int zb = b * N4;
#pragma unroll 4
    for (int k = 0; k < KNN; ++k) {
        int j = idxs[li * KNN + k];
        const uint4* zr = (const uint4*)(z + (size_t)(zb + j) * CH + cq);  // 16 bf16 = 2x uint4
        uint4 v0 = zr[0], v1 = zr[1];
        const uint* pv = (const uint*)&v0;
#pragma unroll
        for (int u8 = 0; u8 < 8; ++u8) {
            uint vv = (u8 < 4) ? pv[u8] : ((const uint*)&v1)[u8 - 4];
            float f0 = bf2f((ushort)(vv & 0xffff));
            float f1 = bf2f((ushort)(vv >> 16));
            s[u8 * 2] += f0;     qa[u8 * 2] += f0 * f0;
            s[u8 * 2 + 1] += f1; qa[u8 * 2 + 1] += f1 * f1;
        }
    }
    float x = bf2f(f2b(xyz4[gp * 3 + 0]));
    float y = bf2f(f2b(xyz4[gp * 3 + 1]));
    float zc = bf2f(f2b(xyz4[gp * 3 + 2]));
#pragma unroll
    for (int m = 0; m < 16; ++m) {
        int c = cq + m;
        float uu = x * bf2f(w1x[c * 3]) + y * bf2f(w1x[c * 3 + 1]) + zc * bf2f(w1x[c * 3 + 2]);
        float ss = s[m], qq = qa[m];
        atomicAdd(&sacc[c], ss - 32.f * uu);
        atomicAdd(&sqacc[c], qq - 2.f * uu * ss + 32.f * uu * uu);
    }
    __syncthreads();
    if (t < 128) {
        atomicAdd(&stats[b * CH + t], sacc[t]);
        atomicAdd(&stats[B * CH + b * CH + t], sqacc[t]);
    }
}

// ---------------- fused pass: 256 rows/block, dbuf LDS; z bf16; affine-folded normalization ----------------
__global__ __launch_bounds__(256) void k_fused2(
    const ushort* __restrict__ z, const int* __restrict__ idx,
    const float* __restrict__ xyz4, const ushort* __restrict__ W1b,
    const ushort* __restrict__ W2b, const float* __restrict__ stats1,
    float* __restrict__ stats2, ushort* __restrict__ ymax)
{
    __shared__ __align__(16) ushort hs[2][64][136];
    __shared__ float sinvs[128], smean[128];
    __shared__ float pre[8][128];        // (u + mean) * sinv per point
    __shared__ ushort w1x[384];
    int t = threadIdx.x;
    int g0 = blockIdx.x * 256;          // 256 rows = 8 points
    int b = g0 >> 16;
    int gp0 = g0 >> 5;
    int l = t & 63, w = t >> 6, lr = l & 15, lg = l >> 4;
    U16 b2f[4][2];
#pragma unroll
    for (int kc = 0; kc < 4; ++kc)
#pragma unroll
        for (int jj = 0; jj < 2; ++jj)
            b2f[kc][jj].u = *(const uint4*)&W2b[(size_t)(w * 32 + jj * 16 + lr) * 136 + kc * 32 + lg * 8];
    if (t < 128) {
        float s = stats1[b * CH + t], q2 = stats1[B * CH + b * CH + t];
        float mean = s * (1.f / ROWS_PER_B);
        float var = q2 * (1.f / ROWS_PER_B) - mean * mean;
        float iv = rsqrtf(var + 1e-5f);
        sinvs[t] = iv; smean[t] = mean;
        w1x[t * 3 + 0] = W1b[t * 168 + 128];
        w1x[t * 3 + 1] = W1b[t * 168 + 129];
        w1x[t * 3 + 2] = W1b[t * 168 + 130];
    }
    __syncthreads();
    {   // pre[p][c] = (u[p][c] + mean[c]) * sinv[c]; 8 points x 128 cols, 4 cols/thread
        int p = t >> 5, i = t & 31;
        float x = bf2f(f2b(xyz4[(gp0 + p) * 3 + 0]));
        float y = bf2f(f2b(xyz4[(gp0 + p) * 3 + 1]));
        float zc = bf2f(f2b(xyz4[(gp0 + p) * 3 + 2]));
#pragma unroll
        for (int jj = 0; jj < 4; ++jj) {
            int c = i * 4 + jj;
            float uu = x * bf2f(w1x[c * 3]) + y * bf2f(w1x[c * 3 + 1]) + zc * bf2f(w1x[c * 3 + 2]);
            pre[p][c] = (uu + smean[c]) * sinvs[c];
        }
    }
    int r = t >> 2, q = t & 3;
    // prologue: z loads for sub-tile 0 (32 bf16 cols = 4x uint4)
    uint4 zv[4];
    {
        int j = idx[g0 + r];
        const uint4* zr = (const uint4*)(z + (size_t)(b * N4 + j) * CH + q * 32);
#pragma unroll
        for (int m = 0; m < 4; ++m) zv[m] = zr[m];
    }
    float sA[2] = {0.f, 0.f}, qA[2] = {0.f, 0.f};
    f32x4 z4 = {0.f, 0.f, 0.f, 0.f};
    __syncthreads();   // sinvs/pre ready
    for (int st = 0; st < 4; ++st) {
        ushort (*buf)[136] = hs[st & 1];
        {
            int urow = (st * 64 + r) >> 5;
#pragma unroll
            for (int mm = 0; mm < 4; ++mm) {
                const uint* pv = (const uint*)&zv[mm];
                ushort o[8];
#pragma unroll
                for (int e = 0; e < 4; ++e) {
                    int c = q * 32 + mm * 8 + e * 2;
                    float f0 = bf2f((ushort)(pv[e] & 0xffff));
                    float f1 = bf2f((ushort)(pv[e] >> 16));
                    o[e * 2]     = f2b(fmaxf(fmaf(f0, sinvs[c],     -pre[urow][c]),     0.f));
                    o[e * 2 + 1] = f2b(fmaxf(fmaf(f1, sinvs[c + 1], -pre[urow][c + 1]), 0.f));
                }
                *(uint4*)&buf[r][q * 32 + mm * 8] = *(uint4*)o;
            }
            if (q == 0) { uint4 zz = make_uint4(0, 0, 0, 0); *(uint4*)&buf[r][128] = zz; }
        }
        __syncthreads();
        if (st < 3) {
            int j = idx[g0 + (st + 1) * 64 + r];
            const uint4* zr = (const uint4*)(z + (size_t)(b * N4 + j) * CH + q * 32);
#pragma unroll
            for (int m = 0; m < 4; ++m) zv[m] = zr[m];
        }
        f32x4 acc[4][2];
#pragma unroll
        for (int i = 0; i < 4; ++i) { acc[i][0] = z4; acc[i][1] = z4; }
#pragma unroll
        for (int kc = 0; kc < 4; ++kc) {
            U16 a[4];
#pragma unroll
            for (int i = 0; i < 4; ++i) a[i].u = *(const uint4*)&buf[16 * i + lr][kc * 32 + lg * 8];
#pragma unroll
            for (int i = 0; i < 4; ++i)
#pragma unroll
                for (int jj = 0; jj < 2; ++jj)
                    acc[i][jj] = __builtin_amdgcn_mfma_f32_16x16x32_bf16(a[i].s, b2f[kc][jj].s, acc[i][jj], 0, 0, 0);
        }
        int gpA = gp0 + st * 2;
#pragma unroll
        for (int jj = 0; jj < 2; ++jj) {
            int c = w * 32 + jj * 16 + lr;
            float m0 = -3.4e38f, m1 = -3.4e38f;
#pragma unroll
            for (int i = 0; i < 4; ++i)
#pragma unroll
                for (int rg = 0; rg < 4; ++rg) {
                    float v = acc[i][jj][rg];
                    sA[jj] += v; qA[jj] += v * v;
                    if (i < 2) m0 = fmaxf(m0, v); else m1 = fmaxf(m1, v);
                }
            m0 = fmaxf(m0, __shfl_xor(m0, 16, 64)); m0 = fmaxf(m0, __shfl_xor(m0, 32, 64));
            m1 = fmaxf(m1, __shfl_xor(m1, 16, 64)); m1 = fmaxf(m1, __shfl_xor(m1, 32, 64));
            if (lg == 0) {
                ymax[(size_t)gpA * CH + c] = f2b(m0);
                ymax[(size_t)(gpA + 1) * CH + c] = f2b(m1);
            }
        }
    }
#pragma unroll
    for (int jj = 0; jj < 2; ++jj) {
        int c = w * 32 + jj * 16 + lr;
        float ss = sA[jj], qq = qA[jj];
        ss += __shfl_xor(ss, 16, 64); ss += __shfl_xor(ss, 32, 64);
        qq += __shfl_xor(qq, 16, 64); qq += __shfl_xor(qq, 32, 64);
        if (lg == 0) {
            atomicAdd(&stats2[b * CH + c], ss);
            atomicAdd(&stats2[B * CH + b * CH + c], qq);
        }
    }
}

// ---------------- FC head: relu(normrelu(ymax)@W1^T+b1) @ W2^T + b2 -> flow_lr [B,3,N4] ----------------
__global__ __launch_bounds__(256, 1) void k_fc(
    const ushort* __restrict__ Ymax, const float* __restrict__ stats,
    const float* __restrict__ W1, const float* __restrict__ b1,
    const float* __restrict__ W2, const float* __restrict__ b2,
    float* __restrict__ out)
{
    __shared__ float hs[64][132];
    __shared__ float ws[128][132];
    __shared__ float sinvs[128], sprem[128];
    int t = threadIdx.x;
    int g0 = blockIdx.x * 64;
    int b = g0 >> 11;
    if (t < 128) {
        float s = stats[b * CH + t], q2 = stats[B * CH + b * CH + t];
        float mean = s * (1.f / ROWS_PER_B);
        float var = q2 * (1.f / ROWS_PER_B) - mean * mean;
        float iv = rsqrtf(var + 1e-5f);
        sinvs[t] = iv; sprem[t] = mean * iv;
    }
    for (int i = t; i < 128 * 132; i += 256) {
        int dd = i / 132, c = i - dd * 132;
        ws[dd][c] = (c < 128) ? W1[dd * 128 + c] : 0.f;
    }
    __syncthreads();
    int r = t >> 2, q = t & 3;
    {
        const uint4* Xrow = (const uint4*)(Ymax + (size_t)(g0 + r) * CH + q * 32);
#pragma unroll
        for (int m = 0; m < 4; ++m) {
            uint4 v = Xrow[m];
            const uint* pv = (const uint*)&v;
            int c0 = q * 32 + m * 8;
#pragma unroll
            for (int e = 0; e < 4; ++e) {
                int c = c0 + 2 * e;
                hs[r][c]     = fmaxf(fmaf(bf2f((ushort)(pv[e] & 0xffff)), sinvs[c],     -sprem[c]),     0.f);
                hs[r][c + 1] = fmaxf(fmaf(bf2f((ushort)(pv[e] >> 16)),    sinvs[c + 1], -sprem[c + 1]), 0.f);
            }
        }
        if (q == 0) *(float4*)&hs[r][128] = make_float4(0.f, 0.f, 0.f, 0.f);
    }
    __syncthreads();
    int tx = t & 15, ty = t >> 4;
    float acc[4][8];
#pragma unroll
    for (int i = 0; i < 4; ++i)
#pragma unroll
        for (int jj = 0; jj < 8; ++jj) acc[i][jj] = 0.f;
    for (int kb = 0; kb < 33; ++kb) {
        float4 a[4]; float4 w[8];
#pragma unroll
        for (int i = 0; i < 4; ++i) a[i] = *(float4*)&hs[ty * 4 + i][kb * 4];
#pragma unroll
        for (int jj = 0; jj < 8; ++jj) w[jj] = *(float4*)&ws[tx + 16 * jj][kb * 4];
#pragma unroll
        for (int i = 0; i < 4; ++i)
#pragma unroll
            for (int jj = 0; jj < 8; ++jj)
                acc[i][jj] += a[i].x * w[jj].x + a[i].y * w[jj].y
                            + a[i].z * w[jj].z + a[i].w * w[jj].w;
    }
    __syncthreads();
#pragma unroll
    for (int jj = 0; jj < 8; ++jj) {
        int c = tx + 16 * jj;
        float bias = b1[c];
#pragma unroll
        for (int i = 0; i < 4; ++i)
            hs[ty * 4 + i][c] = fmaxf(acc[i][jj] + bias, 0.f);
    }
    __syncthreads();
    if (t < 192) {
        int rr = t / 3, o = t - rr * 3;
        float sum = b2[o];
        for (int c = 0; c < 128; ++c) sum += hs[rr][c] * W2[o * 128 + c];
        int g = g0 + rr;
        int bb = g >> 11, n = g & (N4 - 1);
        out[FLOWLR_OFF + ((size_t)bb * 3 + o) * N4 + n] = sum;
    }
}

// ---------------- feature propagation: 3-NN inverse-sqdist interp onto xyz1 ----------------
__global__ __launch_bounds__(256) void k_fp(
    const float* __restrict__ xyz_s1, const float* __restrict__ xyz4,
    float* __restrict__ out)
{
    __shared__ float xs[4 * 528], ys[4 * 528], zs[4 * 528], ss[4 * 528];
    int b = blockIdx.x >> 7;             // 128 blocks per batch
    int q0 = (blockIdx.x & 127) * 64;
    int t = threadIdx.x;
    for (int i = t; i < N4; i += 256) {
        int p = (i >> 9) * 528 + (i & 511);
        const float* s = xyz4 + (size_t)b * N4 * 3 + (size_t)i * 3;
        float x = s[0], y = s[1], z = s[2];
        xs[p] = x; ys[p] = y; zs[p] = z;
        ss[p] = x * x + y * y + z * z;
    }
    __syncthreads();
    int q = q0 + (t >> 2), c = t & 3;
    float qx = xyz_s1[((size_t)b * 3 + 0) * N1 + q];
    float qy = xyz_s1[((size_t)b * 3 + 1) * N1 + q];
    float qz = xyz_s1[((size_t)b * 3 + 2) * N1 + q];
    float nqx = -2.f * qx, nqy = -2.f * qy, nqz = -2.f * qz;
    float sq = qx * qx + qy * qy + qz * qz;
    float d0 = 3.4e38f, d1 = 3.4e38f, d2 = 3.4e38f;   // KEYS (= d^2 - |q|^2)
    int i0 = 0, i1 = 0, i2 = 0;
    int base = c * 528, nb = c * 512;
    for (int ii = 0; ii < 512; ii += 4) {
        float4 x4 = *(float4*)&xs[base + ii];
        float4 y4 = *(float4*)&ys[base + ii];
        float4 z4 = *(float4*)&zs[base + ii];
        float4 s4 = *(float4*)&ss[base + ii];
#pragma unroll
        for (int j = 0; j < 4; ++j) {
            float dd = fmaf(((const float*)&x4)[j], nqx,
                       fmaf(((const float*)&y4)[j], nqy,
                       fmaf(((const float*)&z4)[j], nqz, ((const float*)&s4)[j])));
            if (dd < d2) {
                int n = nb + ii + j;
                if (dd < d0)      { d2 = d1; i2 = i1; d1 = d0; i1 = i0; d0 = dd; i0 = n; }
                else if (dd < d1) { d2 = d1; i2 = i1; d1 = dd; i1 = n; }
                else              { d2 = dd; i2 = n; }
            }
        }
    }
#pragma unroll
    for (int m = 1; m <= 2; m <<= 1) {
        float e0 = __shfl_xor(d0, m, 64), e1 = __shfl_xor(d1, m, 64), e2 = __shfl_xor(d2, m, 64);
        int   j0 = __shfl_xor(i0, m, 64), j1 = __shfl_xor(i1, m, 64), j2 = __shfl_xor(i2, m, 64);
        float ed[3] = { e0, e1, e2 }; int ej[3] = { j0, j1, j2 };
#pragma unroll
        for (int s = 0; s < 3; ++s) {
            float dd = ed[s]; int jn = ej[s];
            bool lt2 = dd < d2 || (dd == d2 && jn < i2);
            if (lt2) {
                bool lt0 = dd < d0 || (dd == d0 && jn < i0);
                bool lt1 = dd < d1 || (dd == d1 && jn < i1);
                if (lt0)      { d2 = d1; i2 = i1; d1 = d0; i1 = i0; d0 = dd; i0 = jn; }
                else if (lt1) { d2 = d1; i2 = i1; d1 = dd; i1 = jn; }
                else          { d2 = dd; i2 = jn; }
            }
        }
    }
    float dd0 = fmaxf(d0 + sq, 0.f), dd1 = fmaxf(d1 + sq, 0.f), dd2 = fmaxf(d2 + sq, 0.f);
    float w0 = 1.f / (dd0 + 1e-8f), w1 = 1.f / (dd1 + 1e-8f), w2 = 1.f / (dd2 + 1e-8f);
    float inv = 1.f / (w0 + w1 + w2);
    const float* flr = out + FLOWLR_OFF + (size_t)b * 3 * N4;
    if (c < 3) {
        float v = (w0 * flr[c * N4 + i0] + w1 * flr[c * N4 + i1] + w2 * flr[c * N4 + i2]) * inv;
        out[((size_t)b * 3 + c) * N1 + q] = v;
    }
}

extern "C" void kernel_launch(void* const* d_in, const int* in_sizes, int n_in,
                              void* d_out, int out_size, void* d_ws, size_t ws_size,
                              hipStream_t stream) {
    const float* xyz_s1 = (const float*)d_in[0];
    const float* xyz_s4 = (const float*)d_in[1];
    const float* feats  = (const float*)d_in[2];
    const float* sa1_W1 = (const float*)d_in[3];
    const float* sa1_W2 = (const float*)d_in[5];
    const float* sa2_W1 = (const float*)d_in[7];
    const float* sa2_W2 = (const float*)d_in[9];
    const float* fc_W1  = (const float*)d_in[11];
    const float* fc_b1  = (const float*)d_in[12];
    const float* fc_W2  = (const float*)d_in[13];
    const float* fc_b2  = (const float*)d_in[14];
    float* out = (float*)d_out;

    char* wsb = (char*)d_ws;
    float*  xyz4   = (float*)(wsb + 0);                  // 196608 B
    int*    idx    = (int*)(wsb + 196608);               // 2 MB   -> 2293760
    ushort* featTb = (ushort*)(wsb + 2293760);           // 4 MB   -> 6488064
    ushort* W1b1   = (ushort*)(wsb + 6488064);           // 64 KB  -> 6553600
    ushort* W1b2   = (ushort*)(wsb + 6553600);           // 64 KB  -> 6619136
    ushort* W2b1   = (ushort*)(wsb + 6619136);           // 64 KB  -> 6684672
    ushort* W2b2   = (ushort*)(wsb + 6684672);           // 64 KB  -> 6750208
    float*  statsA = (float*)(wsb + 6750208);            // 8 KB each x4 (contiguous)
    float*  statsB = (float*)(wsb + 6758400);
    float*  statsC = (float*)(wsb + 6766592);
    float*  statsD = (float*)(wsb + 6774784);
    ushort* ymax   = (ushort*)(wsb + 6782976);           // 4 MB  -> 10977280
    ushort* zbuf   = (ushort*)(wsb + 10977280);          // 4 MB  -> 15171584 (bf16 z)

    // ---- setup ----
    k_prep<<<400, 256, 0, stream>>>(xyz_s4, xyz4, sa1_W1, sa2_W1, sa1_W2, sa2_W2,
                                    W1b1, W1b2, W2b1, W2b2, statsA);
    k_knn<<<B * (N4 / 8), 512, 0, stream>>>(xyz4, idx);
    dim3 gt(B, N4 / 32, CH / 32), bt(32, 8);
    k_feat_t<<<gt, bt, 0, stream>>>(feats, featTb);

    // ---- SA1 ----
    k_dense<<<NPTS / 64, 256, 0, stream>>>(featTb, xyz4, W1b1, zbuf, nullptr);
    k_gstats<<<NPTS / 32, 256, 0, stream>>>(zbuf, idx, xyz4, W1b1, statsA);
    k_fused2<<<ROWS_TOTAL / 256, 256, 0, stream>>>(zbuf, idx, xyz4, W1b1, W2b1,
                                                   statsA, statsB, ymax);
    // ---- SA2 (dense folds the SA1 norm+relu of ymax via statsB) ----
    k_dense<<<NPTS / 64, 256, 0, stream>>>(ymax, xyz4, W1b2, zbuf, statsB);
    k_gstats<<<NPTS / 32, 256, 0, stream>>>(zbuf, idx, xyz4, W1b2, statsC);
    k_fused2<<<ROWS_TOTAL / 256, 256, 0, stream>>>(zbuf, idx, xyz4, W1b2, W2b2,
                                                   statsC, statsD, ymax);

    // ---- FC head (folds SA2 norm+relu via statsD) + flow_lr ----
    k_fc<<<(B * N4) / 64, 256, 0, stream>>>(ymax, statsD, fc_W1, fc_b1, fc_W2, fc_b2, out);
    // ---- feature propagation -> flow ----
    k_fp<<<B * (N1 / 64), 256, 0, stream>>>(xyz_s1, xyz4, out);
}